// Round 1
// baseline (1254.685 us; speedup 1.0000x reference)
//
#include <hip/hip_runtime.h>
#include <cstdint>
#include <cstddef>

// Problem constants (fixed by the reference)
#define N_A   50000
#define N_B   50000
#define E_AB  320000
#define E_AA  320000
#define IN_DIM 128
#define HID    128
#define ED     64

// ---------------------------------------------------------------------------
// Node projection: P1 = X @ Wn[0:128] + (Wh_b + Wn_b),  P2 = X @ Wn[128:256]
// One thread per output column j (128 threads/block), 8 rows per block.
// X reads are block-uniform (scalar loads); W reads coalesced across j.
// ---------------------------------------------------------------------------
__global__ __launch_bounds__(128) void proj_dual_kernel(
    const float* __restrict__ X,    // [N][128]
    const float* __restrict__ Wn,   // [256][128]
    const float* __restrict__ bh,   // [128]
    const float* __restrict__ bn,   // [128]
    float* __restrict__ P1,
    float* __restrict__ P2,
    int N)
{
    const int j  = threadIdx.x;
    const int r0 = blockIdx.x * 8;
    const float* __restrict__ W1 = Wn;
    const float* __restrict__ W2 = Wn + 128 * 128;

    float acc1[8], acc2[8];
#pragma unroll
    for (int r = 0; r < 8; ++r) { acc1[r] = 0.f; acc2[r] = 0.f; }

    for (int k = 0; k < 128; k += 4) {
        float w1[4], w2[4];
#pragma unroll
        for (int q = 0; q < 4; ++q) {
            w1[q] = W1[(k + q) * 128 + j];
            w2[q] = W2[(k + q) * 128 + j];
        }
#pragma unroll
        for (int r = 0; r < 8; ++r) {
            const float4 xv = *(const float4*)&X[(size_t)(r0 + r) * 128 + k];
            acc1[r] = fmaf(xv.x, w1[0], fmaf(xv.y, w1[1], fmaf(xv.z, w1[2], fmaf(xv.w, w1[3], acc1[r]))));
            acc2[r] = fmaf(xv.x, w2[0], fmaf(xv.y, w2[1], fmaf(xv.z, w2[2], fmaf(xv.w, w2[3], acc2[r]))));
        }
    }
    const float bias = bh[j] + bn[j];
#pragma unroll
    for (int r = 0; r < 8; ++r) {
        const int row = r0 + r;
        if (row < N) {
            P1[(size_t)row * 128 + j] = acc1[r] + bias;
            P2[(size_t)row * 128 + j] = acc2[r];
        }
    }
}

__global__ __launch_bounds__(128) void proj_single_kernel(
    const float* __restrict__ X,    // [N][128]
    const float* __restrict__ W2,   // [128][128] (= Wn + 128*128)
    float* __restrict__ P2,
    int N)
{
    const int j  = threadIdx.x;
    const int r0 = blockIdx.x * 8;

    float acc[8];
#pragma unroll
    for (int r = 0; r < 8; ++r) acc[r] = 0.f;

    for (int k = 0; k < 128; k += 4) {
        float w[4];
#pragma unroll
        for (int q = 0; q < 4; ++q) w[q] = W2[(k + q) * 128 + j];
#pragma unroll
        for (int r = 0; r < 8; ++r) {
            const float4 xv = *(const float4*)&X[(size_t)(r0 + r) * 128 + k];
            acc[r] = fmaf(xv.x, w[0], fmaf(xv.y, w[1], fmaf(xv.z, w[2], fmaf(xv.w, w[3], acc[r]))));
        }
    }
#pragma unroll
    for (int r = 0; r < 8; ++r) {
        const int row = r0 + r;
        if (row < N) P2[(size_t)row * 128 + j] = acc[r];
    }
}

// ---------------------------------------------------------------------------
// Edge score: score[e] = sum_j w_e[j] * relu( (ea[e] @ Wh)[j] + P1[s][j] + P2[d][j] )
// 64 edges per block, 256 threads: thread (e8, j4) computes 8 edges x 4 cols.
// Wh (32KB) + ea tile (16KB) staged in LDS. FMA-bound inner loop.
// ---------------------------------------------------------------------------
__global__ __launch_bounds__(256) void edge_score_kernel(
    const float* __restrict__ ea,   // [E][64]
    const int*   __restrict__ ei,   // [2][E]
    const float* __restrict__ P1,   // src projections (bias folded in)
    const float* __restrict__ P2,   // dst projections
    const float* __restrict__ Wh,   // [64][128]
    const float* __restrict__ we,   // [128]
    float* __restrict__ score,      // [E]
    int E)
{
    __shared__ float sW[64 * 128];   // 32 KB
    __shared__ float sEA[64 * 64];   // 16 KB
    __shared__ int   sS[64], sD[64];

    const int t  = threadIdx.x;
    const int e0 = blockIdx.x * 64;

    for (int i = t; i < 64 * 128; i += 256) sW[i] = Wh[i];
    for (int i = t; i < 64 * 64; i += 256) {
        const int ee = e0 + (i >> 6);
        sEA[i] = ea[(size_t)ee * 64 + (i & 63)];
    }
    if (t < 64) {
        sS[t] = ei[e0 + t];
        sD[t] = ei[(size_t)E + e0 + t];
    }
    __syncthreads();

    const int j4 = t & 31;   // column group: cols j4*4 .. j4*4+3
    const int e8 = t >> 5;   // edge group: edges e8*8 .. e8*8+7

    float acc[8][4];
#pragma unroll
    for (int r = 0; r < 8; ++r) { acc[r][0] = acc[r][1] = acc[r][2] = acc[r][3] = 0.f; }

#pragma unroll 4
    for (int k = 0; k < 64; ++k) {
        const float4 w = *(const float4*)&sW[k * 128 + j4 * 4];
#pragma unroll
        for (int r = 0; r < 8; ++r) {
            const float a = sEA[(e8 * 8 + r) * 64 + k];
            acc[r][0] = fmaf(a, w.x, acc[r][0]);
            acc[r][1] = fmaf(a, w.y, acc[r][1]);
            acc[r][2] = fmaf(a, w.z, acc[r][2]);
            acc[r][3] = fmaf(a, w.w, acc[r][3]);
        }
    }

    const float4 wv = *(const float4*)&we[j4 * 4];
    float part[8];
#pragma unroll
    for (int r = 0; r < 8; ++r) {
        const int le = e8 * 8 + r;
        const float4 p1 = *(const float4*)&P1[(size_t)sS[le] * 128 + j4 * 4];
        const float4 p2 = *(const float4*)&P2[(size_t)sD[le] * 128 + j4 * 4];
        const float v0 = fmaxf(acc[r][0] + p1.x + p2.x, 0.f);
        const float v1 = fmaxf(acc[r][1] + p1.y + p2.y, 0.f);
        const float v2 = fmaxf(acc[r][2] + p1.z + p2.z, 0.f);
        const float v3 = fmaxf(acc[r][3] + p1.w + p2.w, 0.f);
        part[r] = v0 * wv.x + v1 * wv.y + v2 * wv.z + v3 * wv.w;
    }
    // reduce over the 32 j4 lanes (xor masks < 32 stay within each 32-lane half)
#pragma unroll
    for (int m = 16; m >= 1; m >>= 1) {
#pragma unroll
        for (int r = 0; r < 8; ++r) part[r] += __shfl_xor(part[r], m, 64);
    }
    if (j4 == 0) {
#pragma unroll
        for (int r = 0; r < 8; ++r) score[e0 + e8 * 8 + r] = part[r];
    }
}

// ---------------------------------------------------------------------------
// Softmax over all E scores: online (max, sum) partials -> merge -> normalize
// ---------------------------------------------------------------------------
__device__ inline void online_merge(float& m, float& l, float om, float ol) {
    const float nm = fmaxf(m, om);
    l = l * __expf(m - nm) + ol * __expf(om - nm);
    m = nm;
}

__global__ __launch_bounds__(256) void softmax_part_kernel(
    const float* __restrict__ sc, int E,
    float* __restrict__ pm, float* __restrict__ pl)
{
    float m = -1e30f, l = 0.f;
    for (int i = blockIdx.x * 256 + threadIdx.x; i < E; i += gridDim.x * 256) {
        const float s = sc[i];
        const float nm = fmaxf(m, s);
        l = l * __expf(m - nm) + __expf(s - nm);
        m = nm;
    }
#pragma unroll
    for (int off = 1; off < 64; off <<= 1) {
        const float om = __shfl_xor(m, off, 64);
        const float ol = __shfl_xor(l, off, 64);
        online_merge(m, l, om, ol);
    }
    __shared__ float smm[4], sll[4];
    const int w = threadIdx.x >> 6, lane = threadIdx.x & 63;
    if (lane == 0) { smm[w] = m; sll[w] = l; }
    __syncthreads();
    if (threadIdx.x == 0) {
        float M = smm[0], L = sll[0];
        for (int i = 1; i < 4; ++i) online_merge(M, L, smm[i], sll[i]);
        pm[blockIdx.x] = M;
        pl[blockIdx.x] = L;
    }
}

__global__ __launch_bounds__(256) void softmax_final_kernel(
    const float* __restrict__ pm, const float* __restrict__ pl,
    float* __restrict__ ML)   // ML[0]=max, ML[1]=sum
{
    float m = pm[threadIdx.x];
    float l = pl[threadIdx.x];
#pragma unroll
    for (int off = 1; off < 64; off <<= 1) {
        const float om = __shfl_xor(m, off, 64);
        const float ol = __shfl_xor(l, off, 64);
        online_merge(m, l, om, ol);
    }
    __shared__ float smm[4], sll[4];
    const int w = threadIdx.x >> 6, lane = threadIdx.x & 63;
    if (lane == 0) { smm[w] = m; sll[w] = l; }
    __syncthreads();
    if (threadIdx.x == 0) {
        float M = smm[0], L = sll[0];
        for (int i = 1; i < 4; ++i) online_merge(M, L, smm[i], sll[i]);
        ML[0] = M;
        ML[1] = L;
    }
}

__global__ __launch_bounds__(256) void softmax_norm_kernel(
    float* __restrict__ sc, int E, const float* __restrict__ ML)
{
    const float M = ML[0];
    const float rL = 1.0f / ML[1];
    const int i = blockIdx.x * 256 + threadIdx.x;
    if (i < E) sc[i] = __expf(sc[i] - M) * rL;
}

// ---------------------------------------------------------------------------
// Scatter: one 64-lane wave per edge-side task; float2 per lane; f32 atomics.
// tasks: [0,E_AB): TA[s_ab] -= a*x_b[d];  [E_AB,2E_AB): TB[d_ab] -= a*x_a[s];
//        [2E_AB, 2E_AB+E_AA): TA[s_aa] -= a*x_a[d]
// ---------------------------------------------------------------------------
__global__ __launch_bounds__(256) void scatter_kernel(
    const int* __restrict__ ei_ab, const float* __restrict__ al_ab,
    const int* __restrict__ ei_aa, const float* __restrict__ al_aa,
    const float* __restrict__ x_a, const float* __restrict__ x_b,
    float* __restrict__ TA, float* __restrict__ TB)
{
    const long gtid = (long)blockIdx.x * 256 + threadIdx.x;
    const int task = (int)(gtid >> 6);
    const int lane = threadIdx.x & 63;

    const float* src;
    float* dst;
    float a;
    if (task < E_AB) {
        const int e = task;
        const int s = ei_ab[e], d = ei_ab[E_AB + e];
        a = -al_ab[e];
        src = &x_b[(size_t)d * 128];
        dst = &TA[(size_t)s * 128];
    } else if (task < 2 * E_AB) {
        const int e = task - E_AB;
        const int s = ei_ab[e], d = ei_ab[E_AB + e];
        a = -al_ab[e];
        src = &x_a[(size_t)s * 128];
        dst = &TB[(size_t)d * 128];
    } else {
        const int e = task - 2 * E_AB;
        const int s = ei_aa[e], d = ei_aa[E_AA + e];
        a = -al_aa[e];
        src = &x_a[(size_t)d * 128];
        dst = &TA[(size_t)s * 128];
    }
    const float2 v = *(const float2*)&src[lane * 2];
    unsafeAtomicAdd(&dst[lane * 2 + 0], a * v.x);
    unsafeAtomicAdd(&dst[lane * 2 + 1], a * v.y);
}

// ---------------------------------------------------------------------------
// Final residual transform, in place on T (= x + lf):  T <- T + T@F + b
// Row-private: each block owns 8 rows. Barrier separates all reads from writes.
// ---------------------------------------------------------------------------
__global__ __launch_bounds__(128) void final_kernel(
    float* __restrict__ T, const float* __restrict__ F,
    const float* __restrict__ fb, int N)
{
    const int j  = threadIdx.x;
    const int r0 = blockIdx.x * 8;

    float acc[8];
#pragma unroll
    for (int r = 0; r < 8; ++r) acc[r] = 0.f;

    for (int k = 0; k < 128; k += 4) {
        float f[4];
#pragma unroll
        for (int q = 0; q < 4; ++q) f[q] = F[(k + q) * 128 + j];
#pragma unroll
        for (int r = 0; r < 8; ++r) {
            const float4 xv = *(const float4*)&T[(size_t)(r0 + r) * 128 + k];
            acc[r] = fmaf(xv.x, f[0], fmaf(xv.y, f[1], fmaf(xv.z, f[2], fmaf(xv.w, f[3], acc[r]))));
        }
    }
    float told[8];
#pragma unroll
    for (int r = 0; r < 8; ++r) told[r] = T[(size_t)(r0 + r) * 128 + j];
    const float b = fb[j];
    __syncthreads();   // all reads of these 8 rows complete before any write
#pragma unroll
    for (int r = 0; r < 8; ++r) {
        const int row = r0 + r;
        if (row < N) T[(size_t)row * 128 + j] = told[r] + b + acc[r];
    }
}

// ---------------------------------------------------------------------------
extern "C" void kernel_launch(void* const* d_in, const int* in_sizes, int n_in,
                              void* d_out, int out_size, void* d_ws, size_t ws_size,
                              hipStream_t stream)
{
    const float* x_a   = (const float*)d_in[0];
    const float* x_b   = (const float*)d_in[1];
    const int*   ei_ab = (const int*)d_in[2];
    const float* ea_ab = (const float*)d_in[3];
    const int*   ei_aa = (const int*)d_in[4];
    const float* ea_aa = (const float*)d_in[5];
    const float* Wh_w  = (const float*)d_in[6];
    const float* Wh_b  = (const float*)d_in[7];
    const float* Wn_w  = (const float*)d_in[8];
    const float* Wn_b  = (const float*)d_in[9];
    const float* w_e   = (const float*)d_in[10];
    const float* ft_w  = (const float*)d_in[11];
    const float* ft_b  = (const float*)d_in[12];

    float* out = (float*)d_out;
    float* ws  = (float*)d_ws;

    // workspace layout (floats): P1[6.4M] P2a[6.4M] P2b[6.4M] RED[~1.5K]  (~77 MB)
    float* P1  = ws;
    float* P2a = ws + 6400000;
    float* P2b = ws + 12800000;
    float* RED = ws + 19200000;
    float* pm_ab = RED;        float* pl_ab = RED + 256;
    float* pm_aa = RED + 512;  float* pl_aa = RED + 768;
    float* ML_ab = RED + 1024; float* ML_aa = RED + 1026;

    // d_out layout: out_a[6.4M] out_b[6.4M] alpha_ab[320K] alpha_aa[320K]
    float* TA   = out;             // t_a, then transformed in place to out_a
    float* TB   = out + 6400000;
    float* alAB = out + 12800000;  // scores first, then alpha in place
    float* alAA = out + 13120000;

    // 1) node projections
    proj_dual_kernel<<<N_A / 8, 128, 0, stream>>>(x_a, Wn_w, Wh_b, Wn_b, P1, P2a, N_A);
    proj_single_kernel<<<N_B / 8, 128, 0, stream>>>(x_b, Wn_w + 128 * 128, P2b, N_B);

    // 2) edge scores (written into the alpha slots of d_out)
    edge_score_kernel<<<E_AB / 64, 256, 0, stream>>>(ea_ab, ei_ab, P1, P2b, Wh_w, w_e, alAB, E_AB);
    edge_score_kernel<<<E_AA / 64, 256, 0, stream>>>(ea_aa, ei_aa, P1, P2a, Wh_w, w_e, alAA, E_AA);

    // 3) global softmax per edge type (in place)
    softmax_part_kernel<<<256, 256, 0, stream>>>(alAB, E_AB, pm_ab, pl_ab);
    softmax_final_kernel<<<1, 256, 0, stream>>>(pm_ab, pl_ab, ML_ab);
    softmax_norm_kernel<<<(E_AB + 255) / 256, 256, 0, stream>>>(alAB, E_AB, ML_ab);
    softmax_part_kernel<<<256, 256, 0, stream>>>(alAA, E_AA, pm_aa, pl_aa);
    softmax_final_kernel<<<1, 256, 0, stream>>>(pm_aa, pl_aa, ML_aa);
    softmax_norm_kernel<<<(E_AA + 255) / 256, 256, 0, stream>>>(alAA, E_AA, ML_aa);

    // 4) t = x  (P1/P2a are dead now; t lives in d_out so ws stays small)
    hipMemcpyAsync(TA, x_a, (size_t)6400000 * sizeof(float), hipMemcpyDeviceToDevice, stream);
    hipMemcpyAsync(TB, x_b, (size_t)6400000 * sizeof(float), hipMemcpyDeviceToDevice, stream);

    // 5) scatter-add edge contributions (960K wave-tasks)
    {
        const long waves = 2L * E_AB + E_AA;            // 960000
        const long blocks = waves * 64 / 256;           // 240000
        scatter_kernel<<<(int)blocks, 256, 0, stream>>>(ei_ab, alAB, ei_aa, alAA,
                                                        x_a, x_b, TA, TB);
    }

    // 6) out = t + t@F + b  (in place)
    final_kernel<<<N_A / 8, 128, 0, stream>>>(TA, ft_w, ft_b, N_A);
    final_kernel<<<N_B / 8, 128, 0, stream>>>(TB, ft_w, ft_b, N_B);

    (void)in_sizes; (void)n_in; (void)out_size; (void)ws_size;
}

// Round 2
// 697.470 us; speedup vs baseline: 1.7989x; 1.7989x over previous
//
#include <hip/hip_runtime.h>
#include <cstdint>
#include <cstddef>

// Problem constants (fixed by the reference)
#define N_A   50000
#define N_B   50000
#define E_AB  320000
#define E_AA  320000
#define IN_DIM 128
#define HID    128
#define ED     64

// ---------------------------------------------------------------------------
// Node projection: P1 = X @ Wn[0:128] + (Wh_b + Wn_b),  P2 = X @ Wn[128:256]
// ---------------------------------------------------------------------------
__global__ __launch_bounds__(128) void proj_dual_kernel(
    const float* __restrict__ X,    // [N][128]
    const float* __restrict__ Wn,   // [256][128]
    const float* __restrict__ bh,   // [128]
    const float* __restrict__ bn,   // [128]
    float* __restrict__ P1,
    float* __restrict__ P2,
    int N)
{
    const int j  = threadIdx.x;
    const int r0 = blockIdx.x * 8;
    const float* __restrict__ W1 = Wn;
    const float* __restrict__ W2 = Wn + 128 * 128;

    float acc1[8], acc2[8];
#pragma unroll
    for (int r = 0; r < 8; ++r) { acc1[r] = 0.f; acc2[r] = 0.f; }

    for (int k = 0; k < 128; k += 4) {
        float w1[4], w2[4];
#pragma unroll
        for (int q = 0; q < 4; ++q) {
            w1[q] = W1[(k + q) * 128 + j];
            w2[q] = W2[(k + q) * 128 + j];
        }
#pragma unroll
        for (int r = 0; r < 8; ++r) {
            const float4 xv = *(const float4*)&X[(size_t)(r0 + r) * 128 + k];
            acc1[r] = fmaf(xv.x, w1[0], fmaf(xv.y, w1[1], fmaf(xv.z, w1[2], fmaf(xv.w, w1[3], acc1[r]))));
            acc2[r] = fmaf(xv.x, w2[0], fmaf(xv.y, w2[1], fmaf(xv.z, w2[2], fmaf(xv.w, w2[3], acc2[r]))));
        }
    }
    const float bias = bh[j] + bn[j];
#pragma unroll
    for (int r = 0; r < 8; ++r) {
        const int row = r0 + r;
        if (row < N) {
            P1[(size_t)row * 128 + j] = acc1[r] + bias;
            P2[(size_t)row * 128 + j] = acc2[r];
        }
    }
}

__global__ __launch_bounds__(128) void proj_single_kernel(
    const float* __restrict__ X,    // [N][128]
    const float* __restrict__ W2,   // [128][128]
    float* __restrict__ P2,
    int N)
{
    const int j  = threadIdx.x;
    const int r0 = blockIdx.x * 8;

    float acc[8];
#pragma unroll
    for (int r = 0; r < 8; ++r) acc[r] = 0.f;

    for (int k = 0; k < 128; k += 4) {
        float w[4];
#pragma unroll
        for (int q = 0; q < 4; ++q) w[q] = W2[(k + q) * 128 + j];
#pragma unroll
        for (int r = 0; r < 8; ++r) {
            const float4 xv = *(const float4*)&X[(size_t)(r0 + r) * 128 + k];
            acc[r] = fmaf(xv.x, w[0], fmaf(xv.y, w[1], fmaf(xv.z, w[2], fmaf(xv.w, w[3], acc[r]))));
        }
    }
#pragma unroll
    for (int r = 0; r < 8; ++r) {
        const int row = r0 + r;
        if (row < N) P2[(size_t)row * 128 + j] = acc[r];
    }
}

// ---------------------------------------------------------------------------
// Edge score: score[e] = sum_j w_e[j] * relu( (ea[e] @ Wh)[j] + P1[s][j] + P2[d][j] )
// ---------------------------------------------------------------------------
__global__ __launch_bounds__(256) void edge_score_kernel(
    const float* __restrict__ ea,   // [E][64]
    const int*   __restrict__ ei,   // [2][E]
    const float* __restrict__ P1,   // src projections (bias folded in)
    const float* __restrict__ P2,   // dst projections
    const float* __restrict__ Wh,   // [64][128]
    const float* __restrict__ we,   // [128]
    float* __restrict__ score,      // [E]
    int E)
{
    __shared__ float sW[64 * 128];   // 32 KB
    __shared__ float sEA[64 * 64];   // 16 KB
    __shared__ int   sS[64], sD[64];

    const int t  = threadIdx.x;
    const int e0 = blockIdx.x * 64;

    for (int i = t; i < 64 * 128; i += 256) sW[i] = Wh[i];
    for (int i = t; i < 64 * 64; i += 256) {
        const int ee = e0 + (i >> 6);
        sEA[i] = ea[(size_t)ee * 64 + (i & 63)];
    }
    if (t < 64) {
        sS[t] = ei[e0 + t];
        sD[t] = ei[(size_t)E + e0 + t];
    }
    __syncthreads();

    const int j4 = t & 31;   // column group: cols j4*4 .. j4*4+3
    const int e8 = t >> 5;   // edge group: edges e8*8 .. e8*8+7

    float acc[8][4];
#pragma unroll
    for (int r = 0; r < 8; ++r) { acc[r][0] = acc[r][1] = acc[r][2] = acc[r][3] = 0.f; }

#pragma unroll 4
    for (int k = 0; k < 64; ++k) {
        const float4 w = *(const float4*)&sW[k * 128 + j4 * 4];
#pragma unroll
        for (int r = 0; r < 8; ++r) {
            const float a = sEA[(e8 * 8 + r) * 64 + k];
            acc[r][0] = fmaf(a, w.x, acc[r][0]);
            acc[r][1] = fmaf(a, w.y, acc[r][1]);
            acc[r][2] = fmaf(a, w.z, acc[r][2]);
            acc[r][3] = fmaf(a, w.w, acc[r][3]);
        }
    }

    const float4 wv = *(const float4*)&we[j4 * 4];
    float part[8];
#pragma unroll
    for (int r = 0; r < 8; ++r) {
        const int le = e8 * 8 + r;
        const float4 p1 = *(const float4*)&P1[(size_t)sS[le] * 128 + j4 * 4];
        const float4 p2 = *(const float4*)&P2[(size_t)sD[le] * 128 + j4 * 4];
        const float v0 = fmaxf(acc[r][0] + p1.x + p2.x, 0.f);
        const float v1 = fmaxf(acc[r][1] + p1.y + p2.y, 0.f);
        const float v2 = fmaxf(acc[r][2] + p1.z + p2.z, 0.f);
        const float v3 = fmaxf(acc[r][3] + p1.w + p2.w, 0.f);
        part[r] = v0 * wv.x + v1 * wv.y + v2 * wv.z + v3 * wv.w;
    }
#pragma unroll
    for (int m = 16; m >= 1; m >>= 1) {
#pragma unroll
        for (int r = 0; r < 8; ++r) part[r] += __shfl_xor(part[r], m, 64);
    }
    if (j4 == 0) {
#pragma unroll
        for (int r = 0; r < 8; ++r) score[e0 + e8 * 8 + r] = part[r];
    }
}

// ---------------------------------------------------------------------------
// Softmax over all E scores
// ---------------------------------------------------------------------------
__device__ inline void online_merge(float& m, float& l, float om, float ol) {
    const float nm = fmaxf(m, om);
    l = l * __expf(m - nm) + ol * __expf(om - nm);
    m = nm;
}

__global__ __launch_bounds__(256) void softmax_part_kernel(
    const float* __restrict__ sc, int E,
    float* __restrict__ pm, float* __restrict__ pl)
{
    float m = -1e30f, l = 0.f;
    for (int i = blockIdx.x * 256 + threadIdx.x; i < E; i += gridDim.x * 256) {
        const float s = sc[i];
        const float nm = fmaxf(m, s);
        l = l * __expf(m - nm) + __expf(s - nm);
        m = nm;
    }
#pragma unroll
    for (int off = 1; off < 64; off <<= 1) {
        const float om = __shfl_xor(m, off, 64);
        const float ol = __shfl_xor(l, off, 64);
        online_merge(m, l, om, ol);
    }
    __shared__ float smm[4], sll[4];
    const int w = threadIdx.x >> 6, lane = threadIdx.x & 63;
    if (lane == 0) { smm[w] = m; sll[w] = l; }
    __syncthreads();
    if (threadIdx.x == 0) {
        float M = smm[0], L = sll[0];
        for (int i = 1; i < 4; ++i) online_merge(M, L, smm[i], sll[i]);
        pm[blockIdx.x] = M;
        pl[blockIdx.x] = L;
    }
}

__global__ __launch_bounds__(256) void softmax_final_kernel(
    const float* __restrict__ pm, const float* __restrict__ pl,
    float* __restrict__ ML)
{
    float m = pm[threadIdx.x];
    float l = pl[threadIdx.x];
#pragma unroll
    for (int off = 1; off < 64; off <<= 1) {
        const float om = __shfl_xor(m, off, 64);
        const float ol = __shfl_xor(l, off, 64);
        online_merge(m, l, om, ol);
    }
    __shared__ float smm[4], sll[4];
    const int w = threadIdx.x >> 6, lane = threadIdx.x & 63;
    if (lane == 0) { smm[w] = m; sll[w] = l; }
    __syncthreads();
    if (threadIdx.x == 0) {
        float M = smm[0], L = sll[0];
        for (int i = 1; i < 4; ++i) online_merge(M, L, smm[i], sll[i]);
        ML[0] = M;
        ML[1] = L;
    }
}

__global__ __launch_bounds__(256) void softmax_norm_kernel(
    float* __restrict__ sc, int E, const float* __restrict__ ML)
{
    const float M = ML[0];
    const float rL = 1.0f / ML[1];
    const int i = blockIdx.x * 256 + threadIdx.x;
    if (i < E) sc[i] = __expf(sc[i] - M) * rL;
}

// ---------------------------------------------------------------------------
// CSR build: count -> scan -> fill.  Replaces the 123M-f32-atomic scatter.
// Entry code: src_row | (1<<20 if row indexes x_b).  Value: alpha bits.
// ---------------------------------------------------------------------------
__global__ __launch_bounds__(256) void csr_count_kernel(
    const int* __restrict__ ei_ab, const int* __restrict__ ei_aa,
    int* __restrict__ cntA, int* __restrict__ cntB)
{
    const int i = blockIdx.x * 256 + threadIdx.x;
    if (i < E_AB) {
        atomicAdd(&cntA[ei_ab[i]], 1);          // TA <- s_ab side
        atomicAdd(&cntB[ei_ab[E_AB + i]], 1);   // TB <- d_ab side
    }
    if (i < E_AA) {
        atomicAdd(&cntA[ei_aa[i]], 1);          // TA <- s_aa side
    }
}

// One block per target (blockIdx 0 = A, 1 = B). Exclusive scan of 50000
// counts, in place (cnt array becomes cursor array), offsets to off[0..N].
__global__ __launch_bounds__(1024) void csr_scan_kernel(
    int* __restrict__ cntA, int* __restrict__ offA,
    int* __restrict__ cntB, int* __restrict__ offB, int N)
{
    int* cnt = (blockIdx.x == 0) ? cntA : cntB;
    int* off = (blockIdx.x == 0) ? offA : offB;

    __shared__ int warpsum[16];
    const int t = threadIdx.x, lane = t & 63, w = t >> 6;
    int carry = 0;

    for (int base = 0; base < N; base += 1024) {
        const int i = base + t;
        const int v = (i < N) ? cnt[i] : 0;
        int x = v;
#pragma unroll
        for (int d = 1; d < 64; d <<= 1) {
            const int y = __shfl_up(x, d, 64);
            if (lane >= d) x += y;
        }
        if (lane == 63) warpsum[w] = x;
        __syncthreads();
        if (w == 0 && lane < 16) {
            int s = warpsum[lane];
#pragma unroll
            for (int d = 1; d < 16; d <<= 1) {
                const int y = __shfl_up(s, d, 64);
                if (lane >= d) s += y;
            }
            warpsum[lane] = s;
        }
        __syncthreads();
        const int excl = (x - v) + ((w > 0) ? warpsum[w - 1] : 0) + carry;
        if (i < N) { off[i] = excl; cnt[i] = excl; }   // cnt becomes cursor
        carry += warpsum[15];
        __syncthreads();   // protect warpsum before next chunk
    }
    if (t == 0) off[N] = carry;
}

__global__ __launch_bounds__(256) void csr_fill_kernel(
    const int* __restrict__ ei_ab, const int* __restrict__ ei_aa,
    const float* __restrict__ alAB, const float* __restrict__ alAA,
    int* __restrict__ curA, int* __restrict__ curB,
    int2* __restrict__ idxA, int2* __restrict__ idxB)
{
    const int i = blockIdx.x * 256 + threadIdx.x;
    if (i < E_AB) {
        const int s = ei_ab[i], d = ei_ab[E_AB + i];
        const int ab = __float_as_int(alAB[i]);
        const int pA = atomicAdd(&curA[s], 1);
        idxA[pA] = make_int2(d | (1 << 20), ab);   // TA pulls from x_b[d]
        const int pB = atomicAdd(&curB[d], 1);
        idxB[pB] = make_int2(s, ab);               // TB pulls from x_a[s]
    }
    if (i < E_AA) {
        const int s = ei_aa[i], d = ei_aa[E_AA + i];
        const int aa = __float_as_int(alAA[i]);
        const int pA = atomicAdd(&curA[s], 1);
        idxA[pA] = make_int2(d, aa);               // TA pulls from x_a[d]
    }
}

// ---------------------------------------------------------------------------
// Gather: one 64-lane wave per destination node. acc init = x_self row
// (folds the t = x memcpy). Each output row written exactly once, no atomics.
// ---------------------------------------------------------------------------
__global__ __launch_bounds__(256) void gather_kernel(
    const int*  __restrict__ off,    // [N+1]
    const int2* __restrict__ idx,
    const float* __restrict__ xa,    // code flag 0 -> this base
    const float* __restrict__ xb,    // code flag 1 -> this base
    const float* __restrict__ xself,
    float* __restrict__ T,
    int N)
{
    const int wid  = (blockIdx.x * 256 + threadIdx.x) >> 6;
    const int lane = threadIdx.x & 63;
    if (wid >= N) return;

    const int beg = off[wid], end = off[wid + 1];
    float2 acc = *(const float2*)&xself[(size_t)wid * 128 + lane * 2];

    int e = beg;
    for (; e + 1 < end; e += 2) {
        const int2 e0 = idx[e];
        const int2 e1 = idx[e + 1];
        const float a0 = __int_as_float(e0.y);
        const float a1 = __int_as_float(e1.y);
        const float* s0 = (e0.x & (1 << 20)) ? &xb[(size_t)(e0.x & 0xFFFFF) * 128]
                                             : &xa[(size_t)(e0.x & 0xFFFFF) * 128];
        const float* s1 = (e1.x & (1 << 20)) ? &xb[(size_t)(e1.x & 0xFFFFF) * 128]
                                             : &xa[(size_t)(e1.x & 0xFFFFF) * 128];
        const float2 v0 = *(const float2*)&s0[lane * 2];
        const float2 v1 = *(const float2*)&s1[lane * 2];
        acc.x -= a0 * v0.x + a1 * v1.x;
        acc.y -= a0 * v0.y + a1 * v1.y;
    }
    if (e < end) {
        const int2 e0 = idx[e];
        const float a0 = __int_as_float(e0.y);
        const float* s0 = (e0.x & (1 << 20)) ? &xb[(size_t)(e0.x & 0xFFFFF) * 128]
                                             : &xa[(size_t)(e0.x & 0xFFFFF) * 128];
        const float2 v0 = *(const float2*)&s0[lane * 2];
        acc.x -= a0 * v0.x;
        acc.y -= a0 * v0.y;
    }
    *(float2*)&T[(size_t)wid * 128 + lane * 2] = acc;
}

// ---------------------------------------------------------------------------
// Final residual transform, in place on T:  T <- T + T@F + b
// ---------------------------------------------------------------------------
__global__ __launch_bounds__(128) void final_kernel(
    float* __restrict__ T, const float* __restrict__ F,
    const float* __restrict__ fb, int N)
{
    const int j  = threadIdx.x;
    const int r0 = blockIdx.x * 8;

    float acc[8];
#pragma unroll
    for (int r = 0; r < 8; ++r) acc[r] = 0.f;

    for (int k = 0; k < 128; k += 4) {
        float f[4];
#pragma unroll
        for (int q = 0; q < 4; ++q) f[q] = F[(k + q) * 128 + j];
#pragma unroll
        for (int r = 0; r < 8; ++r) {
            const float4 xv = *(const float4*)&T[(size_t)(r0 + r) * 128 + k];
            acc[r] = fmaf(xv.x, f[0], fmaf(xv.y, f[1], fmaf(xv.z, f[2], fmaf(xv.w, f[3], acc[r]))));
        }
    }
    float told[8];
#pragma unroll
    for (int r = 0; r < 8; ++r) told[r] = T[(size_t)(r0 + r) * 128 + j];
    const float b = fb[j];
    __syncthreads();
#pragma unroll
    for (int r = 0; r < 8; ++r) {
        const int row = r0 + r;
        if (row < N) T[(size_t)row * 128 + j] = told[r] + b + acc[r];
    }
}

// ---------------------------------------------------------------------------
extern "C" void kernel_launch(void* const* d_in, const int* in_sizes, int n_in,
                              void* d_out, int out_size, void* d_ws, size_t ws_size,
                              hipStream_t stream)
{
    const float* x_a   = (const float*)d_in[0];
    const float* x_b   = (const float*)d_in[1];
    const int*   ei_ab = (const int*)d_in[2];
    const float* ea_ab = (const float*)d_in[3];
    const int*   ei_aa = (const int*)d_in[4];
    const float* ea_aa = (const float*)d_in[5];
    const float* Wh_w  = (const float*)d_in[6];
    const float* Wh_b  = (const float*)d_in[7];
    const float* Wn_w  = (const float*)d_in[8];
    const float* Wn_b  = (const float*)d_in[9];
    const float* w_e   = (const float*)d_in[10];
    const float* ft_w  = (const float*)d_in[11];
    const float* ft_b  = (const float*)d_in[12];

    float* out = (float*)d_out;
    float* ws  = (float*)d_ws;

    // ws layout (floats): P1[6.4M] P2a[6.4M] P2b[6.4M] RED[2K]
    // After edge_score, P1's region is dead -> reused for CSR:
    //   curA[50000] curB[50000] offA[50001] offB[50001] idxA[1.28M] idxB[640K]
    float* P1  = ws;
    float* P2a = ws + 6400000;
    float* P2b = ws + 12800000;
    float* RED = ws + 19200000;
    float* pm_ab = RED;        float* pl_ab = RED + 256;
    float* pm_aa = RED + 512;  float* pl_aa = RED + 768;
    float* ML_ab = RED + 1024; float* ML_aa = RED + 1026;

    int*  curA = (int*)ws;                 // counts, then cursors
    int*  curB = (int*)ws + 50000;
    int*  offA = (int*)ws + 100352;
    int*  offB = (int*)ws + 150528;
    int2* idxA = (int2*)((int*)ws + 200704);   // 640000 entries
    int2* idxB = (int2*)((int*)ws + 1480704);  // 320000 entries

    // d_out layout: out_a[6.4M] out_b[6.4M] alpha_ab[320K] alpha_aa[320K]
    float* TA   = out;
    float* TB   = out + 6400000;
    float* alAB = out + 12800000;  // scores first, then alpha in place
    float* alAA = out + 13120000;

    // 1) node projections
    proj_dual_kernel<<<N_A / 8, 128, 0, stream>>>(x_a, Wn_w, Wh_b, Wn_b, P1, P2a, N_A);
    proj_single_kernel<<<N_B / 8, 128, 0, stream>>>(x_b, Wn_w + 128 * 128, P2b, N_B);

    // 2) edge scores
    edge_score_kernel<<<E_AB / 64, 256, 0, stream>>>(ea_ab, ei_ab, P1, P2b, Wh_w, w_e, alAB, E_AB);
    edge_score_kernel<<<E_AA / 64, 256, 0, stream>>>(ea_aa, ei_aa, P1, P2a, Wh_w, w_e, alAA, E_AA);

    // 3) global softmax per edge type (in place)
    softmax_part_kernel<<<256, 256, 0, stream>>>(alAB, E_AB, pm_ab, pl_ab);
    softmax_final_kernel<<<1, 256, 0, stream>>>(pm_ab, pl_ab, ML_ab);
    softmax_norm_kernel<<<(E_AB + 255) / 256, 256, 0, stream>>>(alAB, E_AB, ML_ab);
    softmax_part_kernel<<<256, 256, 0, stream>>>(alAA, E_AA, pm_aa, pl_aa);
    softmax_final_kernel<<<1, 256, 0, stream>>>(pm_aa, pl_aa, ML_aa);
    softmax_norm_kernel<<<(E_AA + 255) / 256, 256, 0, stream>>>(alAA, E_AA, ML_aa);

    // 4) CSR build (P1 region is dead now)
    hipMemsetAsync(curA, 0, 100000 * sizeof(int), stream);
    csr_count_kernel<<<(E_AB + 255) / 256, 256, 0, stream>>>(ei_ab, ei_aa, curA, curB);
    csr_scan_kernel<<<2, 1024, 0, stream>>>(curA, offA, curB, offB, N_A);
    csr_fill_kernel<<<(E_AB + 255) / 256, 256, 0, stream>>>(ei_ab, ei_aa, alAB, alAA,
                                                            curA, curB, idxA, idxB);

    // 5) gather (one wave per node; init acc = x row -> folds t = x memcpy)
    gather_kernel<<<(N_A + 3) / 4, 256, 0, stream>>>(offA, idxA, x_a, x_b, x_a, TA, N_A);
    gather_kernel<<<(N_B + 3) / 4, 256, 0, stream>>>(offB, idxB, x_a, x_b, x_b, TB, N_B);

    // 6) out = t + t@F + b  (in place)
    final_kernel<<<N_A / 8, 128, 0, stream>>>(TA, ft_w, ft_b, N_A);
    final_kernel<<<N_B / 8, 128, 0, stream>>>(TB, ft_w, ft_b, N_B);

    (void)in_sizes; (void)n_in; (void)out_size; (void)ws_size;
}

// Round 3
// 612.351 us; speedup vs baseline: 2.0490x; 1.1390x over previous
//
#include <hip/hip_runtime.h>
#include <cstdint>
#include <cstddef>

// Problem constants (fixed by the reference)
#define N_A   50000
#define N_B   50000
#define E_AB  320000
#define E_AA  320000
#define IN_DIM 128
#define HID    128
#define ED     64

using bf16x8 = __attribute__((ext_vector_type(8))) short;
using f32x4  = __attribute__((ext_vector_type(4))) float;
typedef unsigned short ushort_t;
typedef unsigned int   uint_t;

__device__ inline ushort_t bf16r(float f) {   // f32 -> bf16 bits, RNE
    uint_t u = __float_as_uint(f);
    u = (u + 0x7FFF + ((u >> 16) & 1)) >> 16;
    return (ushort_t)u;
}
__device__ inline float bf2f(ushort_t h) {
    return __uint_as_float(((uint_t)h) << 16);
}

// ---------------------------------------------------------------------------
// Node projection: P1 = X @ Wn[0:128] + (Wh_b + Wn_b),  P2 = X @ Wn[128:256]
// ---------------------------------------------------------------------------
__global__ __launch_bounds__(128) void proj_dual_kernel(
    const float* __restrict__ X, const float* __restrict__ Wn,
    const float* __restrict__ bh, const float* __restrict__ bn,
    float* __restrict__ P1, float* __restrict__ P2, int N)
{
    const int j  = threadIdx.x;
    const int r0 = blockIdx.x * 8;
    const float* __restrict__ W1 = Wn;
    const float* __restrict__ W2 = Wn + 128 * 128;

    float acc1[8], acc2[8];
#pragma unroll
    for (int r = 0; r < 8; ++r) { acc1[r] = 0.f; acc2[r] = 0.f; }

    for (int k = 0; k < 128; k += 4) {
        float w1[4], w2[4];
#pragma unroll
        for (int q = 0; q < 4; ++q) {
            w1[q] = W1[(k + q) * 128 + j];
            w2[q] = W2[(k + q) * 128 + j];
        }
#pragma unroll
        for (int r = 0; r < 8; ++r) {
            const float4 xv = *(const float4*)&X[(size_t)(r0 + r) * 128 + k];
            acc1[r] = fmaf(xv.x, w1[0], fmaf(xv.y, w1[1], fmaf(xv.z, w1[2], fmaf(xv.w, w1[3], acc1[r]))));
            acc2[r] = fmaf(xv.x, w2[0], fmaf(xv.y, w2[1], fmaf(xv.z, w2[2], fmaf(xv.w, w2[3], acc2[r]))));
        }
    }
    const float bias = bh[j] + bn[j];
#pragma unroll
    for (int r = 0; r < 8; ++r) {
        const int row = r0 + r;
        if (row < N) {
            P1[(size_t)row * 128 + j] = acc1[r] + bias;
            P2[(size_t)row * 128 + j] = acc2[r];
        }
    }
}

__global__ __launch_bounds__(128) void proj_single_kernel(
    const float* __restrict__ X, const float* __restrict__ W2,
    float* __restrict__ P2, int N)
{
    const int j  = threadIdx.x;
    const int r0 = blockIdx.x * 8;

    float acc[8];
#pragma unroll
    for (int r = 0; r < 8; ++r) acc[r] = 0.f;

    for (int k = 0; k < 128; k += 4) {
        float w[4];
#pragma unroll
        for (int q = 0; q < 4; ++q) w[q] = W2[(k + q) * 128 + j];
#pragma unroll
        for (int r = 0; r < 8; ++r) {
            const float4 xv = *(const float4*)&X[(size_t)(r0 + r) * 128 + k];
            acc[r] = fmaf(xv.x, w[0], fmaf(xv.y, w[1], fmaf(xv.z, w[2], fmaf(xv.w, w[3], acc[r]))));
        }
    }
#pragma unroll
    for (int r = 0; r < 8; ++r) {
        const int row = r0 + r;
        if (row < N) P2[(size_t)row * 128 + j] = acc[r];
    }
}

// ---------------------------------------------------------------------------
// Pre-pack Wh into bf16 hi/lo B-fragments for mfma_f32_16x16x32_bf16.
// B frag: lane holds col = lane&15, k = kt*32 + (lane>>4)*8 + j  (j=0..7)
// Layout: Bhi[((ct*2+kt)*64 + lane)*8 + j]
// ---------------------------------------------------------------------------
__global__ __launch_bounds__(256) void prep_b_kernel(
    const float* __restrict__ Wh, ushort_t* __restrict__ Bhi, ushort_t* __restrict__ Blo)
{
    const int t = blockIdx.x * 256 + threadIdx.x;   // 0..1023
    const int frag = t >> 6;                        // ct*2+kt
    const int lane = t & 63;
    const int ct = frag >> 1, kt = frag & 1;
    const int col = ct * 16 + (lane & 15);
    const int kb  = kt * 32 + (lane >> 4) * 8;
#pragma unroll
    for (int j = 0; j < 8; ++j) {
        const float v = Wh[(kb + j) * 128 + col];
        const ushort_t h = bf16r(v);
        const float hf = bf2f(h);
        Bhi[(size_t)t * 8 + j] = h;
        Blo[(size_t)t * 8 + j] = bf16r(v - hf);
    }
}

// ---------------------------------------------------------------------------
// Edge score via MFMA (bf16x2 split => ~f32 accuracy):
//   score[e] = sum_j we[j] * relu( (ea[e]@Wh)[j] + P1[s][j] + P2[d][j] )
// 4 waves/block, 16 edges/wave, no LDS, no barriers.
// ---------------------------------------------------------------------------
__global__ __launch_bounds__(256) void edge_score_mfma(
    const float* __restrict__ ea,    // [E][64]
    const int*   __restrict__ ei,    // [2][E]
    const float* __restrict__ P1,
    const float* __restrict__ P2,
    const ushort_t* __restrict__ Bhi,
    const ushort_t* __restrict__ Blo,
    const float* __restrict__ we,
    float* __restrict__ score, int E)
{
    const int t    = threadIdx.x;
    const int lane = t & 63;
    const int l15  = lane & 15;
    const int lg   = lane >> 4;
    const int e0   = blockIdx.x * 64 + (t >> 6) * 16;   // wave's 16 edges

    // A fragment: row = l15 (edge e0+l15), k = kt*32 + lg*8 + j
    const float* arow = &ea[(size_t)(e0 + l15) * 64 + lg * 8];
    float af[16];
    *(float4*)(af + 0)  = *(const float4*)(arow + 0);
    *(float4*)(af + 4)  = *(const float4*)(arow + 4);
    *(float4*)(af + 8)  = *(const float4*)(arow + 32);
    *(float4*)(af + 12) = *(const float4*)(arow + 36);

    bf16x8 ahi0, alo0, ahi1, alo1;
#pragma unroll
    for (int j = 0; j < 8; ++j) {
        const ushort_t h0 = bf16r(af[j]);
        ahi0[j] = (short)h0;
        alo0[j] = (short)bf16r(af[j] - bf2f(h0));
        const ushort_t h1 = bf16r(af[8 + j]);
        ahi1[j] = (short)h1;
        alo1[j] = (short)bf16r(af[8 + j] - bf2f(h1));
    }

    f32x4 acc[8];
#pragma unroll
    for (int ct = 0; ct < 8; ++ct) acc[ct] = (f32x4){0.f, 0.f, 0.f, 0.f};

#pragma unroll
    for (int ct = 0; ct < 8; ++ct) {
        const bf16x8 bh0 = *(const bf16x8*)&Bhi[(size_t)(ct * 2 + 0) * 512 + lane * 8];
        const bf16x8 bl0 = *(const bf16x8*)&Blo[(size_t)(ct * 2 + 0) * 512 + lane * 8];
        const bf16x8 bh1 = *(const bf16x8*)&Bhi[(size_t)(ct * 2 + 1) * 512 + lane * 8];
        const bf16x8 bl1 = *(const bf16x8*)&Blo[(size_t)(ct * 2 + 1) * 512 + lane * 8];
        acc[ct] = __builtin_amdgcn_mfma_f32_16x16x32_bf16(ahi0, bh0, acc[ct], 0, 0, 0);
        acc[ct] = __builtin_amdgcn_mfma_f32_16x16x32_bf16(alo0, bh0, acc[ct], 0, 0, 0);
        acc[ct] = __builtin_amdgcn_mfma_f32_16x16x32_bf16(ahi0, bl0, acc[ct], 0, 0, 0);
        acc[ct] = __builtin_amdgcn_mfma_f32_16x16x32_bf16(ahi1, bh1, acc[ct], 0, 0, 0);
        acc[ct] = __builtin_amdgcn_mfma_f32_16x16x32_bf16(alo1, bh1, acc[ct], 0, 0, 0);
        acc[ct] = __builtin_amdgcn_mfma_f32_16x16x32_bf16(ahi1, bl1, acc[ct], 0, 0, 0);
    }

    // C layout: col = l15, row = lg*4 + i  (edge = e0 + lg*4 + i)
    int sidx[4], didx[4];
#pragma unroll
    for (int i = 0; i < 4; ++i) {
        const int e = e0 + lg * 4 + i;
        sidx[i] = ei[e];
        didx[i] = ei[(size_t)E + e];
    }

    float part[4] = {0.f, 0.f, 0.f, 0.f};
#pragma unroll
    for (int ct = 0; ct < 8; ++ct) {
        const float wv = we[ct * 16 + l15];
#pragma unroll
        for (int i = 0; i < 4; ++i) {
            const float h = acc[ct][i]
                          + P1[(size_t)sidx[i] * 128 + ct * 16 + l15]
                          + P2[(size_t)didx[i] * 128 + ct * 16 + l15];
            part[i] = fmaf(fmaxf(h, 0.f), wv, part[i]);
        }
    }
#pragma unroll
    for (int m = 8; m >= 1; m >>= 1) {
#pragma unroll
        for (int i = 0; i < 4; ++i) part[i] += __shfl_xor(part[i], m, 64);
    }
    if (l15 == 0) {
#pragma unroll
        for (int i = 0; i < 4; ++i) score[e0 + lg * 4 + i] = part[i];
    }
}

// ---------------------------------------------------------------------------
// Softmax over all E scores
// ---------------------------------------------------------------------------
__device__ inline void online_merge(float& m, float& l, float om, float ol) {
    const float nm = fmaxf(m, om);
    l = l * __expf(m - nm) + ol * __expf(om - nm);
    m = nm;
}

__global__ __launch_bounds__(256) void softmax_part_kernel(
    const float* __restrict__ sc, int E,
    float* __restrict__ pm, float* __restrict__ pl)
{
    float m = -1e30f, l = 0.f;
    for (int i = blockIdx.x * 256 + threadIdx.x; i < E; i += gridDim.x * 256) {
        const float s = sc[i];
        const float nm = fmaxf(m, s);
        l = l * __expf(m - nm) + __expf(s - nm);
        m = nm;
    }
#pragma unroll
    for (int off = 1; off < 64; off <<= 1) {
        const float om = __shfl_xor(m, off, 64);
        const float ol = __shfl_xor(l, off, 64);
        online_merge(m, l, om, ol);
    }
    __shared__ float smm[4], sll[4];
    const int w = threadIdx.x >> 6, lane = threadIdx.x & 63;
    if (lane == 0) { smm[w] = m; sll[w] = l; }
    __syncthreads();
    if (threadIdx.x == 0) {
        float M = smm[0], L = sll[0];
        for (int i = 1; i < 4; ++i) online_merge(M, L, smm[i], sll[i]);
        pm[blockIdx.x] = M;
        pl[blockIdx.x] = L;
    }
}

__global__ __launch_bounds__(256) void softmax_final_kernel(
    const float* __restrict__ pm, const float* __restrict__ pl,
    float* __restrict__ ML)
{
    float m = pm[threadIdx.x];
    float l = pl[threadIdx.x];
#pragma unroll
    for (int off = 1; off < 64; off <<= 1) {
        const float om = __shfl_xor(m, off, 64);
        const float ol = __shfl_xor(l, off, 64);
        online_merge(m, l, om, ol);
    }
    __shared__ float smm[4], sll[4];
    const int w = threadIdx.x >> 6, lane = threadIdx.x & 63;
    if (lane == 0) { smm[w] = m; sll[w] = l; }
    __syncthreads();
    if (threadIdx.x == 0) {
        float M = smm[0], L = sll[0];
        for (int i = 1; i < 4; ++i) online_merge(M, L, smm[i], sll[i]);
        ML[0] = M;
        ML[1] = L;
    }
}

__global__ __launch_bounds__(256) void softmax_norm_kernel(
    float* __restrict__ sc, int E, const float* __restrict__ ML)
{
    const float M = ML[0];
    const float rL = 1.0f / ML[1];
    const int i = blockIdx.x * 256 + threadIdx.x;
    if (i < E) sc[i] = __expf(sc[i] - M) * rL;
}

// ---------------------------------------------------------------------------
// CSR build: count -> scan -> fill
// ---------------------------------------------------------------------------
__global__ __launch_bounds__(256) void csr_count_kernel(
    const int* __restrict__ ei_ab, const int* __restrict__ ei_aa,
    int* __restrict__ cntA, int* __restrict__ cntB)
{
    const int i = blockIdx.x * 256 + threadIdx.x;
    if (i < E_AB) {
        atomicAdd(&cntA[ei_ab[i]], 1);
        atomicAdd(&cntB[ei_ab[E_AB + i]], 1);
    }
    if (i < E_AA) {
        atomicAdd(&cntA[ei_aa[i]], 1);
    }
}

__global__ __launch_bounds__(1024) void csr_scan_kernel(
    int* __restrict__ cntA, int* __restrict__ offA,
    int* __restrict__ cntB, int* __restrict__ offB, int N)
{
    int* cnt = (blockIdx.x == 0) ? cntA : cntB;
    int* off = (blockIdx.x == 0) ? offA : offB;

    __shared__ int warpsum[16];
    const int t = threadIdx.x, lane = t & 63, w = t >> 6;
    int carry = 0;

    for (int base = 0; base < N; base += 1024) {
        const int i = base + t;
        const int v = (i < N) ? cnt[i] : 0;
        int x = v;
#pragma unroll
        for (int d = 1; d < 64; d <<= 1) {
            const int y = __shfl_up(x, d, 64);
            if (lane >= d) x += y;
        }
        if (lane == 63) warpsum[w] = x;
        __syncthreads();
        if (w == 0 && lane < 16) {
            int s = warpsum[lane];
#pragma unroll
            for (int d = 1; d < 16; d <<= 1) {
                const int y = __shfl_up(s, d, 64);
                if (lane >= d) s += y;
            }
            warpsum[lane] = s;
        }
        __syncthreads();
        const int excl = (x - v) + ((w > 0) ? warpsum[w - 1] : 0) + carry;
        if (i < N) { off[i] = excl; cnt[i] = excl; }
        carry += warpsum[15];
        __syncthreads();
    }
    if (t == 0) off[N] = carry;
}

__global__ __launch_bounds__(256) void csr_fill_kernel(
    const int* __restrict__ ei_ab, const int* __restrict__ ei_aa,
    const float* __restrict__ alAB, const float* __restrict__ alAA,
    int* __restrict__ curA, int* __restrict__ curB,
    int2* __restrict__ idxA, int2* __restrict__ idxB)
{
    const int i = blockIdx.x * 256 + threadIdx.x;
    if (i < E_AB) {
        const int s = ei_ab[i], d = ei_ab[E_AB + i];
        const int ab = __float_as_int(alAB[i]);
        const int pA = atomicAdd(&curA[s], 1);
        idxA[pA] = make_int2(d | (1 << 20), ab);
        const int pB = atomicAdd(&curB[d], 1);
        idxB[pB] = make_int2(s, ab);
    }
    if (i < E_AA) {
        const int s = ei_aa[i], d = ei_aa[E_AA + i];
        const int aa = __float_as_int(alAA[i]);
        const int pA = atomicAdd(&curA[s], 1);
        idxA[pA] = make_int2(d, aa);
    }
}

// ---------------------------------------------------------------------------
// f32 -> bf16 array conversion (8 elems/thread)
// ---------------------------------------------------------------------------
__global__ __launch_bounds__(256) void cvt_bf16_kernel(
    const float* __restrict__ X, ushort_t* __restrict__ Y, int n8)
{
    const int i = blockIdx.x * 256 + threadIdx.x;
    if (i >= n8) return;
    const float4 a = ((const float4*)X)[i * 2 + 0];
    const float4 b = ((const float4*)X)[i * 2 + 1];
    uint4 o;
    o.x = (uint_t)bf16r(a.x) | ((uint_t)bf16r(a.y) << 16);
    o.y = (uint_t)bf16r(a.z) | ((uint_t)bf16r(a.w) << 16);
    o.z = (uint_t)bf16r(b.x) | ((uint_t)bf16r(b.y) << 16);
    o.w = (uint_t)bf16r(b.z) | ((uint_t)bf16r(b.w) << 16);
    ((uint4*)Y)[i] = o;
}

// ---------------------------------------------------------------------------
// Gather: one 64-lane wave per destination node; bf16 neighbor features.
// acc init = exact f32 x_self row.
// ---------------------------------------------------------------------------
__global__ __launch_bounds__(256) void gather_kernel(
    const int*  __restrict__ off, const int2* __restrict__ idx,
    const ushort_t* __restrict__ xa16, const ushort_t* __restrict__ xb16,
    const float* __restrict__ xself, float* __restrict__ T, int N)
{
    const int wid  = (blockIdx.x * 256 + threadIdx.x) >> 6;
    const int lane = threadIdx.x & 63;
    if (wid >= N) return;

    const int beg = off[wid], end = off[wid + 1];
    float2 acc = *(const float2*)&xself[(size_t)wid * 128 + lane * 2];

    int e = beg;
    for (; e + 1 < end; e += 2) {
        const int2 e0 = idx[e];
        const int2 e1 = idx[e + 1];
        const float a0 = __int_as_float(e0.y);
        const float a1 = __int_as_float(e1.y);
        const ushort_t* s0 = (e0.x & (1 << 20)) ? &xb16[(size_t)(e0.x & 0xFFFFF) * 128]
                                                : &xa16[(size_t)(e0.x & 0xFFFFF) * 128];
        const ushort_t* s1 = (e1.x & (1 << 20)) ? &xb16[(size_t)(e1.x & 0xFFFFF) * 128]
                                                : &xa16[(size_t)(e1.x & 0xFFFFF) * 128];
        const ushort2 v0 = *(const ushort2*)&s0[lane * 2];
        const ushort2 v1 = *(const ushort2*)&s1[lane * 2];
        acc.x -= a0 * bf2f(v0.x) + a1 * bf2f(v1.x);
        acc.y -= a0 * bf2f(v0.y) + a1 * bf2f(v1.y);
    }
    if (e < end) {
        const int2 e0 = idx[e];
        const float a0 = __int_as_float(e0.y);
        const ushort_t* s0 = (e0.x & (1 << 20)) ? &xb16[(size_t)(e0.x & 0xFFFFF) * 128]
                                                : &xa16[(size_t)(e0.x & 0xFFFFF) * 128];
        const ushort2 v0 = *(const ushort2*)&s0[lane * 2];
        acc.x -= a0 * bf2f(v0.x);
        acc.y -= a0 * bf2f(v0.y);
    }
    *(float2*)&T[(size_t)wid * 128 + lane * 2] = acc;
}

// ---------------------------------------------------------------------------
// Final residual transform, in place on T:  T <- T + T@F + b
// ---------------------------------------------------------------------------
__global__ __launch_bounds__(128) void final_kernel(
    float* __restrict__ T, const float* __restrict__ F,
    const float* __restrict__ fb, int N)
{
    const int j  = threadIdx.x;
    const int r0 = blockIdx.x * 8;

    float acc[8];
#pragma unroll
    for (int r = 0; r < 8; ++r) acc[r] = 0.f;

    for (int k = 0; k < 128; k += 4) {
        float f[4];
#pragma unroll
        for (int q = 0; q < 4; ++q) f[q] = F[(k + q) * 128 + j];
#pragma unroll
        for (int r = 0; r < 8; ++r) {
            const float4 xv = *(const float4*)&T[(size_t)(r0 + r) * 128 + k];
            acc[r] = fmaf(xv.x, f[0], fmaf(xv.y, f[1], fmaf(xv.z, f[2], fmaf(xv.w, f[3], acc[r]))));
        }
    }
    float told[8];
#pragma unroll
    for (int r = 0; r < 8; ++r) told[r] = T[(size_t)(r0 + r) * 128 + j];
    const float b = fb[j];
    __syncthreads();
#pragma unroll
    for (int r = 0; r < 8; ++r) {
        const int row = r0 + r;
        if (row < N) T[(size_t)row * 128 + j] = told[r] + b + acc[r];
    }
}

// ---------------------------------------------------------------------------
extern "C" void kernel_launch(void* const* d_in, const int* in_sizes, int n_in,
                              void* d_out, int out_size, void* d_ws, size_t ws_size,
                              hipStream_t stream)
{
    const float* x_a   = (const float*)d_in[0];
    const float* x_b   = (const float*)d_in[1];
    const int*   ei_ab = (const int*)d_in[2];
    const float* ea_ab = (const float*)d_in[3];
    const int*   ei_aa = (const int*)d_in[4];
    const float* ea_aa = (const float*)d_in[5];
    const float* Wh_w  = (const float*)d_in[6];
    const float* Wh_b  = (const float*)d_in[7];
    const float* Wn_w  = (const float*)d_in[8];
    const float* Wn_b  = (const float*)d_in[9];
    const float* w_e   = (const float*)d_in[10];
    const float* ft_w  = (const float*)d_in[11];
    const float* ft_b  = (const float*)d_in[12];

    float* out = (float*)d_out;
    float* ws  = (float*)d_ws;

    // ws layout (floats):
    //   P1 [0 .. 6.4M)          -- after edge scores: reused for CSR
    //   P2a[6.4M .. 12.8M)      -- after edge scores: reused for xa16/xb16
    //   P2b[12.8M .. 19.2M)
    //   RED[19.2M .. 19.2M+2048)
    //   Bhi/Blo [19.2M+2048 .. +8192 ushorts]
    float* P1  = ws;
    float* P2a = ws + 6400000;
    float* P2b = ws + 12800000;
    float* RED = ws + 19200000;
    float* pm_ab = RED;        float* pl_ab = RED + 256;
    float* pm_aa = RED + 512;  float* pl_aa = RED + 768;
    float* ML_ab = RED + 1024; float* ML_aa = RED + 1026;
    ushort_t* Bhi = (ushort_t*)(ws + 19202048);          // 8192 ushorts
    ushort_t* Blo = Bhi + 8192;                          // 8192 ushorts

    // CSR region (P1 dead after edge scores)
    int*  curA = (int*)ws;
    int*  curB = (int*)ws + 50000;
    int*  offA = (int*)ws + 100352;
    int*  offB = (int*)ws + 150528;
    int2* idxA = (int2*)((int*)ws + 200704);   // 640000 entries
    int2* idxB = (int2*)((int*)ws + 1480704);  // 320000 entries

    // bf16 x copies (P2a dead after edge scores): 3.2M floats each
    ushort_t* xa16 = (ushort_t*)P2a;
    ushort_t* xb16 = (ushort_t*)(P2a + 3200000);

    // d_out layout: out_a[6.4M] out_b[6.4M] alpha_ab[320K] alpha_aa[320K]
    float* TA   = out;
    float* TB   = out + 6400000;
    float* alAB = out + 12800000;
    float* alAA = out + 13120000;

    // 0) pack Wh into bf16 hi/lo B-fragments
    prep_b_kernel<<<4, 256, 0, stream>>>(Wh_w, Bhi, Blo);

    // 1) node projections (f32)
    proj_dual_kernel<<<N_A / 8, 128, 0, stream>>>(x_a, Wn_w, Wh_b, Wn_b, P1, P2a, N_A);
    proj_single_kernel<<<N_B / 8, 128, 0, stream>>>(x_b, Wn_w + 128 * 128, P2b, N_B);

    // 2) edge scores via MFMA
    edge_score_mfma<<<E_AB / 64, 256, 0, stream>>>(ea_ab, ei_ab, P1, P2b, Bhi, Blo, w_e, alAB, E_AB);
    edge_score_mfma<<<E_AA / 64, 256, 0, stream>>>(ea_aa, ei_aa, P1, P2a, Bhi, Blo, w_e, alAA, E_AA);

    // 3) global softmax per edge type (in place)
    softmax_part_kernel<<<256, 256, 0, stream>>>(alAB, E_AB, pm_ab, pl_ab);
    softmax_final_kernel<<<1, 256, 0, stream>>>(pm_ab, pl_ab, ML_ab);
    softmax_norm_kernel<<<(E_AB + 255) / 256, 256, 0, stream>>>(alAB, E_AB, ML_ab);
    softmax_part_kernel<<<256, 256, 0, stream>>>(alAA, E_AA, pm_aa, pl_aa);
    softmax_final_kernel<<<1, 256, 0, stream>>>(pm_aa, pl_aa, ML_aa);
    softmax_norm_kernel<<<(E_AA + 255) / 256, 256, 0, stream>>>(alAA, E_AA, ML_aa);

    // 4) CSR build (P1 region is dead now)
    hipMemsetAsync(curA, 0, 100000 * sizeof(int), stream);
    csr_count_kernel<<<(E_AB + 255) / 256, 256, 0, stream>>>(ei_ab, ei_aa, curA, curB);
    csr_scan_kernel<<<2, 1024, 0, stream>>>(curA, offA, curB, offB, N_A);
    csr_fill_kernel<<<(E_AB + 255) / 256, 256, 0, stream>>>(ei_ab, ei_aa, alAB, alAA,
                                                            curA, curB, idxA, idxB);

    // 5) bf16 copies of x (P2a region dead now), then gather
    cvt_bf16_kernel<<<(800000 + 255) / 256, 256, 0, stream>>>(x_a, xa16, 800000);
    cvt_bf16_kernel<<<(800000 + 255) / 256, 256, 0, stream>>>(x_b, xb16, 800000);
    gather_kernel<<<(N_A + 3) / 4, 256, 0, stream>>>(offA, idxA, xa16, xb16, x_a, TA, N_A);
    gather_kernel<<<(N_B + 3) / 4, 256, 0, stream>>>(offB, idxB, xa16, xb16, x_b, TB, N_B);

    // 6) out = t + t@F + b  (in place)
    final_kernel<<<N_A / 8, 128, 0, stream>>>(TA, ft_w, ft_b, N_A);
    final_kernel<<<N_B / 8, 128, 0, stream>>>(TB, ft_w, ft_b, N_B);

    (void)in_sizes; (void)n_in; (void)out_size; (void)ws_size;
}

// Round 4
// 505.026 us; speedup vs baseline: 2.4844x; 1.2125x over previous
//
#include <hip/hip_runtime.h>
#include <cstdint>
#include <cstddef>

// Problem constants (fixed by the reference)
#define N_A   50000
#define N_B   50000
#define E_AB  320000
#define E_AA  320000
#define IN_DIM 128
#define HID    128
#define ED     64

using bf16x8 = __attribute__((ext_vector_type(8))) short;
using f32x4  = __attribute__((ext_vector_type(4))) float;
typedef unsigned short ushort_t;
typedef unsigned int   uint_t;

__device__ inline ushort_t bf16r(float f) {   // f32 -> bf16 bits, RNE
    uint_t u = __float_as_uint(f);
    u = (u + 0x7FFF + ((u >> 16) & 1)) >> 16;
    return (ushort_t)u;
}
__device__ inline float bf2f(ushort_t h) {
    return __uint_as_float(((uint_t)h) << 16);
}

// ---------------------------------------------------------------------------
// Pre-pack ALL weights into bf16 hi/lo MFMA B-fragments.
// B frag (16x16x32): lane holds col = ct*16 + (lane&15), k = kt*32 + (lane>>4)*8 + j
// Fragment index within a weight set: f = ct*KT + kt; storage (f*64+lane)*8+j.
// Sets: Wh (KT=2, 16 frags), W1=Wn[0:128] (KT=4, 32), W2=Wn[128:256] (KT=4, 32),
//       FT=ft_w (KT=4, 32).  One wave per fragment, 112 blocks.
// ---------------------------------------------------------------------------
__global__ __launch_bounds__(64) void prep_w_all(
    const float* __restrict__ Wh, const float* __restrict__ W1,
    const float* __restrict__ W2, const float* __restrict__ FT,
    ushort_t* __restrict__ BhWh, ushort_t* __restrict__ BlWh,
    ushort_t* __restrict__ BhW1, ushort_t* __restrict__ BlW1,
    ushort_t* __restrict__ BhW2, ushort_t* __restrict__ BlW2,
    ushort_t* __restrict__ BhFT, ushort_t* __restrict__ BlFT)
{
    const int f = blockIdx.x;
    const int lane = threadIdx.x;
    const float* W; ushort_t *oh, *ol; int KT, fl;
    if (f < 16)      { W = Wh; oh = BhWh; ol = BlWh; KT = 2; fl = f; }
    else if (f < 48) { W = W1; oh = BhW1; ol = BlW1; KT = 4; fl = f - 16; }
    else if (f < 80) { W = W2; oh = BhW2; ol = BlW2; KT = 4; fl = f - 48; }
    else             { W = FT; oh = BhFT; ol = BlFT; KT = 4; fl = f - 80; }
    const int ct = fl / KT, kt = fl % KT;
    const int col = ct * 16 + (lane & 15);
    const int kb  = kt * 32 + (lane >> 4) * 8;
#pragma unroll
    for (int j = 0; j < 8; ++j) {
        const float v = W[(kb + j) * 128 + col];
        const ushort_t h = bf16r(v);
        oh[(size_t)(fl * 64 + lane) * 8 + j] = h;
        ol[(size_t)(fl * 64 + lane) * 8 + j] = bf16r(v - bf2f(h));
    }
}

// ---------------------------------------------------------------------------
// Load a row's A-fragments (4 k-tiles, hi/lo split) for 16x16x32 bf16 MFMA.
// ---------------------------------------------------------------------------
__device__ inline void load_a_frags(const float* __restrict__ rowp, int lg,
                                    bf16x8* ahi, bf16x8* alo)
{
#pragma unroll
    for (int kt = 0; kt < 4; ++kt) {
        float v[8];
        *(float4*)(v + 0) = *(const float4*)(rowp + kt * 32 + lg * 8);
        *(float4*)(v + 4) = *(const float4*)(rowp + kt * 32 + lg * 8 + 4);
#pragma unroll
        for (int j = 0; j < 8; ++j) {
            const ushort_t h = bf16r(v[j]);
            ahi[kt][j] = (short)h;
            alo[kt][j] = (short)bf16r(v[j] - bf2f(h));
        }
    }
}

// ---------------------------------------------------------------------------
// proj_dual: P1 = X@W1 + (bh+bn), P2 = X@W2   (X = x_a), via split MFMA.
// 4 waves/block, 16 rows/wave.
// ---------------------------------------------------------------------------
__global__ __launch_bounds__(256) void proj_dual_mfma(
    const float* __restrict__ X,
    const ushort_t* __restrict__ B1h, const ushort_t* __restrict__ B1l,
    const ushort_t* __restrict__ B2h, const ushort_t* __restrict__ B2l,
    const float* __restrict__ bh, const float* __restrict__ bn,
    float* __restrict__ P1, float* __restrict__ P2, int N)
{
    const int lane = threadIdx.x & 63;
    const int l15 = lane & 15, lg = lane >> 4;
    const int r0 = blockIdx.x * 64 + (threadIdx.x >> 6) * 16;
    const int arow = (r0 + l15 < N) ? (r0 + l15) : (N - 1);

    bf16x8 ahi[4], alo[4];
    load_a_frags(&X[(size_t)arow * 128], lg, ahi, alo);

    f32x4 acc1[8], acc2[8];
#pragma unroll
    for (int ct = 0; ct < 8; ++ct) {
        const float b = bh[ct * 16 + l15] + bn[ct * 16 + l15];
        acc1[ct] = (f32x4){b, b, b, b};
        acc2[ct] = (f32x4){0.f, 0.f, 0.f, 0.f};
    }

#pragma unroll
    for (int ct = 0; ct < 8; ++ct) {
#pragma unroll
        for (int kt = 0; kt < 4; ++kt) {
            const size_t fo = (size_t)((ct * 4 + kt) * 64 + lane) * 8;
            const bf16x8 b1h = *(const bf16x8*)&B1h[fo];
            const bf16x8 b1l = *(const bf16x8*)&B1l[fo];
            const bf16x8 b2h = *(const bf16x8*)&B2h[fo];
            const bf16x8 b2l = *(const bf16x8*)&B2l[fo];
            acc1[ct] = __builtin_amdgcn_mfma_f32_16x16x32_bf16(ahi[kt], b1h, acc1[ct], 0, 0, 0);
            acc1[ct] = __builtin_amdgcn_mfma_f32_16x16x32_bf16(alo[kt], b1h, acc1[ct], 0, 0, 0);
            acc1[ct] = __builtin_amdgcn_mfma_f32_16x16x32_bf16(ahi[kt], b1l, acc1[ct], 0, 0, 0);
            acc2[ct] = __builtin_amdgcn_mfma_f32_16x16x32_bf16(ahi[kt], b2h, acc2[ct], 0, 0, 0);
            acc2[ct] = __builtin_amdgcn_mfma_f32_16x16x32_bf16(alo[kt], b2h, acc2[ct], 0, 0, 0);
            acc2[ct] = __builtin_amdgcn_mfma_f32_16x16x32_bf16(ahi[kt], b2l, acc2[ct], 0, 0, 0);
        }
    }
    // C layout: col = l15, row = lg*4 + i
#pragma unroll
    for (int ct = 0; ct < 8; ++ct) {
#pragma unroll
        for (int i = 0; i < 4; ++i) {
            const int row = r0 + lg * 4 + i;
            if (row < N) {
                P1[(size_t)row * 128 + ct * 16 + l15] = acc1[ct][i];
                P2[(size_t)row * 128 + ct * 16 + l15] = acc2[ct][i];
            }
        }
    }
}

// proj_single: P = X@W (no bias), X = x_b, W = W2.
__global__ __launch_bounds__(256) void proj_single_mfma(
    const float* __restrict__ X,
    const ushort_t* __restrict__ Bh, const ushort_t* __restrict__ Bl,
    float* __restrict__ P, int N)
{
    const int lane = threadIdx.x & 63;
    const int l15 = lane & 15, lg = lane >> 4;
    const int r0 = blockIdx.x * 64 + (threadIdx.x >> 6) * 16;
    const int arow = (r0 + l15 < N) ? (r0 + l15) : (N - 1);

    bf16x8 ahi[4], alo[4];
    load_a_frags(&X[(size_t)arow * 128], lg, ahi, alo);

    f32x4 acc[8];
#pragma unroll
    for (int ct = 0; ct < 8; ++ct) acc[ct] = (f32x4){0.f, 0.f, 0.f, 0.f};

#pragma unroll
    for (int ct = 0; ct < 8; ++ct) {
#pragma unroll
        for (int kt = 0; kt < 4; ++kt) {
            const size_t fo = (size_t)((ct * 4 + kt) * 64 + lane) * 8;
            const bf16x8 bhf = *(const bf16x8*)&Bh[fo];
            const bf16x8 blf = *(const bf16x8*)&Bl[fo];
            acc[ct] = __builtin_amdgcn_mfma_f32_16x16x32_bf16(ahi[kt], bhf, acc[ct], 0, 0, 0);
            acc[ct] = __builtin_amdgcn_mfma_f32_16x16x32_bf16(alo[kt], bhf, acc[ct], 0, 0, 0);
            acc[ct] = __builtin_amdgcn_mfma_f32_16x16x32_bf16(ahi[kt], blf, acc[ct], 0, 0, 0);
        }
    }
#pragma unroll
    for (int ct = 0; ct < 8; ++ct) {
#pragma unroll
        for (int i = 0; i < 4; ++i) {
            const int row = r0 + lg * 4 + i;
            if (row < N) P[(size_t)row * 128 + ct * 16 + l15] = acc[ct][i];
        }
    }
}

// final: T <- T + T@FT + fb, in place. acc init = T[row][col] + fb[col].
__global__ __launch_bounds__(256) void final_mfma(
    float* __restrict__ T,
    const ushort_t* __restrict__ Bh, const ushort_t* __restrict__ Bl,
    const float* __restrict__ fb, int N)
{
    const int lane = threadIdx.x & 63;
    const int l15 = lane & 15, lg = lane >> 4;
    const int r0 = blockIdx.x * 64 + (threadIdx.x >> 6) * 16;
    const int arow = (r0 + l15 < N) ? (r0 + l15) : (N - 1);

    bf16x8 ahi[4], alo[4];
    load_a_frags(&T[(size_t)arow * 128], lg, ahi, alo);

    f32x4 acc[8];
#pragma unroll
    for (int ct = 0; ct < 8; ++ct) {
        const float b = fb[ct * 16 + l15];
#pragma unroll
        for (int i = 0; i < 4; ++i) {
            const int row = r0 + lg * 4 + i;
            const int rr = (row < N) ? row : (N - 1);
            acc[ct][i] = T[(size_t)rr * 128 + ct * 16 + l15] + b;
        }
    }

#pragma unroll
    for (int ct = 0; ct < 8; ++ct) {
#pragma unroll
        for (int kt = 0; kt < 4; ++kt) {
            const size_t fo = (size_t)((ct * 4 + kt) * 64 + lane) * 8;
            const bf16x8 bhf = *(const bf16x8*)&Bh[fo];
            const bf16x8 blf = *(const bf16x8*)&Bl[fo];
            acc[ct] = __builtin_amdgcn_mfma_f32_16x16x32_bf16(ahi[kt], bhf, acc[ct], 0, 0, 0);
            acc[ct] = __builtin_amdgcn_mfma_f32_16x16x32_bf16(alo[kt], bhf, acc[ct], 0, 0, 0);
            acc[ct] = __builtin_amdgcn_mfma_f32_16x16x32_bf16(ahi[kt], blf, acc[ct], 0, 0, 0);
        }
    }
#pragma unroll
    for (int ct = 0; ct < 8; ++ct) {
#pragma unroll
        for (int i = 0; i < 4; ++i) {
            const int row = r0 + lg * 4 + i;
            if (row < N) T[(size_t)row * 128 + ct * 16 + l15] = acc[ct][i];
        }
    }
}

// ---------------------------------------------------------------------------
// Edge score via MFMA (bf16x2 split => ~f32 accuracy)
// ---------------------------------------------------------------------------
__global__ __launch_bounds__(256) void edge_score_mfma(
    const float* __restrict__ ea,    // [E][64]
    const int*   __restrict__ ei,    // [2][E]
    const float* __restrict__ P1,
    const float* __restrict__ P2,
    const ushort_t* __restrict__ Bhi,
    const ushort_t* __restrict__ Blo,
    const float* __restrict__ we,
    float* __restrict__ score, int E)
{
    const int t    = threadIdx.x;
    const int lane = t & 63;
    const int l15  = lane & 15;
    const int lg   = lane >> 4;
    const int e0   = blockIdx.x * 64 + (t >> 6) * 16;

    const float* arow = &ea[(size_t)(e0 + l15) * 64 + lg * 8];
    float af[16];
    *(float4*)(af + 0)  = *(const float4*)(arow + 0);
    *(float4*)(af + 4)  = *(const float4*)(arow + 4);
    *(float4*)(af + 8)  = *(const float4*)(arow + 32);
    *(float4*)(af + 12) = *(const float4*)(arow + 36);

    bf16x8 ahi0, alo0, ahi1, alo1;
#pragma unroll
    for (int j = 0; j < 8; ++j) {
        const ushort_t h0 = bf16r(af[j]);
        ahi0[j] = (short)h0;
        alo0[j] = (short)bf16r(af[j] - bf2f(h0));
        const ushort_t h1 = bf16r(af[8 + j]);
        ahi1[j] = (short)h1;
        alo1[j] = (short)bf16r(af[8 + j] - bf2f(h1));
    }

    f32x4 acc[8];
#pragma unroll
    for (int ct = 0; ct < 8; ++ct) acc[ct] = (f32x4){0.f, 0.f, 0.f, 0.f};

#pragma unroll
    for (int ct = 0; ct < 8; ++ct) {
        const bf16x8 bh0 = *(const bf16x8*)&Bhi[(size_t)(ct * 2 + 0) * 512 + lane * 8];
        const bf16x8 bl0 = *(const bf16x8*)&Blo[(size_t)(ct * 2 + 0) * 512 + lane * 8];
        const bf16x8 bh1 = *(const bf16x8*)&Bhi[(size_t)(ct * 2 + 1) * 512 + lane * 8];
        const bf16x8 bl1 = *(const bf16x8*)&Blo[(size_t)(ct * 2 + 1) * 512 + lane * 8];
        acc[ct] = __builtin_amdgcn_mfma_f32_16x16x32_bf16(ahi0, bh0, acc[ct], 0, 0, 0);
        acc[ct] = __builtin_amdgcn_mfma_f32_16x16x32_bf16(alo0, bh0, acc[ct], 0, 0, 0);
        acc[ct] = __builtin_amdgcn_mfma_f32_16x16x32_bf16(ahi0, bl0, acc[ct], 0, 0, 0);
        acc[ct] = __builtin_amdgcn_mfma_f32_16x16x32_bf16(ahi1, bh1, acc[ct], 0, 0, 0);
        acc[ct] = __builtin_amdgcn_mfma_f32_16x16x32_bf16(alo1, bh1, acc[ct], 0, 0, 0);
        acc[ct] = __builtin_amdgcn_mfma_f32_16x16x32_bf16(ahi1, bl1, acc[ct], 0, 0, 0);
    }

    int sidx[4], didx[4];
#pragma unroll
    for (int i = 0; i < 4; ++i) {
        const int e = e0 + lg * 4 + i;
        sidx[i] = ei[e];
        didx[i] = ei[(size_t)E + e];
    }

    float part[4] = {0.f, 0.f, 0.f, 0.f};
#pragma unroll
    for (int ct = 0; ct < 8; ++ct) {
        const float wv = we[ct * 16 + l15];
#pragma unroll
        for (int i = 0; i < 4; ++i) {
            const float h = acc[ct][i]
                          + P1[(size_t)sidx[i] * 128 + ct * 16 + l15]
                          + P2[(size_t)didx[i] * 128 + ct * 16 + l15];
            part[i] = fmaf(fmaxf(h, 0.f), wv, part[i]);
        }
    }
#pragma unroll
    for (int m = 8; m >= 1; m >>= 1) {
#pragma unroll
        for (int i = 0; i < 4; ++i) part[i] += __shfl_xor(part[i], m, 64);
    }
    if (l15 == 0) {
#pragma unroll
        for (int i = 0; i < 4; ++i) score[e0 + lg * 4 + i] = part[i];
    }
}

// ---------------------------------------------------------------------------
// Softmax over all E scores
// ---------------------------------------------------------------------------
__device__ inline void online_merge(float& m, float& l, float om, float ol) {
    const float nm = fmaxf(m, om);
    l = l * __expf(m - nm) + ol * __expf(om - nm);
    m = nm;
}

__global__ __launch_bounds__(256) void softmax_part_kernel(
    const float* __restrict__ sc, int E,
    float* __restrict__ pm, float* __restrict__ pl)
{
    float m = -1e30f, l = 0.f;
    for (int i = blockIdx.x * 256 + threadIdx.x; i < E; i += gridDim.x * 256) {
        const float s = sc[i];
        const float nm = fmaxf(m, s);
        l = l * __expf(m - nm) + __expf(s - nm);
        m = nm;
    }
#pragma unroll
    for (int off = 1; off < 64; off <<= 1) {
        const float om = __shfl_xor(m, off, 64);
        const float ol = __shfl_xor(l, off, 64);
        online_merge(m, l, om, ol);
    }
    __shared__ float smm[4], sll[4];
    const int w = threadIdx.x >> 6, lane = threadIdx.x & 63;
    if (lane == 0) { smm[w] = m; sll[w] = l; }
    __syncthreads();
    if (threadIdx.x == 0) {
        float M = smm[0], L = sll[0];
        for (int i = 1; i < 4; ++i) online_merge(M, L, smm[i], sll[i]);
        pm[blockIdx.x] = M;
        pl[blockIdx.x] = L;
    }
}

__global__ __launch_bounds__(256) void softmax_final_kernel(
    const float* __restrict__ pm, const float* __restrict__ pl,
    float* __restrict__ ML)
{
    float m = pm[threadIdx.x];
    float l = pl[threadIdx.x];
#pragma unroll
    for (int off = 1; off < 64; off <<= 1) {
        const float om = __shfl_xor(m, off, 64);
        const float ol = __shfl_xor(l, off, 64);
        online_merge(m, l, om, ol);
    }
    __shared__ float smm[4], sll[4];
    const int w = threadIdx.x >> 6, lane = threadIdx.x & 63;
    if (lane == 0) { smm[w] = m; sll[w] = l; }
    __syncthreads();
    if (threadIdx.x == 0) {
        float M = smm[0], L = sll[0];
        for (int i = 1; i < 4; ++i) online_merge(M, L, smm[i], sll[i]);
        ML[0] = M;
        ML[1] = L;
    }
}

__global__ __launch_bounds__(256) void softmax_norm_kernel(
    float* __restrict__ sc, int E, const float* __restrict__ ML)
{
    const float M = ML[0];
    const float rL = 1.0f / ML[1];
    const int i = blockIdx.x * 256 + threadIdx.x;
    if (i < E) sc[i] = __expf(sc[i] - M) * rL;
}

// ---------------------------------------------------------------------------
// CSR build: count -> scan -> fill
// ---------------------------------------------------------------------------
__global__ __launch_bounds__(256) void csr_count_kernel(
    const int* __restrict__ ei_ab, const int* __restrict__ ei_aa,
    int* __restrict__ cntA, int* __restrict__ cntB)
{
    const int i = blockIdx.x * 256 + threadIdx.x;
    if (i < E_AB) {
        atomicAdd(&cntA[ei_ab[i]], 1);
        atomicAdd(&cntB[ei_ab[E_AB + i]], 1);
    }
    if (i < E_AA) {
        atomicAdd(&cntA[ei_aa[i]], 1);
    }
}

__global__ __launch_bounds__(1024) void csr_scan_kernel(
    int* __restrict__ cntA, int* __restrict__ offA,
    int* __restrict__ cntB, int* __restrict__ offB, int N)
{
    int* cnt = (blockIdx.x == 0) ? cntA : cntB;
    int* off = (blockIdx.x == 0) ? offA : offB;

    __shared__ int warpsum[16];
    const int t = threadIdx.x, lane = t & 63, w = t >> 6;
    int carry = 0;

    for (int base = 0; base < N; base += 1024) {
        const int i = base + t;
        const int v = (i < N) ? cnt[i] : 0;
        int x = v;
#pragma unroll
        for (int d = 1; d < 64; d <<= 1) {
            const int y = __shfl_up(x, d, 64);
            if (lane >= d) x += y;
        }
        if (lane == 63) warpsum[w] = x;
        __syncthreads();
        if (w == 0 && lane < 16) {
            int s = warpsum[lane];
#pragma unroll
            for (int d = 1; d < 16; d <<= 1) {
                const int y = __shfl_up(s, d, 64);
                if (lane >= d) s += y;
            }
            warpsum[lane] = s;
        }
        __syncthreads();
        const int excl = (x - v) + ((w > 0) ? warpsum[w - 1] : 0) + carry;
        if (i < N) { off[i] = excl; cnt[i] = excl; }
        carry += warpsum[15];
        __syncthreads();
    }
    if (t == 0) off[N] = carry;
}

__global__ __launch_bounds__(256) void csr_fill_kernel(
    const int* __restrict__ ei_ab, const int* __restrict__ ei_aa,
    const float* __restrict__ alAB, const float* __restrict__ alAA,
    int* __restrict__ curA, int* __restrict__ curB,
    int2* __restrict__ idxA, int2* __restrict__ idxB)
{
    const int i = blockIdx.x * 256 + threadIdx.x;
    if (i < E_AB) {
        const int s = ei_ab[i], d = ei_ab[E_AB + i];
        const int ab = __float_as_int(alAB[i]);
        const int pA = atomicAdd(&curA[s], 1);
        idxA[pA] = make_int2(d | (1 << 20), ab);
        const int pB = atomicAdd(&curB[d], 1);
        idxB[pB] = make_int2(s, ab);
    }
    if (i < E_AA) {
        const int s = ei_aa[i], d = ei_aa[E_AA + i];
        const int aa = __float_as_int(alAA[i]);
        const int pA = atomicAdd(&curA[s], 1);
        idxA[pA] = make_int2(d, aa);
    }
}

// ---------------------------------------------------------------------------
// f32 -> bf16 array conversion (8 elems/thread)
// ---------------------------------------------------------------------------
__global__ __launch_bounds__(256) void cvt_bf16_kernel(
    const float* __restrict__ X, ushort_t* __restrict__ Y, int n8)
{
    const int i = blockIdx.x * 256 + threadIdx.x;
    if (i >= n8) return;
    const float4 a = ((const float4*)X)[i * 2 + 0];
    const float4 b = ((const float4*)X)[i * 2 + 1];
    uint4 o;
    o.x = (uint_t)bf16r(a.x) | ((uint_t)bf16r(a.y) << 16);
    o.y = (uint_t)bf16r(a.z) | ((uint_t)bf16r(a.w) << 16);
    o.z = (uint_t)bf16r(b.x) | ((uint_t)bf16r(b.y) << 16);
    o.w = (uint_t)bf16r(b.z) | ((uint_t)bf16r(b.w) << 16);
    ((uint4*)Y)[i] = o;
}

// ---------------------------------------------------------------------------
// Gather: one 64-lane wave per destination node; bf16 neighbor features.
// ---------------------------------------------------------------------------
__global__ __launch_bounds__(256) void gather_kernel(
    const int*  __restrict__ off, const int2* __restrict__ idx,
    const ushort_t* __restrict__ xa16, const ushort_t* __restrict__ xb16,
    const float* __restrict__ xself, float* __restrict__ T, int N)
{
    const int wid  = (blockIdx.x * 256 + threadIdx.x) >> 6;
    const int lane = threadIdx.x & 63;
    if (wid >= N) return;

    const int beg = off[wid], end = off[wid + 1];
    float2 acc = *(const float2*)&xself[(size_t)wid * 128 + lane * 2];

    int e = beg;
    for (; e + 1 < end; e += 2) {
        const int2 e0 = idx[e];
        const int2 e1 = idx[e + 1];
        const float a0 = __int_as_float(e0.y);
        const float a1 = __int_as_float(e1.y);
        const ushort_t* s0 = (e0.x & (1 << 20)) ? &xb16[(size_t)(e0.x & 0xFFFFF) * 128]
                                                : &xa16[(size_t)(e0.x & 0xFFFFF) * 128];
        const ushort_t* s1 = (e1.x & (1 << 20)) ? &xb16[(size_t)(e1.x & 0xFFFFF) * 128]
                                                : &xa16[(size_t)(e1.x & 0xFFFFF) * 128];
        const ushort2 v0 = *(const ushort2*)&s0[lane * 2];
        const ushort2 v1 = *(const ushort2*)&s1[lane * 2];
        acc.x -= a0 * bf2f(v0.x) + a1 * bf2f(v1.x);
        acc.y -= a0 * bf2f(v0.y) + a1 * bf2f(v1.y);
    }
    if (e < end) {
        const int2 e0 = idx[e];
        const float a0 = __int_as_float(e0.y);
        const ushort_t* s0 = (e0.x & (1 << 20)) ? &xb16[(size_t)(e0.x & 0xFFFFF) * 128]
                                                : &xa16[(size_t)(e0.x & 0xFFFFF) * 128];
        const ushort2 v0 = *(const ushort2*)&s0[lane * 2];
        acc.x -= a0 * bf2f(v0.x);
        acc.y -= a0 * bf2f(v0.y);
    }
    *(float2*)&T[(size_t)wid * 128 + lane * 2] = acc;
}

// ---------------------------------------------------------------------------
extern "C" void kernel_launch(void* const* d_in, const int* in_sizes, int n_in,
                              void* d_out, int out_size, void* d_ws, size_t ws_size,
                              hipStream_t stream)
{
    const float* x_a   = (const float*)d_in[0];
    const float* x_b   = (const float*)d_in[1];
    const int*   ei_ab = (const int*)d_in[2];
    const float* ea_ab = (const float*)d_in[3];
    const int*   ei_aa = (const int*)d_in[4];
    const float* ea_aa = (const float*)d_in[5];
    const float* Wh_w  = (const float*)d_in[6];
    const float* Wh_b  = (const float*)d_in[7];
    const float* Wn_w  = (const float*)d_in[8];
    const float* Wn_b  = (const float*)d_in[9];
    const float* w_e   = (const float*)d_in[10];
    const float* ft_w  = (const float*)d_in[11];
    const float* ft_b  = (const float*)d_in[12];

    float* out = (float*)d_out;
    float* ws  = (float*)d_ws;

    // ws layout (floats):
    //   P1 [0 .. 6.4M)          -- after edge scores: reused for CSR
    //   P2a[6.4M .. 12.8M)      -- after edge scores: reused for xa16/xb16
    //   P2b[12.8M .. 19.2M)
    //   RED[19.2M .. +2048)
    //   weight fragments after that (~230 KB)
    float* P1  = ws;
    float* P2a = ws + 6400000;
    float* P2b = ws + 12800000;
    float* RED = ws + 19200000;
    float* pm_ab = RED;        float* pl_ab = RED + 256;
    float* pm_aa = RED + 512;  float* pl_aa = RED + 768;
    float* ML_ab = RED + 1024; float* ML_aa = RED + 1026;

    ushort_t* FR   = (ushort_t*)(ws + 19202048);
    ushort_t* BhWh = FR;            // 16 frags * 512 = 8192
    ushort_t* BlWh = FR + 8192;
    ushort_t* BhW1 = FR + 16384;    // 32 frags * 512 = 16384
    ushort_t* BlW1 = FR + 32768;
    ushort_t* BhW2 = FR + 49152;
    ushort_t* BlW2 = FR + 65536;
    ushort_t* BhFT = FR + 81920;
    ushort_t* BlFT = FR + 98304;    // end 114688 ushorts

    // CSR region (P1 dead after edge scores)
    int*  curA = (int*)ws;
    int*  curB = (int*)ws + 50000;
    int*  offA = (int*)ws + 100352;
    int*  offB = (int*)ws + 150528;
    int2* idxA = (int2*)((int*)ws + 200704);   // 640000 entries
    int2* idxB = (int2*)((int*)ws + 1480704);  // 320000 entries

    // bf16 x copies (P2a dead after edge scores)
    ushort_t* xa16 = (ushort_t*)P2a;
    ushort_t* xb16 = (ushort_t*)(P2a + 3200000);

    // d_out layout: out_a[6.4M] out_b[6.4M] alpha_ab[320K] alpha_aa[320K]
    float* TA   = out;
    float* TB   = out + 6400000;
    float* alAB = out + 12800000;
    float* alAA = out + 13120000;

    // 0) pack all weights into bf16 hi/lo fragments
    prep_w_all<<<112, 64, 0, stream>>>(Wh_w, Wn_w, Wn_w + 128 * 128, ft_w,
                                       BhWh, BlWh, BhW1, BlW1, BhW2, BlW2, BhFT, BlFT);

    // 1) node projections via MFMA
    proj_dual_mfma<<<(N_A + 63) / 64, 256, 0, stream>>>(x_a, BhW1, BlW1, BhW2, BlW2,
                                                        Wh_b, Wn_b, P1, P2a, N_A);
    proj_single_mfma<<<(N_B + 63) / 64, 256, 0, stream>>>(x_b, BhW2, BlW2, P2b, N_B);

    // 2) edge scores via MFMA
    edge_score_mfma<<<E_AB / 64, 256, 0, stream>>>(ea_ab, ei_ab, P1, P2b, BhWh, BlWh, w_e, alAB, E_AB);
    edge_score_mfma<<<E_AA / 64, 256, 0, stream>>>(ea_aa, ei_aa, P1, P2a, BhWh, BlWh, w_e, alAA, E_AA);

    // 3) global softmax per edge type (in place)
    softmax_part_kernel<<<256, 256, 0, stream>>>(alAB, E_AB, pm_ab, pl_ab);
    softmax_final_kernel<<<1, 256, 0, stream>>>(pm_ab, pl_ab, ML_ab);
    softmax_norm_kernel<<<(E_AB + 255) / 256, 256, 0, stream>>>(alAB, E_AB, ML_ab);
    softmax_part_kernel<<<256, 256, 0, stream>>>(alAA, E_AA, pm_aa, pl_aa);
    softmax_final_kernel<<<1, 256, 0, stream>>>(pm_aa, pl_aa, ML_aa);
    softmax_norm_kernel<<<(E_AA + 255) / 256, 256, 0, stream>>>(alAA, E_AA, ML_aa);

    // 4) CSR build (P1 region is dead now)
    hipMemsetAsync(curA, 0, 100000 * sizeof(int), stream);
    csr_count_kernel<<<(E_AB + 255) / 256, 256, 0, stream>>>(ei_ab, ei_aa, curA, curB);
    csr_scan_kernel<<<2, 1024, 0, stream>>>(curA, offA, curB, offB, N_A);
    csr_fill_kernel<<<(E_AB + 255) / 256, 256, 0, stream>>>(ei_ab, ei_aa, alAB, alAA,
                                                            curA, curB, idxA, idxB);

    // 5) bf16 copies of x (P2a region dead now), then gather
    cvt_bf16_kernel<<<(800000 + 255) / 256, 256, 0, stream>>>(x_a, xa16, 800000);
    cvt_bf16_kernel<<<(800000 + 255) / 256, 256, 0, stream>>>(x_b, xb16, 800000);
    gather_kernel<<<(N_A + 3) / 4, 256, 0, stream>>>(offA, idxA, xa16, xb16, x_a, TA, N_A);
    gather_kernel<<<(N_B + 3) / 4, 256, 0, stream>>>(offB, idxB, xa16, xb16, x_b, TB, N_B);

    // 6) out = t + t@F + b  (in place, MFMA with folded residual+bias)
    final_mfma<<<(N_A + 63) / 64, 256, 0, stream>>>(TA, BhFT, BlFT, ft_b, N_A);
    final_mfma<<<(N_B + 63) / 64, 256, 0, stream>>>(TB, BhFT, BlFT, ft_b, N_B);

    (void)in_sizes; (void)n_in; (void)out_size; (void)ws_size;
}

// Round 5
// 383.696 us; speedup vs baseline: 3.2700x; 1.3162x over previous
//
#include <hip/hip_runtime.h>
#include <hip/hip_fp16.h>
#include <cstdint>
#include <cstddef>

// Problem constants (fixed by the reference)
#define N_A   50000
#define N_B   50000
#define E_AB  320000
#define E_AA  320000
#define IN_DIM 128
#define HID    128
#define ED     64

using bf16x8 = __attribute__((ext_vector_type(8))) short;
using f32x4  = __attribute__((ext_vector_type(4))) float;
typedef unsigned short ushort_t;
typedef unsigned int   uint_t;

__device__ inline ushort_t bf16r(float f) {   // f32 -> bf16 bits, RNE
    uint_t u = __float_as_uint(f);
    u = (u + 0x7FFF + ((u >> 16) & 1)) >> 16;
    return (ushort_t)u;
}
__device__ inline float bf2f(ushort_t h) {
    return __uint_as_float(((uint_t)h) << 16);
}
__device__ inline ushort_t f16r(float f) { return __half_as_ushort(__float2half_rn(f)); }
__device__ inline float f16f(ushort_t u) { return __half2float(__ushort_as_half(u)); }
__device__ inline uint_t packh2(float a, float b) {
    return (uint_t)f16r(a) | ((uint_t)f16r(b) << 16);
}

// ---------------------------------------------------------------------------
// Pre-pack all weights into bf16 hi/lo MFMA B-fragments + permuted w_e.
// B frag (16x16x32): lane holds col = ct*16 + (lane&15), k = kt*32 + (lane>>4)*8 + j
// Sets: Wh (KT=2, 16 frags), W1 (KT=4, 32), W2 (KT=4, 32), FT (KT=4, 32).
// Block 112: wep[l15*8+ct] = we[ct*16+l15].
// ---------------------------------------------------------------------------
__global__ __launch_bounds__(64) void prep_w_all(
    const float* __restrict__ Wh, const float* __restrict__ W1,
    const float* __restrict__ W2, const float* __restrict__ FT,
    const float* __restrict__ we,
    ushort_t* __restrict__ BhWh, ushort_t* __restrict__ BlWh,
    ushort_t* __restrict__ BhW1, ushort_t* __restrict__ BlW1,
    ushort_t* __restrict__ BhW2, ushort_t* __restrict__ BlW2,
    ushort_t* __restrict__ BhFT, ushort_t* __restrict__ BlFT,
    float* __restrict__ wep)
{
    const int f = blockIdx.x;
    const int lane = threadIdx.x;
    if (f == 112) {
#pragma unroll
        for (int q = 0; q < 2; ++q) {
            const int idx = lane + q * 64;
            const int l15 = idx >> 3, ct = idx & 7;
            wep[idx] = we[ct * 16 + l15];
        }
        return;
    }
    const float* W; ushort_t *oh, *ol; int KT, fl;
    if (f < 16)      { W = Wh; oh = BhWh; ol = BlWh; KT = 2; fl = f; }
    else if (f < 48) { W = W1; oh = BhW1; ol = BlW1; KT = 4; fl = f - 16; }
    else if (f < 80) { W = W2; oh = BhW2; ol = BlW2; KT = 4; fl = f - 48; }
    else             { W = FT; oh = BhFT; ol = BlFT; KT = 4; fl = f - 80; }
    const int ct = fl / KT, kt = fl % KT;
    const int col = ct * 16 + (lane & 15);
    const int kb  = kt * 32 + (lane >> 4) * 8;
#pragma unroll
    for (int j = 0; j < 8; ++j) {
        const float v = W[(kb + j) * 128 + col];
        const ushort_t h = bf16r(v);
        oh[(size_t)(fl * 64 + lane) * 8 + j] = h;
        ol[(size_t)(fl * 64 + lane) * 8 + j] = bf16r(v - bf2f(h));
    }
}

// ---------------------------------------------------------------------------
// proj_dual: P1 = x_a@W1 + (bh+bn), P2 = x_a@W2, stored f16 in layout
// P[row*128 + l15*8 + ct]. Also emits f16 copy of x_a (xa16, row-linear).
// ---------------------------------------------------------------------------
__global__ __launch_bounds__(256) void proj_dual_mfma(
    const float* __restrict__ X,
    const ushort_t* __restrict__ B1h, const ushort_t* __restrict__ B1l,
    const ushort_t* __restrict__ B2h, const ushort_t* __restrict__ B2l,
    const float* __restrict__ bh, const float* __restrict__ bn,
    ushort_t* __restrict__ P1, ushort_t* __restrict__ P2,
    ushort_t* __restrict__ X16, int N)
{
    const int lane = threadIdx.x & 63;
    const int l15 = lane & 15, lg = lane >> 4;
    const int r0 = blockIdx.x * 64 + (threadIdx.x >> 6) * 16;
    const int arow = (r0 + l15 < N) ? (r0 + l15) : (N - 1);

    bf16x8 ahi[4], alo[4];
#pragma unroll
    for (int kt = 0; kt < 4; ++kt) {
        float v[8];
        *(float4*)(v + 0) = *(const float4*)&X[(size_t)arow * 128 + kt * 32 + lg * 8];
        *(float4*)(v + 4) = *(const float4*)&X[(size_t)arow * 128 + kt * 32 + lg * 8 + 4];
        uint4 xu;
        xu.x = packh2(v[0], v[1]); xu.y = packh2(v[2], v[3]);
        xu.z = packh2(v[4], v[5]); xu.w = packh2(v[6], v[7]);
        *(uint4*)&X16[(size_t)arow * 128 + kt * 32 + lg * 8] = xu;
#pragma unroll
        for (int j = 0; j < 8; ++j) {
            const ushort_t h = bf16r(v[j]);
            ahi[kt][j] = (short)h;
            alo[kt][j] = (short)bf16r(v[j] - bf2f(h));
        }
    }

    f32x4 acc1[8], acc2[8];
#pragma unroll
    for (int ct = 0; ct < 8; ++ct) {
        const float b = bh[ct * 16 + l15] + bn[ct * 16 + l15];
        acc1[ct] = (f32x4){b, b, b, b};
        acc2[ct] = (f32x4){0.f, 0.f, 0.f, 0.f};
    }

#pragma unroll
    for (int ct = 0; ct < 8; ++ct) {
#pragma unroll
        for (int kt = 0; kt < 4; ++kt) {
            const size_t fo = (size_t)((ct * 4 + kt) * 64 + lane) * 8;
            const bf16x8 b1h = *(const bf16x8*)&B1h[fo];
            const bf16x8 b1l = *(const bf16x8*)&B1l[fo];
            const bf16x8 b2h = *(const bf16x8*)&B2h[fo];
            const bf16x8 b2l = *(const bf16x8*)&B2l[fo];
            acc1[ct] = __builtin_amdgcn_mfma_f32_16x16x32_bf16(ahi[kt], b1h, acc1[ct], 0, 0, 0);
            acc1[ct] = __builtin_amdgcn_mfma_f32_16x16x32_bf16(alo[kt], b1h, acc1[ct], 0, 0, 0);
            acc1[ct] = __builtin_amdgcn_mfma_f32_16x16x32_bf16(ahi[kt], b1l, acc1[ct], 0, 0, 0);
            acc2[ct] = __builtin_amdgcn_mfma_f32_16x16x32_bf16(ahi[kt], b2h, acc2[ct], 0, 0, 0);
            acc2[ct] = __builtin_amdgcn_mfma_f32_16x16x32_bf16(alo[kt], b2h, acc2[ct], 0, 0, 0);
            acc2[ct] = __builtin_amdgcn_mfma_f32_16x16x32_bf16(ahi[kt], b2l, acc2[ct], 0, 0, 0);
        }
    }
    // C layout: col = ct*16+l15, row = r0 + lg*4 + i  -> store interleaved f16
#pragma unroll
    for (int i = 0; i < 4; ++i) {
        const int row = r0 + lg * 4 + i;
        if (row < N) {
            uint4 u1, u2;
            u1.x = packh2(acc1[0][i], acc1[1][i]); u1.y = packh2(acc1[2][i], acc1[3][i]);
            u1.z = packh2(acc1[4][i], acc1[5][i]); u1.w = packh2(acc1[6][i], acc1[7][i]);
            u2.x = packh2(acc2[0][i], acc2[1][i]); u2.y = packh2(acc2[2][i], acc2[3][i]);
            u2.z = packh2(acc2[4][i], acc2[5][i]); u2.w = packh2(acc2[6][i], acc2[7][i]);
            *(uint4*)&P1[(size_t)row * 128 + l15 * 8] = u1;
            *(uint4*)&P2[(size_t)row * 128 + l15 * 8] = u2;
        }
    }
}

// proj_single: P = x_b@W2 (no bias), f16 interleaved; emits xb16.
__global__ __launch_bounds__(256) void proj_single_mfma(
    const float* __restrict__ X,
    const ushort_t* __restrict__ Bh, const ushort_t* __restrict__ Bl,
    ushort_t* __restrict__ P, ushort_t* __restrict__ X16, int N)
{
    const int lane = threadIdx.x & 63;
    const int l15 = lane & 15, lg = lane >> 4;
    const int r0 = blockIdx.x * 64 + (threadIdx.x >> 6) * 16;
    const int arow = (r0 + l15 < N) ? (r0 + l15) : (N - 1);

    bf16x8 ahi[4], alo[4];
#pragma unroll
    for (int kt = 0; kt < 4; ++kt) {
        float v[8];
        *(float4*)(v + 0) = *(const float4*)&X[(size_t)arow * 128 + kt * 32 + lg * 8];
        *(float4*)(v + 4) = *(const float4*)&X[(size_t)arow * 128 + kt * 32 + lg * 8 + 4];
        uint4 xu;
        xu.x = packh2(v[0], v[1]); xu.y = packh2(v[2], v[3]);
        xu.z = packh2(v[4], v[5]); xu.w = packh2(v[6], v[7]);
        *(uint4*)&X16[(size_t)arow * 128 + kt * 32 + lg * 8] = xu;
#pragma unroll
        for (int j = 0; j < 8; ++j) {
            const ushort_t h = bf16r(v[j]);
            ahi[kt][j] = (short)h;
            alo[kt][j] = (short)bf16r(v[j] - bf2f(h));
        }
    }

    f32x4 acc[8];
#pragma unroll
    for (int ct = 0; ct < 8; ++ct) acc[ct] = (f32x4){0.f, 0.f, 0.f, 0.f};

#pragma unroll
    for (int ct = 0; ct < 8; ++ct) {
#pragma unroll
        for (int kt = 0; kt < 4; ++kt) {
            const size_t fo = (size_t)((ct * 4 + kt) * 64 + lane) * 8;
            const bf16x8 bhf = *(const bf16x8*)&Bh[fo];
            const bf16x8 blf = *(const bf16x8*)&Bl[fo];
            acc[ct] = __builtin_amdgcn_mfma_f32_16x16x32_bf16(ahi[kt], bhf, acc[ct], 0, 0, 0);
            acc[ct] = __builtin_amdgcn_mfma_f32_16x16x32_bf16(alo[kt], bhf, acc[ct], 0, 0, 0);
            acc[ct] = __builtin_amdgcn_mfma_f32_16x16x32_bf16(ahi[kt], blf, acc[ct], 0, 0, 0);
        }
    }
#pragma unroll
    for (int i = 0; i < 4; ++i) {
        const int row = r0 + lg * 4 + i;
        if (row < N) {
            uint4 u;
            u.x = packh2(acc[0][i], acc[1][i]); u.y = packh2(acc[2][i], acc[3][i]);
            u.z = packh2(acc[4][i], acc[5][i]); u.w = packh2(acc[6][i], acc[7][i]);
            *(uint4*)&P[(size_t)row * 128 + l15 * 8] = u;
        }
    }
}

// final: T <- T + T@FT + fb, in place.
__global__ __launch_bounds__(256) void final_mfma(
    float* __restrict__ T,
    const ushort_t* __restrict__ Bh, const ushort_t* __restrict__ Bl,
    const float* __restrict__ fb, int N)
{
    const int lane = threadIdx.x & 63;
    const int l15 = lane & 15, lg = lane >> 4;
    const int r0 = blockIdx.x * 64 + (threadIdx.x >> 6) * 16;
    const int arow = (r0 + l15 < N) ? (r0 + l15) : (N - 1);

    bf16x8 ahi[4], alo[4];
#pragma unroll
    for (int kt = 0; kt < 4; ++kt) {
        float v[8];
        *(float4*)(v + 0) = *(const float4*)&T[(size_t)arow * 128 + kt * 32 + lg * 8];
        *(float4*)(v + 4) = *(const float4*)&T[(size_t)arow * 128 + kt * 32 + lg * 8 + 4];
#pragma unroll
        for (int j = 0; j < 8; ++j) {
            const ushort_t h = bf16r(v[j]);
            ahi[kt][j] = (short)h;
            alo[kt][j] = (short)bf16r(v[j] - bf2f(h));
        }
    }

    f32x4 acc[8];
#pragma unroll
    for (int ct = 0; ct < 8; ++ct) {
        const float b = fb[ct * 16 + l15];
#pragma unroll
        for (int i = 0; i < 4; ++i) {
            const int row = r0 + lg * 4 + i;
            const int rr = (row < N) ? row : (N - 1);
            acc[ct][i] = T[(size_t)rr * 128 + ct * 16 + l15] + b;
        }
    }

#pragma unroll
    for (int ct = 0; ct < 8; ++ct) {
#pragma unroll
        for (int kt = 0; kt < 4; ++kt) {
            const size_t fo = (size_t)((ct * 4 + kt) * 64 + lane) * 8;
            const bf16x8 bhf = *(const bf16x8*)&Bh[fo];
            const bf16x8 blf = *(const bf16x8*)&Bl[fo];
            acc[ct] = __builtin_amdgcn_mfma_f32_16x16x32_bf16(ahi[kt], bhf, acc[ct], 0, 0, 0);
            acc[ct] = __builtin_amdgcn_mfma_f32_16x16x32_bf16(alo[kt], bhf, acc[ct], 0, 0, 0);
            acc[ct] = __builtin_amdgcn_mfma_f32_16x16x32_bf16(ahi[kt], blf, acc[ct], 0, 0, 0);
        }
    }
#pragma unroll
    for (int ct = 0; ct < 8; ++ct) {
#pragma unroll
        for (int i = 0; i < 4; ++i) {
            const int row = r0 + lg * 4 + i;
            if (row < N) T[(size_t)row * 128 + ct * 16 + l15] = acc[ct][i];
        }
    }
}

// ---------------------------------------------------------------------------
// Edge score via MFMA; P tables f16 interleaved (one uint4 per lane per row).
// P loads hoisted before the MFMA block so latency hides under MFMA.
// ---------------------------------------------------------------------------
__global__ __launch_bounds__(256) void edge_score_mfma(
    const float* __restrict__ ea,     // [E][64]
    const int*   __restrict__ ei,     // [2][E]
    const ushort_t* __restrict__ P1h,
    const ushort_t* __restrict__ P2h,
    const ushort_t* __restrict__ Bhi,
    const ushort_t* __restrict__ Blo,
    const float* __restrict__ wep,    // permuted w_e: wep[l15*8+ct]
    float* __restrict__ score, int E)
{
    const int t    = threadIdx.x;
    const int lane = t & 63;
    const int l15  = lane & 15;
    const int lg   = lane >> 4;
    const int e0   = blockIdx.x * 64 + (t >> 6) * 16;

    int sidx[4], didx[4];
#pragma unroll
    for (int i = 0; i < 4; ++i) {
        const int e = e0 + lg * 4 + i;
        sidx[i] = ei[e];
        didx[i] = ei[(size_t)E + e];
    }
    uint4 p1u[4], p2u[4];
#pragma unroll
    for (int i = 0; i < 4; ++i) {
        p1u[i] = *(const uint4*)&P1h[(size_t)sidx[i] * 128 + l15 * 8];
        p2u[i] = *(const uint4*)&P2h[(size_t)didx[i] * 128 + l15 * 8];
    }

    const float* arow = &ea[(size_t)(e0 + l15) * 64 + lg * 8];
    float af[16];
    *(float4*)(af + 0)  = *(const float4*)(arow + 0);
    *(float4*)(af + 4)  = *(const float4*)(arow + 4);
    *(float4*)(af + 8)  = *(const float4*)(arow + 32);
    *(float4*)(af + 12) = *(const float4*)(arow + 36);

    bf16x8 ahi0, alo0, ahi1, alo1;
#pragma unroll
    for (int j = 0; j < 8; ++j) {
        const ushort_t h0 = bf16r(af[j]);
        ahi0[j] = (short)h0;
        alo0[j] = (short)bf16r(af[j] - bf2f(h0));
        const ushort_t h1 = bf16r(af[8 + j]);
        ahi1[j] = (short)h1;
        alo1[j] = (short)bf16r(af[8 + j] - bf2f(h1));
    }

    f32x4 acc[8];
#pragma unroll
    for (int ct = 0; ct < 8; ++ct) acc[ct] = (f32x4){0.f, 0.f, 0.f, 0.f};

#pragma unroll
    for (int ct = 0; ct < 8; ++ct) {
        const bf16x8 bh0 = *(const bf16x8*)&Bhi[(size_t)(ct * 2 + 0) * 512 + lane * 8];
        const bf16x8 bl0 = *(const bf16x8*)&Blo[(size_t)(ct * 2 + 0) * 512 + lane * 8];
        const bf16x8 bh1 = *(const bf16x8*)&Bhi[(size_t)(ct * 2 + 1) * 512 + lane * 8];
        const bf16x8 bl1 = *(const bf16x8*)&Blo[(size_t)(ct * 2 + 1) * 512 + lane * 8];
        acc[ct] = __builtin_amdgcn_mfma_f32_16x16x32_bf16(ahi0, bh0, acc[ct], 0, 0, 0);
        acc[ct] = __builtin_amdgcn_mfma_f32_16x16x32_bf16(alo0, bh0, acc[ct], 0, 0, 0);
        acc[ct] = __builtin_amdgcn_mfma_f32_16x16x32_bf16(ahi0, bl0, acc[ct], 0, 0, 0);
        acc[ct] = __builtin_amdgcn_mfma_f32_16x16x32_bf16(ahi1, bh1, acc[ct], 0, 0, 0);
        acc[ct] = __builtin_amdgcn_mfma_f32_16x16x32_bf16(alo1, bh1, acc[ct], 0, 0, 0);
        acc[ct] = __builtin_amdgcn_mfma_f32_16x16x32_bf16(ahi1, bl1, acc[ct], 0, 0, 0);
    }

    float w8[8];
    *(float4*)(w8 + 0) = *(const float4*)&wep[l15 * 8];
    *(float4*)(w8 + 4) = *(const float4*)&wep[l15 * 8 + 4];

    float part[4] = {0.f, 0.f, 0.f, 0.f};
#pragma unroll
    for (int i = 0; i < 4; ++i) {
        const uint_t* u1 = (const uint_t*)&p1u[i];
        const uint_t* u2 = (const uint_t*)&p2u[i];
#pragma unroll
        for (int q = 0; q < 4; ++q) {
            const float pa1 = f16f((ushort_t)(u1[q] & 0xFFFF));
            const float pb1 = f16f((ushort_t)(u1[q] >> 16));
            const float pa2 = f16f((ushort_t)(u2[q] & 0xFFFF));
            const float pb2 = f16f((ushort_t)(u2[q] >> 16));
            const float h0 = acc[2 * q][i] + pa1 + pa2;
            const float h1 = acc[2 * q + 1][i] + pb1 + pb2;
            part[i] = fmaf(fmaxf(h0, 0.f), w8[2 * q], part[i]);
            part[i] = fmaf(fmaxf(h1, 0.f), w8[2 * q + 1], part[i]);
        }
    }
#pragma unroll
    for (int m = 8; m >= 1; m >>= 1) {
#pragma unroll
        for (int i = 0; i < 4; ++i) part[i] += __shfl_xor(part[i], m, 64);
    }
    if (l15 == 0) {
#pragma unroll
        for (int i = 0; i < 4; ++i) score[e0 + lg * 4 + i] = part[i];
    }
}

// ---------------------------------------------------------------------------
// Softmax partials, both edge types in one launch (grid 512)
// ---------------------------------------------------------------------------
__device__ inline void online_merge(float& m, float& l, float om, float ol) {
    const float nm = fmaxf(m, om);
    l = l * __expf(m - nm) + ol * __expf(om - nm);
    m = nm;
}

__global__ __launch_bounds__(256) void softmax_part_kernel(
    const float* __restrict__ scAB, const float* __restrict__ scAA,
    float* __restrict__ pm, float* __restrict__ pl)
{
    const int type = blockIdx.x >> 8;
    const int b = blockIdx.x & 255;
    const float* sc = type ? scAA : scAB;
    float m = -1e30f, l = 0.f;
    for (int i = b * 256 + threadIdx.x; i < E_AB; i += 256 * 256) {
        const float s = sc[i];
        const float nm = fmaxf(m, s);
        l = l * __expf(m - nm) + __expf(s - nm);
        m = nm;
    }
#pragma unroll
    for (int off = 1; off < 64; off <<= 1) {
        const float om = __shfl_xor(m, off, 64);
        const float ol = __shfl_xor(l, off, 64);
        online_merge(m, l, om, ol);
    }
    __shared__ float smm[4], sll[4];
    const int w = threadIdx.x >> 6, lane = threadIdx.x & 63;
    if (lane == 0) { smm[w] = m; sll[w] = l; }
    __syncthreads();
    if (threadIdx.x == 0) {
        float M = smm[0], L = sll[0];
        for (int i = 1; i < 4; ++i) online_merge(M, L, smm[i], sll[i]);
        pm[blockIdx.x] = M;
        pl[blockIdx.x] = L;
    }
}

// grid 2: block 0 -> ML[0,1] (AB), block 1 -> ML[2,3] (AA)
__global__ __launch_bounds__(256) void softmax_final_kernel(
    const float* __restrict__ pm, const float* __restrict__ pl,
    float* __restrict__ ML)
{
    float m = pm[blockIdx.x * 256 + threadIdx.x];
    float l = pl[blockIdx.x * 256 + threadIdx.x];
#pragma unroll
    for (int off = 1; off < 64; off <<= 1) {
        const float om = __shfl_xor(m, off, 64);
        const float ol = __shfl_xor(l, off, 64);
        online_merge(m, l, om, ol);
    }
    __shared__ float smm[4], sll[4];
    const int w = threadIdx.x >> 6, lane = threadIdx.x & 63;
    if (lane == 0) { smm[w] = m; sll[w] = l; }
    __syncthreads();
    if (threadIdx.x == 0) {
        float M = smm[0], L = sll[0];
        for (int i = 1; i < 4; ++i) online_merge(M, L, smm[i], sll[i]);
        ML[blockIdx.x * 2]     = M;
        ML[blockIdx.x * 2 + 1] = L;
    }
}

// ---------------------------------------------------------------------------
// CSR: count (records per-edge rank) -> scan -> fill (atomic-free, fused norm)
// ---------------------------------------------------------------------------
__global__ __launch_bounds__(256) void csr_count_kernel(
    const int* __restrict__ ei_ab, const int* __restrict__ ei_aa,
    int* __restrict__ cntA, int* __restrict__ cntB,
    int* __restrict__ rkAab, int* __restrict__ rkBab, int* __restrict__ rkAaa)
{
    const int i = blockIdx.x * 256 + threadIdx.x;
    if (i < E_AB) {
        rkAab[i] = atomicAdd(&cntA[ei_ab[i]], 1);
        rkBab[i] = atomicAdd(&cntB[ei_ab[E_AB + i]], 1);
    }
    if (i < E_AA) {
        rkAaa[i] = atomicAdd(&cntA[ei_aa[i]], 1);
    }
}

__global__ __launch_bounds__(1024) void csr_scan_kernel(
    const int* __restrict__ cntA, int* __restrict__ offA,
    const int* __restrict__ cntB, int* __restrict__ offB, int N)
{
    const int* cnt = (blockIdx.x == 0) ? cntA : cntB;
    int* off = (blockIdx.x == 0) ? offA : offB;

    __shared__ int warpsum[16];
    const int t = threadIdx.x, lane = t & 63, w = t >> 6;
    int carry = 0;

    for (int base = 0; base < N; base += 1024) {
        const int i = base + t;
        const int v = (i < N) ? cnt[i] : 0;
        int x = v;
#pragma unroll
        for (int d = 1; d < 64; d <<= 1) {
            const int y = __shfl_up(x, d, 64);
            if (lane >= d) x += y;
        }
        if (lane == 63) warpsum[w] = x;
        __syncthreads();
        if (w == 0 && lane < 16) {
            int s = warpsum[lane];
#pragma unroll
            for (int d = 1; d < 16; d <<= 1) {
                const int y = __shfl_up(s, d, 64);
                if (lane >= d) s += y;
            }
            warpsum[lane] = s;
        }
        __syncthreads();
        const int excl = (x - v) + ((w > 0) ? warpsum[w - 1] : 0) + carry;
        if (i < N) off[i] = excl;
        carry += warpsum[15];
        __syncthreads();
    }
    if (t == 0) off[N] = carry;
}

// Atomic-free fill with fused softmax normalization.
// Reads raw scores + ML; writes normalized alpha (to d_out) and CSR entries.
__global__ __launch_bounds__(256) void csr_fill_kernel(
    const int* __restrict__ ei_ab, const int* __restrict__ ei_aa,
    float* __restrict__ scAB, float* __restrict__ scAA,
    const float* __restrict__ ML,
    const int* __restrict__ offA, const int* __restrict__ offB,
    const int* __restrict__ rkAab, const int* __restrict__ rkBab,
    const int* __restrict__ rkAaa,
    int2* __restrict__ idxA, int2* __restrict__ idxB)
{
    const int i = blockIdx.x * 256 + threadIdx.x;
    const float Mab = ML[0], rLab = 1.0f / ML[1];
    const float Maa = ML[2], rLaa = 1.0f / ML[3];
    if (i < E_AB) {
        const float a = __expf(scAB[i] - Mab) * rLab;
        scAB[i] = a;
        const int s = ei_ab[i], d = ei_ab[E_AB + i];
        const int ab = __float_as_int(a);
        idxA[offA[s] + rkAab[i]] = make_int2(d | (1 << 20), ab);
        idxB[offB[d] + rkBab[i]] = make_int2(s, ab);
    }
    if (i < E_AA) {
        const float a = __expf(scAA[i] - Maa) * rLaa;
        scAA[i] = a;
        const int s = ei_aa[i], d = ei_aa[E_AA + i];
        idxA[offA[s] + rkAaa[i]] = make_int2(d, __float_as_int(a));
    }
}

// ---------------------------------------------------------------------------
// Gather: one 64-lane wave per destination node; f16 neighbor features.
// ---------------------------------------------------------------------------
__global__ __launch_bounds__(256) void gather_kernel(
    const int*  __restrict__ off, const int2* __restrict__ idx,
    const ushort_t* __restrict__ xa16, const ushort_t* __restrict__ xb16,
    const float* __restrict__ xself, float* __restrict__ T, int N)
{
    const int wid  = (blockIdx.x * 256 + threadIdx.x) >> 6;
    const int lane = threadIdx.x & 63;
    if (wid >= N) return;

    const int beg = off[wid], end = off[wid + 1];
    float2 acc = *(const float2*)&xself[(size_t)wid * 128 + lane * 2];

    int e = beg;
    for (; e + 1 < end; e += 2) {
        const int2 e0 = idx[e];
        const int2 e1 = idx[e + 1];
        const float a0 = __int_as_float(e0.y);
        const float a1 = __int_as_float(e1.y);
        const ushort_t* s0 = (e0.x & (1 << 20)) ? &xb16[(size_t)(e0.x & 0xFFFFF) * 128]
                                                : &xa16[(size_t)(e0.x & 0xFFFFF) * 128];
        const ushort_t* s1 = (e1.x & (1 << 20)) ? &xb16[(size_t)(e1.x & 0xFFFFF) * 128]
                                                : &xa16[(size_t)(e1.x & 0xFFFFF) * 128];
        const ushort2 v0 = *(const ushort2*)&s0[lane * 2];
        const ushort2 v1 = *(const ushort2*)&s1[lane * 2];
        acc.x -= a0 * f16f(v0.x) + a1 * f16f(v1.x);
        acc.y -= a0 * f16f(v0.y) + a1 * f16f(v1.y);
    }
    if (e < end) {
        const int2 e0 = idx[e];
        const float a0 = __int_as_float(e0.y);
        const ushort_t* s0 = (e0.x & (1 << 20)) ? &xb16[(size_t)(e0.x & 0xFFFFF) * 128]
                                                : &xa16[(size_t)(e0.x & 0xFFFFF) * 128];
        const ushort2 v0 = *(const ushort2*)&s0[lane * 2];
        acc.x -= a0 * f16f(v0.x);
        acc.y -= a0 * f16f(v0.y);
    }
    *(float2*)&T[(size_t)wid * 128 + lane * 2] = acc;
}

// ---------------------------------------------------------------------------
extern "C" void kernel_launch(void* const* d_in, const int* in_sizes, int n_in,
                              void* d_out, int out_size, void* d_ws, size_t ws_size,
                              hipStream_t stream)
{
    const float* x_a   = (const float*)d_in[0];
    const float* x_b   = (const float*)d_in[1];
    const int*   ei_ab = (const int*)d_in[2];
    const float* ea_ab = (const float*)d_in[3];
    const int*   ei_aa = (const int*)d_in[4];
    const float* ea_aa = (const float*)d_in[5];
    const float* Wh_w  = (const float*)d_in[6];
    const float* Wh_b  = (const float*)d_in[7];
    const float* Wn_w  = (const float*)d_in[8];
    const float* Wn_b  = (const float*)d_in[9];
    const float* w_e   = (const float*)d_in[10];
    const float* ft_w  = (const float*)d_in[11];
    const float* ft_b  = (const float*)d_in[12];

    float* out = (float*)d_out;
    float* ws  = (float*)d_ws;

    // ws layout (4B units; all regions disjoint, no lifetime reuse):
    ushort_t* P1h  = (ushort_t*)(ws);              // 6.4M ushorts
    ushort_t* P2ah = (ushort_t*)(ws + 3200000);
    ushort_t* P2bh = (ushort_t*)(ws + 6400000);
    ushort_t* xa16 = (ushort_t*)(ws + 9600000);
    ushort_t* xb16 = (ushort_t*)(ws + 12800000);   // ends 16.0M floats
    int* rkAab = (int*)(ws + 16000000);
    int* rkBab = (int*)(ws + 16320000);
    int* rkAaa = (int*)(ws + 16640000);
    int* cntA  = (int*)(ws + 16960000);            // cntA+cntB contiguous 100K
    int* cntB  = (int*)(ws + 17010000);
    int* offA  = (int*)(ws + 17060000);            // 50001
    int* offB  = (int*)(ws + 17110004);            // 50001
    float* pm  = ws + 17160008;                    // 512
    float* pl  = ws + 17160520;                    // 512
    float* ML  = ws + 17161032;                    // 4
    float* wep = ws + 17161100;                    // 128
    ushort_t* FR = (ushort_t*)(ws + 17162000);     // 114688 ushorts
    ushort_t* BhWh = FR;
    ushort_t* BlWh = FR + 8192;
    ushort_t* BhW1 = FR + 16384;
    ushort_t* BlW1 = FR + 32768;
    ushort_t* BhW2 = FR + 49152;
    ushort_t* BlW2 = FR + 65536;
    ushort_t* BhFT = FR + 81920;
    ushort_t* BlFT = FR + 98304;
    int2* idxA = (int2*)(ws + 17220000);           // 640000 entries
    int2* idxB = (int2*)(ws + 18500000);           // 320000 entries

    // d_out layout: out_a[6.4M] out_b[6.4M] alpha_ab[320K] alpha_aa[320K]
    float* TA   = out;
    float* TB   = out + 6400000;
    float* alAB = out + 12800000;   // raw scores, then normalized in csr_fill
    float* alAA = out + 13120000;

    // 0) pack weights (bf16 hi/lo fragments) + permuted w_e
    prep_w_all<<<113, 64, 0, stream>>>(Wh_w, Wn_w, Wn_w + 128 * 128, ft_w, w_e,
                                       BhWh, BlWh, BhW1, BlW1, BhW2, BlW2, BhFT, BlFT, wep);

    // 1) node projections (f16 tables, interleaved layout) + f16 x copies
    proj_dual_mfma<<<(N_A + 63) / 64, 256, 0, stream>>>(x_a, BhW1, BlW1, BhW2, BlW2,
                                                        Wh_b, Wn_b, P1h, P2ah, xa16, N_A);
    proj_single_mfma<<<(N_B + 63) / 64, 256, 0, stream>>>(x_b, BhW2, BlW2, P2bh, xb16, N_B);

    // 2) edge scores via MFMA (raw scores into alpha slots)
    edge_score_mfma<<<E_AB / 64, 256, 0, stream>>>(ea_ab, ei_ab, P1h, P2bh, BhWh, BlWh, wep, alAB, E_AB);
    edge_score_mfma<<<E_AA / 64, 256, 0, stream>>>(ea_aa, ei_aa, P1h, P2ah, BhWh, BlWh, wep, alAA, E_AA);

    // 3) softmax reductions (both types)
    softmax_part_kernel<<<512, 256, 0, stream>>>(alAB, alAA, pm, pl);
    softmax_final_kernel<<<2, 256, 0, stream>>>(pm, pl, ML);

    // 4) CSR build: count (+ranks) -> scan -> fill (atomic-free, fused norm)
    hipMemsetAsync(cntA, 0, 100000 * sizeof(int), stream);
    csr_count_kernel<<<(E_AB + 255) / 256, 256, 0, stream>>>(ei_ab, ei_aa, cntA, cntB,
                                                             rkAab, rkBab, rkAaa);
    csr_scan_kernel<<<2, 1024, 0, stream>>>(cntA, offA, cntB, offB, N_A);
    csr_fill_kernel<<<(E_AB + 255) / 256, 256, 0, stream>>>(ei_ab, ei_aa, alAB, alAA, ML,
                                                            offA, offB, rkAab, rkBab, rkAaa,
                                                            idxA, idxB);

    // 5) gather (one wave per node; acc init = f32 x row)
    gather_kernel<<<(N_A + 3) / 4, 256, 0, stream>>>(offA, idxA, xa16, xb16, x_a, TA, N_A);
    gather_kernel<<<(N_B + 3) / 4, 256, 0, stream>>>(offB, idxB, xa16, xb16, x_b, TB, N_B);

    // 6) out = t + t@F + b  (in place, MFMA with folded residual+bias)
    final_mfma<<<(N_A + 63) / 64, 256, 0, stream>>>(TA, BhFT, BlFT, ft_b, N_A);
    final_mfma<<<(N_B + 63) / 64, 256, 0, stream>>>(TB, BhFT, BlFT, ft_b, N_B);

    (void)in_sizes; (void)n_in; (void)out_size; (void)ws_size;
}

// Round 6
// 338.004 us; speedup vs baseline: 3.7120x; 1.1352x over previous
//
#include <hip/hip_runtime.h>
#include <hip/hip_fp16.h>
#include <cstdint>
#include <cstddef>

// Problem constants (fixed by the reference)
#define N_A   50000
#define N_B   50000
#define E_AB  320000
#define E_AA  320000
#define IN_DIM 128
#define HID    128
#define ED     64

using bf16x8 = __attribute__((ext_vector_type(8))) short;
using f32x4  = __attribute__((ext_vector_type(4))) float;
typedef unsigned short ushort_t;
typedef unsigned int   uint_t;

__device__ inline ushort_t bf16r(float f) {   // f32 -> bf16 bits, RNE
    uint_t u = __float_as_uint(f);
    u = (u + 0x7FFF + ((u >> 16) & 1)) >> 16;
    return (ushort_t)u;
}
__device__ inline float bf2f(ushort_t h) {
    return __uint_as_float(((uint_t)h) << 16);
}
__device__ inline ushort_t f16r(float f) { return __half_as_ushort(__float2half_rn(f)); }
__device__ inline float f16f(ushort_t u) { return __half2float(__ushort_as_half(u)); }
__device__ inline uint_t packh2(float a, float b) {
    return (uint_t)f16r(a) | ((uint_t)f16r(b) << 16);
}

__device__ inline void online_merge(float& m, float& l, float om, float ol) {
    const float nm = fmaxf(m, om);
    l = l * __expf(m - nm) + ol * __expf(om - nm);
    m = nm;
}

// ---------------------------------------------------------------------------
// Pre-pack all weights into bf16 hi/lo MFMA B-fragments + permuted w_e.
// B frag (16x16x32): lane holds col = ct*16 + (lane&15), k = kt*32 + (lane>>4)*8 + j
// Sets: Wh (KT=2, 16 frags), W1 (KT=4, 32), W2 (KT=4, 32), FT (KT=4, 32).
// Block 112: wep[l15*8+ct] = we[ct*16+l15].
// ---------------------------------------------------------------------------
__global__ __launch_bounds__(64) void prep_w_all(
    const float* __restrict__ Wh, const float* __restrict__ W1,
    const float* __restrict__ W2, const float* __restrict__ FT,
    const float* __restrict__ we,
    ushort_t* __restrict__ BhWh, ushort_t* __restrict__ BlWh,
    ushort_t* __restrict__ BhW1, ushort_t* __restrict__ BlW1,
    ushort_t* __restrict__ BhW2, ushort_t* __restrict__ BlW2,
    ushort_t* __restrict__ BhFT, ushort_t* __restrict__ BlFT,
    float* __restrict__ wep)
{
    const int f = blockIdx.x;
    const int lane = threadIdx.x;
    if (f == 112) {
#pragma unroll
        for (int q = 0; q < 2; ++q) {
            const int idx = lane + q * 64;
            const int l15 = idx >> 3, ct = idx & 7;
            wep[idx] = we[ct * 16 + l15];
        }
        return;
    }
    const float* W; ushort_t *oh, *ol; int KT, fl;
    if (f < 16)      { W = Wh; oh = BhWh; ol = BlWh; KT = 2; fl = f; }
    else if (f < 48) { W = W1; oh = BhW1; ol = BlW1; KT = 4; fl = f - 16; }
    else if (f < 80) { W = W2; oh = BhW2; ol = BlW2; KT = 4; fl = f - 48; }
    else             { W = FT; oh = BhFT; ol = BlFT; KT = 4; fl = f - 80; }
    const int ct = fl / KT, kt = fl % KT;
    const int col = ct * 16 + (lane & 15);
    const int kb  = kt * 32 + (lane >> 4) * 8;
#pragma unroll
    for (int j = 0; j < 8; ++j) {
        const float v = W[(kb + j) * 128 + col];
        const ushort_t h = bf16r(v);
        oh[(size_t)(fl * 64 + lane) * 8 + j] = h;
        ol[(size_t)(fl * 64 + lane) * 8 + j] = bf16r(v - bf2f(h));
    }
}

// ---------------------------------------------------------------------------
// proj_dual: P1 = x_a@W1 + (bh+bn), P2 = x_a@W2, stored f16 in layout
// P[row*128 + l15*8 + ct]. Also emits f16 copy of x_a.
// ---------------------------------------------------------------------------
__global__ __launch_bounds__(256) void proj_dual_mfma(
    const float* __restrict__ X,
    const ushort_t* __restrict__ B1h, const ushort_t* __restrict__ B1l,
    const ushort_t* __restrict__ B2h, const ushort_t* __restrict__ B2l,
    const float* __restrict__ bh, const float* __restrict__ bn,
    ushort_t* __restrict__ P1, ushort_t* __restrict__ P2,
    ushort_t* __restrict__ X16, int N)
{
    const int lane = threadIdx.x & 63;
    const int l15 = lane & 15, lg = lane >> 4;
    const int r0 = blockIdx.x * 64 + (threadIdx.x >> 6) * 16;
    const int arow = (r0 + l15 < N) ? (r0 + l15) : (N - 1);

    bf16x8 ahi[4], alo[4];
#pragma unroll
    for (int kt = 0; kt < 4; ++kt) {
        float v[8];
        *(float4*)(v + 0) = *(const float4*)&X[(size_t)arow * 128 + kt * 32 + lg * 8];
        *(float4*)(v + 4) = *(const float4*)&X[(size_t)arow * 128 + kt * 32 + lg * 8 + 4];
        uint4 xu;
        xu.x = packh2(v[0], v[1]); xu.y = packh2(v[2], v[3]);
        xu.z = packh2(v[4], v[5]); xu.w = packh2(v[6], v[7]);
        *(uint4*)&X16[(size_t)arow * 128 + kt * 32 + lg * 8] = xu;
#pragma unroll
        for (int j = 0; j < 8; ++j) {
            const ushort_t h = bf16r(v[j]);
            ahi[kt][j] = (short)h;
            alo[kt][j] = (short)bf16r(v[j] - bf2f(h));
        }
    }

    f32x4 acc1[8], acc2[8];
#pragma unroll
    for (int ct = 0; ct < 8; ++ct) {
        const float b = bh[ct * 16 + l15] + bn[ct * 16 + l15];
        acc1[ct] = (f32x4){b, b, b, b};
        acc2[ct] = (f32x4){0.f, 0.f, 0.f, 0.f};
    }

#pragma unroll
    for (int ct = 0; ct < 8; ++ct) {
#pragma unroll
        for (int kt = 0; kt < 4; ++kt) {
            const size_t fo = (size_t)((ct * 4 + kt) * 64 + lane) * 8;
            const bf16x8 b1h = *(const bf16x8*)&B1h[fo];
            const bf16x8 b1l = *(const bf16x8*)&B1l[fo];
            const bf16x8 b2h = *(const bf16x8*)&B2h[fo];
            const bf16x8 b2l = *(const bf16x8*)&B2l[fo];
            acc1[ct] = __builtin_amdgcn_mfma_f32_16x16x32_bf16(ahi[kt], b1h, acc1[ct], 0, 0, 0);
            acc1[ct] = __builtin_amdgcn_mfma_f32_16x16x32_bf16(alo[kt], b1h, acc1[ct], 0, 0, 0);
            acc1[ct] = __builtin_amdgcn_mfma_f32_16x16x32_bf16(ahi[kt], b1l, acc1[ct], 0, 0, 0);
            acc2[ct] = __builtin_amdgcn_mfma_f32_16x16x32_bf16(ahi[kt], b2h, acc2[ct], 0, 0, 0);
            acc2[ct] = __builtin_amdgcn_mfma_f32_16x16x32_bf16(alo[kt], b2h, acc2[ct], 0, 0, 0);
            acc2[ct] = __builtin_amdgcn_mfma_f32_16x16x32_bf16(ahi[kt], b2l, acc2[ct], 0, 0, 0);
        }
    }
#pragma unroll
    for (int i = 0; i < 4; ++i) {
        const int row = r0 + lg * 4 + i;
        if (row < N) {
            uint4 u1, u2;
            u1.x = packh2(acc1[0][i], acc1[1][i]); u1.y = packh2(acc1[2][i], acc1[3][i]);
            u1.z = packh2(acc1[4][i], acc1[5][i]); u1.w = packh2(acc1[6][i], acc1[7][i]);
            u2.x = packh2(acc2[0][i], acc2[1][i]); u2.y = packh2(acc2[2][i], acc2[3][i]);
            u2.z = packh2(acc2[4][i], acc2[5][i]); u2.w = packh2(acc2[6][i], acc2[7][i]);
            *(uint4*)&P1[(size_t)row * 128 + l15 * 8] = u1;
            *(uint4*)&P2[(size_t)row * 128 + l15 * 8] = u2;
        }
    }
}

// proj_single: P = x_b@W2 (no bias), f16 interleaved; emits xb16.
__global__ __launch_bounds__(256) void proj_single_mfma(
    const float* __restrict__ X,
    const ushort_t* __restrict__ Bh, const ushort_t* __restrict__ Bl,
    ushort_t* __restrict__ P, ushort_t* __restrict__ X16, int N)
{
    const int lane = threadIdx.x & 63;
    const int l15 = lane & 15, lg = lane >> 4;
    const int r0 = blockIdx.x * 64 + (threadIdx.x >> 6) * 16;
    const int arow = (r0 + l15 < N) ? (r0 + l15) : (N - 1);

    bf16x8 ahi[4], alo[4];
#pragma unroll
    for (int kt = 0; kt < 4; ++kt) {
        float v[8];
        *(float4*)(v + 0) = *(const float4*)&X[(size_t)arow * 128 + kt * 32 + lg * 8];
        *(float4*)(v + 4) = *(const float4*)&X[(size_t)arow * 128 + kt * 32 + lg * 8 + 4];
        uint4 xu;
        xu.x = packh2(v[0], v[1]); xu.y = packh2(v[2], v[3]);
        xu.z = packh2(v[4], v[5]); xu.w = packh2(v[6], v[7]);
        *(uint4*)&X16[(size_t)arow * 128 + kt * 32 + lg * 8] = xu;
#pragma unroll
        for (int j = 0; j < 8; ++j) {
            const ushort_t h = bf16r(v[j]);
            ahi[kt][j] = (short)h;
            alo[kt][j] = (short)bf16r(v[j] - bf2f(h));
        }
    }

    f32x4 acc[8];
#pragma unroll
    for (int ct = 0; ct < 8; ++ct) acc[ct] = (f32x4){0.f, 0.f, 0.f, 0.f};

#pragma unroll
    for (int ct = 0; ct < 8; ++ct) {
#pragma unroll
        for (int kt = 0; kt < 4; ++kt) {
            const size_t fo = (size_t)((ct * 4 + kt) * 64 + lane) * 8;
            const bf16x8 bhf = *(const bf16x8*)&Bh[fo];
            const bf16x8 blf = *(const bf16x8*)&Bl[fo];
            acc[ct] = __builtin_amdgcn_mfma_f32_16x16x32_bf16(ahi[kt], bhf, acc[ct], 0, 0, 0);
            acc[ct] = __builtin_amdgcn_mfma_f32_16x16x32_bf16(alo[kt], bhf, acc[ct], 0, 0, 0);
            acc[ct] = __builtin_amdgcn_mfma_f32_16x16x32_bf16(ahi[kt], blf, acc[ct], 0, 0, 0);
        }
    }
#pragma unroll
    for (int i = 0; i < 4; ++i) {
        const int row = r0 + lg * 4 + i;
        if (row < N) {
            uint4 u;
            u.x = packh2(acc[0][i], acc[1][i]); u.y = packh2(acc[2][i], acc[3][i]);
            u.z = packh2(acc[4][i], acc[5][i]); u.w = packh2(acc[6][i], acc[7][i]);
            *(uint4*)&P[(size_t)row * 128 + l15 * 8] = u;
        }
    }
}

// ---------------------------------------------------------------------------
// Edge score: 32 edges/wave (2 A-tiles share each B-fragment load), with
// fused CSR counting (+rank record) and fused softmax block-partials.
// ---------------------------------------------------------------------------
__global__ __launch_bounds__(256) void edge_score_k(
    const float* __restrict__ ea,     // [E][64]
    const int*   __restrict__ ei,     // [2][E]
    const ushort_t* __restrict__ P1h,
    const ushort_t* __restrict__ P2h,
    const ushort_t* __restrict__ Bhi,
    const ushort_t* __restrict__ Blo,
    const float* __restrict__ wep,    // permuted w_e: wep[l15*8+ct]
    float* __restrict__ score,
    int* __restrict__ cntS, int* __restrict__ cntD,
    int* __restrict__ rkS, int* __restrict__ rkD,
    float* __restrict__ pm, float* __restrict__ pl,
    int dual, int E)
{
    const int t    = threadIdx.x;
    const int lane = t & 63;
    const int l15  = lane & 15;
    const int lg   = lane >> 4;
    const int wv   = t >> 6;
    const int eb   = blockIdx.x * 128;

    // fused CSR count + rank (threads 0..127 handle this block's 128 edges)
    if (t < 128) {
        const int e = eb + t;
        const int s = ei[e];
        rkS[e] = atomicAdd(&cntS[s], 1);
        if (dual) {
            const int d = ei[(size_t)E + e];
            rkD[e] = atomicAdd(&cntD[d], 1);
        }
    }

    const int e0 = eb + wv * 32;   // this wave's 32 edges (2 tiles of 16)

    // A fragments, both tiles
    bf16x8 ahi[2][2], alo[2][2];
#pragma unroll
    for (int tl = 0; tl < 2; ++tl) {
        const float* arow = &ea[(size_t)(e0 + tl * 16 + l15) * 64 + lg * 8];
        float af[16];
        *(float4*)(af + 0)  = *(const float4*)(arow + 0);
        *(float4*)(af + 4)  = *(const float4*)(arow + 4);
        *(float4*)(af + 8)  = *(const float4*)(arow + 32);
        *(float4*)(af + 12) = *(const float4*)(arow + 36);
#pragma unroll
        for (int kt = 0; kt < 2; ++kt) {
#pragma unroll
            for (int j = 0; j < 8; ++j) {
                const float v = af[kt * 8 + j];
                const ushort_t h = bf16r(v);
                ahi[tl][kt][j] = (short)h;
                alo[tl][kt][j] = (short)bf16r(v - bf2f(h));
            }
        }
    }

    f32x4 acc[2][8];
#pragma unroll
    for (int tl = 0; tl < 2; ++tl)
#pragma unroll
        for (int ct = 0; ct < 8; ++ct) acc[tl][ct] = (f32x4){0.f, 0.f, 0.f, 0.f};

#pragma unroll
    for (int ct = 0; ct < 8; ++ct) {
        const bf16x8 bh0 = *(const bf16x8*)&Bhi[(size_t)(ct * 2 + 0) * 512 + lane * 8];
        const bf16x8 bl0 = *(const bf16x8*)&Blo[(size_t)(ct * 2 + 0) * 512 + lane * 8];
        const bf16x8 bh1 = *(const bf16x8*)&Bhi[(size_t)(ct * 2 + 1) * 512 + lane * 8];
        const bf16x8 bl1 = *(const bf16x8*)&Blo[(size_t)(ct * 2 + 1) * 512 + lane * 8];
#pragma unroll
        for (int tl = 0; tl < 2; ++tl) {
            acc[tl][ct] = __builtin_amdgcn_mfma_f32_16x16x32_bf16(ahi[tl][0], bh0, acc[tl][ct], 0, 0, 0);
            acc[tl][ct] = __builtin_amdgcn_mfma_f32_16x16x32_bf16(alo[tl][0], bh0, acc[tl][ct], 0, 0, 0);
            acc[tl][ct] = __builtin_amdgcn_mfma_f32_16x16x32_bf16(ahi[tl][0], bl0, acc[tl][ct], 0, 0, 0);
            acc[tl][ct] = __builtin_amdgcn_mfma_f32_16x16x32_bf16(ahi[tl][1], bh1, acc[tl][ct], 0, 0, 0);
            acc[tl][ct] = __builtin_amdgcn_mfma_f32_16x16x32_bf16(alo[tl][1], bh1, acc[tl][ct], 0, 0, 0);
            acc[tl][ct] = __builtin_amdgcn_mfma_f32_16x16x32_bf16(ahi[tl][1], bl1, acc[tl][ct], 0, 0, 0);
        }
    }

    float w8[8];
    *(float4*)(w8 + 0) = *(const float4*)&wep[l15 * 8];
    *(float4*)(w8 + 4) = *(const float4*)&wep[l15 * 8 + 4];

    float part[2][4];
#pragma unroll
    for (int tl = 0; tl < 2; ++tl) {
        int sidx[4], didx[4];
#pragma unroll
        for (int i = 0; i < 4; ++i) {
            const int e = e0 + tl * 16 + lg * 4 + i;
            sidx[i] = ei[e];
            didx[i] = ei[(size_t)E + e];
        }
        uint4 p1u[4], p2u[4];
#pragma unroll
        for (int i = 0; i < 4; ++i) {
            p1u[i] = *(const uint4*)&P1h[(size_t)sidx[i] * 128 + l15 * 8];
            p2u[i] = *(const uint4*)&P2h[(size_t)didx[i] * 128 + l15 * 8];
        }
#pragma unroll
        for (int i = 0; i < 4; ++i) {
            const uint_t* u1 = (const uint_t*)&p1u[i];
            const uint_t* u2 = (const uint_t*)&p2u[i];
            float p = 0.f;
#pragma unroll
            for (int q = 0; q < 4; ++q) {
                const float pa1 = f16f((ushort_t)(u1[q] & 0xFFFF));
                const float pb1 = f16f((ushort_t)(u1[q] >> 16));
                const float pa2 = f16f((ushort_t)(u2[q] & 0xFFFF));
                const float pb2 = f16f((ushort_t)(u2[q] >> 16));
                const float h0 = acc[tl][2 * q][i] + pa1 + pa2;
                const float h1 = acc[tl][2 * q + 1][i] + pb1 + pb2;
                p = fmaf(fmaxf(h0, 0.f), w8[2 * q], p);
                p = fmaf(fmaxf(h1, 0.f), w8[2 * q + 1], p);
            }
            part[tl][i] = p;
        }
#pragma unroll
        for (int m = 8; m >= 1; m >>= 1) {
#pragma unroll
            for (int i = 0; i < 4; ++i) part[tl][i] += __shfl_xor(part[tl][i], m, 64);
        }
        if (l15 == 0) {
#pragma unroll
            for (int i = 0; i < 4; ++i) score[e0 + tl * 16 + lg * 4 + i] = part[tl][i];
        }
    }

    // fused softmax partials: wave-level (m,l) over this wave's 32 scores
    float mw = part[0][0];
#pragma unroll
    for (int tl = 0; tl < 2; ++tl)
#pragma unroll
        for (int i = 0; i < 4; ++i) mw = fmaxf(mw, part[tl][i]);
    float lw = 0.f;
#pragma unroll
    for (int tl = 0; tl < 2; ++tl)
#pragma unroll
        for (int i = 0; i < 4; ++i) lw += __expf(part[tl][i] - mw);
    // merge the 4 lane-groups (each group's 16 lanes hold identical values)
#pragma unroll
    for (int off = 16; off <= 32; off <<= 1) {
        const float om = __shfl_xor(mw, off, 64);
        const float ol = __shfl_xor(lw, off, 64);
        online_merge(mw, lw, om, ol);
    }
    __shared__ float smm[4], sll[4];
    if (lane == 0) { smm[wv] = mw; sll[wv] = lw; }
    __syncthreads();
    if (t == 0) {
        float M = smm[0], L = sll[0];
        for (int i = 1; i < 4; ++i) online_merge(M, L, smm[i], sll[i]);
        pm[blockIdx.x] = M;
        pl[blockIdx.x] = L;
    }
}

// ---------------------------------------------------------------------------
// Final softmax reduction over block partials; grid 2 (type per block)
// ---------------------------------------------------------------------------
__global__ __launch_bounds__(1024) void softmax_final_kernel(
    const float* __restrict__ pm, const float* __restrict__ pl,
    float* __restrict__ ML, int nPart)
{
    const int type = blockIdx.x;
    const float* mi = pm + type * nPart;
    const float* li = pl + type * nPart;
    float m = -1e30f, l = 0.f;
    for (int i = threadIdx.x; i < nPart; i += 1024) online_merge(m, l, mi[i], li[i]);
#pragma unroll
    for (int off = 1; off < 64; off <<= 1) {
        const float om = __shfl_xor(m, off, 64);
        const float ol = __shfl_xor(l, off, 64);
        online_merge(m, l, om, ol);
    }
    __shared__ float smm[16], sll[16];
    const int w = threadIdx.x >> 6, lane = threadIdx.x & 63;
    if (lane == 0) { smm[w] = m; sll[w] = l; }
    __syncthreads();
    if (threadIdx.x == 0) {
        float M = smm[0], L = sll[0];
        for (int i = 1; i < 16; ++i) online_merge(M, L, smm[i], sll[i]);
        ML[type * 2]     = M;
        ML[type * 2 + 1] = L;
    }
}

// ---------------------------------------------------------------------------
// CSR scan (unchanged)
// ---------------------------------------------------------------------------
__global__ __launch_bounds__(1024) void csr_scan_kernel(
    const int* __restrict__ cntA, int* __restrict__ offA,
    const int* __restrict__ cntB, int* __restrict__ offB, int N)
{
    const int* cnt = (blockIdx.x == 0) ? cntA : cntB;
    int* off = (blockIdx.x == 0) ? offA : offB;

    __shared__ int warpsum[16];
    const int t = threadIdx.x, lane = t & 63, w = t >> 6;
    int carry = 0;

    for (int base = 0; base < N; base += 1024) {
        const int i = base + t;
        const int v = (i < N) ? cnt[i] : 0;
        int x = v;
#pragma unroll
        for (int d = 1; d < 64; d <<= 1) {
            const int y = __shfl_up(x, d, 64);
            if (lane >= d) x += y;
        }
        if (lane == 63) warpsum[w] = x;
        __syncthreads();
        if (w == 0 && lane < 16) {
            int s = warpsum[lane];
#pragma unroll
            for (int d = 1; d < 16; d <<= 1) {
                const int y = __shfl_up(s, d, 64);
                if (lane >= d) s += y;
            }
            warpsum[lane] = s;
        }
        __syncthreads();
        const int excl = (x - v) + ((w > 0) ? warpsum[w - 1] : 0) + carry;
        if (i < N) off[i] = excl;
        carry += warpsum[15];
        __syncthreads();
    }
    if (t == 0) off[N] = carry;
}

// Atomic-free fill with fused softmax normalization (positions clamped for
// rocprof-replay atomic-inflation safety).
__global__ __launch_bounds__(256) void csr_fill_kernel(
    const int* __restrict__ ei_ab, const int* __restrict__ ei_aa,
    float* __restrict__ scAB, float* __restrict__ scAA,
    const float* __restrict__ ML,
    const int* __restrict__ offA, const int* __restrict__ offB,
    const int* __restrict__ rkAab, const int* __restrict__ rkBab,
    const int* __restrict__ rkAaa,
    int2* __restrict__ idxA, int2* __restrict__ idxB)
{
    const int i = blockIdx.x * 256 + threadIdx.x;
    const float Mab = ML[0], rLab = 1.0f / ML[1];
    const float Maa = ML[2], rLaa = 1.0f / ML[3];
    if (i < E_AB) {
        const float a = __expf(scAB[i] - Mab) * rLab;
        scAB[i] = a;
        const int s = ei_ab[i], d = ei_ab[E_AB + i];
        const int ab = __float_as_int(a);
        int pA = offA[s] + rkAab[i]; if (pA > 2 * E_AB - 1) pA = 2 * E_AB - 1;
        int pB = offB[d] + rkBab[i]; if (pB > E_AB - 1) pB = E_AB - 1;
        idxA[pA] = make_int2(d | (1 << 20), ab);
        idxB[pB] = make_int2(s, ab);
    }
    if (i < E_AA) {
        const float a = __expf(scAA[i] - Maa) * rLaa;
        scAA[i] = a;
        const int s = ei_aa[i];
        const int daa = ei_aa[E_AA + i];
        int pA = offA[s] + rkAaa[i]; if (pA > 2 * E_AB - 1) pA = 2 * E_AB - 1;
        idxA[pA] = make_int2(daa, __float_as_int(a));
    }
}

// ---------------------------------------------------------------------------
// Fused gather + final: block = 4 waves x 16 rows. Phase 1: quarter-wave
// (16 lanes) per row, 4 rows concurrent per wave, f16 features, acc init =
// f32 x_self row; writes T. Phase 2: final MFMA (T <- T + T@FT + fb) on the
// same 16 rows; T reads hit L2 (just written by this block).
// ---------------------------------------------------------------------------
__global__ __launch_bounds__(256) void gather_final(
    const int*  __restrict__ off, const int2* __restrict__ idx,
    const ushort_t* __restrict__ xa16, const ushort_t* __restrict__ xb16,
    const float* __restrict__ xself,
    const ushort_t* __restrict__ Bh, const ushort_t* __restrict__ Bl,
    const float* __restrict__ fb,
    float* __restrict__ T, int N)
{
    const int lane = threadIdx.x & 63;
    const int l15  = lane & 15, lg = lane >> 4;
    const int wv   = threadIdx.x >> 6;
    const int r0   = blockIdx.x * 64 + wv * 16;

    // ---- Phase 1: gather 16 rows (4 steps x 4 concurrent quarter-wave rows)
    for (int s = 0; s < 4; ++s) {
        const int row = r0 + s * 4 + lg;
        if (row < N) {
            const int beg = off[row], end = off[row + 1];
            float a8[8];
            *(float4*)(a8 + 0) = *(const float4*)&xself[(size_t)row * 128 + l15 * 8];
            *(float4*)(a8 + 4) = *(const float4*)&xself[(size_t)row * 128 + l15 * 8 + 4];
            int e = beg;
            for (; e + 1 < end; e += 2) {
                const int2 q0 = idx[e];
                const int2 q1 = idx[e + 1];
                const float al0 = __int_as_float(q0.y);
                const float al1 = __int_as_float(q1.y);
                const ushort_t* s0 = (q0.x & (1 << 20)) ? xb16 : xa16;
                const ushort_t* s1 = (q1.x & (1 << 20)) ? xb16 : xa16;
                const uint4 f0 = *(const uint4*)&s0[(size_t)(q0.x & 0xFFFFF) * 128 + l15 * 8];
                const uint4 f1 = *(const uint4*)&s1[(size_t)(q1.x & 0xFFFFF) * 128 + l15 * 8];
                const uint_t* u0 = (const uint_t*)&f0;
                const uint_t* u1 = (const uint_t*)&f1;
#pragma unroll
                for (int k = 0; k < 4; ++k) {
                    a8[2 * k]     = fmaf(-al0, f16f((ushort_t)(u0[k] & 0xFFFF)), a8[2 * k]);
                    a8[2 * k + 1] = fmaf(-al0, f16f((ushort_t)(u0[k] >> 16)),    a8[2 * k + 1]);
                    a8[2 * k]     = fmaf(-al1, f16f((ushort_t)(u1[k] & 0xFFFF)), a8[2 * k]);
                    a8[2 * k + 1] = fmaf(-al1, f16f((ushort_t)(u1[k] >> 16)),    a8[2 * k + 1]);
                }
            }
            if (e < end) {
                const int2 q0 = idx[e];
                const float al0 = __int_as_float(q0.y);
                const ushort_t* s0 = (q0.x & (1 << 20)) ? xb16 : xa16;
                const uint4 f0 = *(const uint4*)&s0[(size_t)(q0.x & 0xFFFFF) * 128 + l15 * 8];
                const uint_t* u0 = (const uint_t*)&f0;
#pragma unroll
                for (int k = 0; k < 4; ++k) {
                    a8[2 * k]     = fmaf(-al0, f16f((ushort_t)(u0[k] & 0xFFFF)), a8[2 * k]);
                    a8[2 * k + 1] = fmaf(-al0, f16f((ushort_t)(u0[k] >> 16)),    a8[2 * k + 1]);
                }
            }
            *(float4*)&T[(size_t)row * 128 + l15 * 8]     = *(float4*)(a8 + 0);
            *(float4*)&T[(size_t)row * 128 + l15 * 8 + 4] = *(float4*)(a8 + 4);
        }
    }
    __syncthreads();

    // ---- Phase 2: final MFMA on rows [r0, r0+16)
    const int arow = (r0 + l15 < N) ? (r0 + l15) : (N - 1);
    bf16x8 ahi[4], alo[4];
#pragma unroll
    for (int kt = 0; kt < 4; ++kt) {
        float v[8];
        *(float4*)(v + 0) = *(const float4*)&T[(size_t)arow * 128 + kt * 32 + lg * 8];
        *(float4*)(v + 4) = *(const float4*)&T[(size_t)arow * 128 + kt * 32 + lg * 8 + 4];
#pragma unroll
        for (int j = 0; j < 8; ++j) {
            const ushort_t h = bf16r(v[j]);
            ahi[kt][j] = (short)h;
            alo[kt][j] = (short)bf16r(v[j] - bf2f(h));
        }
    }

    f32x4 acc[8];
#pragma unroll
    for (int ct = 0; ct < 8; ++ct) {
        const float b = fb[ct * 16 + l15];
#pragma unroll
        for (int i = 0; i < 4; ++i) {
            const int row = r0 + lg * 4 + i;
            const int rr = (row < N) ? row : (N - 1);
            acc[ct][i] = T[(size_t)rr * 128 + ct * 16 + l15] + b;
        }
    }

#pragma unroll
    for (int ct = 0; ct < 8; ++ct) {
#pragma unroll
        for (int kt = 0; kt < 4; ++kt) {
            const size_t fo = (size_t)((ct * 4 + kt) * 64 + lane) * 8;
            const bf16x8 bhf = *(const bf16x8*)&Bh[fo];
            const bf16x8 blf = *(const bf16x8*)&Bl[fo];
            acc[ct] = __builtin_amdgcn_mfma_f32_16x16x32_bf16(ahi[kt], bhf, acc[ct], 0, 0, 0);
            acc[ct] = __builtin_amdgcn_mfma_f32_16x16x32_bf16(alo[kt], bhf, acc[ct], 0, 0, 0);
            acc[ct] = __builtin_amdgcn_mfma_f32_16x16x32_bf16(ahi[kt], blf, acc[ct], 0, 0, 0);
        }
    }
#pragma unroll
    for (int ct = 0; ct < 8; ++ct) {
#pragma unroll
        for (int i = 0; i < 4; ++i) {
            const int row = r0 + lg * 4 + i;
            if (row < N) T[(size_t)row * 128 + ct * 16 + l15] = acc[ct][i];
        }
    }
}

// ---------------------------------------------------------------------------
extern "C" void kernel_launch(void* const* d_in, const int* in_sizes, int n_in,
                              void* d_out, int out_size, void* d_ws, size_t ws_size,
                              hipStream_t stream)
{
    const float* x_a   = (const float*)d_in[0];
    const float* x_b   = (const float*)d_in[1];
    const int*   ei_ab = (const int*)d_in[2];
    const float* ea_ab = (const float*)d_in[3];
    const int*   ei_aa = (const int*)d_in[4];
    const float* ea_aa = (const float*)d_in[5];
    const float* Wh_w  = (const float*)d_in[6];
    const float* Wh_b  = (const float*)d_in[7];
    const float* Wn_w  = (const float*)d_in[8];
    const float* Wn_b  = (const float*)d_in[9];
    const float* w_e   = (const float*)d_in[10];
    const float* ft_w  = (const float*)d_in[11];
    const float* ft_b  = (const float*)d_in[12];

    float* out = (float*)d_out;
    float* ws  = (float*)d_ws;

    // ws layout (float offsets; all regions disjoint)
    ushort_t* P1h  = (ushort_t*)(ws);              // 6.4M ushorts
    ushort_t* P2ah = (ushort_t*)(ws + 3200000);
    ushort_t* P2bh = (ushort_t*)(ws + 6400000);
    ushort_t* xa16 = (ushort_t*)(ws + 9600000);
    ushort_t* xb16 = (ushort_t*)(ws + 12800000);
    int* rkAab = (int*)(ws + 16000000);
    int* rkBab = (int*)(ws + 16320000);
    int* rkAaa = (int*)(ws + 16640000);
    int* cntA  = (int*)(ws + 16960000);            // cntA+cntB contiguous
    int* cntB  = (int*)(ws + 17010000);
    int* offA  = (int*)(ws + 17060000);            // 50001
    int* offB  = (int*)(ws + 17110004);            // 50001
    float* pm  = ws + 17160008;                    // 5000 (2500 per type)
    float* pl  = ws + 17165008;                    // 5000
    float* ML  = ws + 17170008;                    // 4
    float* wep = ws + 17170016;                    // 128
    ushort_t* FR = (ushort_t*)(ws + 17170208);     // 114688 ushorts
    ushort_t* BhWh = FR;
    ushort_t* BlWh = FR + 8192;
    ushort_t* BhW1 = FR + 16384;
    ushort_t* BlW1 = FR + 32768;
    ushort_t* BhW2 = FR + 49152;
    ushort_t* BlW2 = FR + 65536;
    ushort_t* BhFT = FR + 81920;
    ushort_t* BlFT = FR + 98304;
    int2* idxA = (int2*)(ws + 17230000);           // 640000 entries
    int2* idxB = (int2*)(ws + 18510000);           // 320000 entries

    // d_out layout: out_a[6.4M] out_b[6.4M] alpha_ab[320K] alpha_aa[320K]
    float* TA   = out;
    float* TB   = out + 6400000;
    float* alAB = out + 12800000;   // raw scores, then normalized in csr_fill
    float* alAA = out + 13120000;

    // 0) zero CSR counters; pack weights
    hipMemsetAsync(cntA, 0, 100000 * sizeof(int), stream);
    prep_w_all<<<113, 64, 0, stream>>>(Wh_w, Wn_w, Wn_w + 128 * 128, ft_w, w_e,
                                       BhWh, BlWh, BhW1, BlW1, BhW2, BlW2, BhFT, BlFT, wep);

    // 1) node projections (f16 tables, interleaved layout) + f16 x copies
    proj_dual_mfma<<<(N_A + 63) / 64, 256, 0, stream>>>(x_a, BhW1, BlW1, BhW2, BlW2,
                                                        Wh_b, Wn_b, P1h, P2ah, xa16, N_A);
    proj_single_mfma<<<(N_B + 63) / 64, 256, 0, stream>>>(x_b, BhW2, BlW2, P2bh, xb16, N_B);

    // 2) edge scores (fused: CSR count+rank, softmax block partials)
    edge_score_k<<<E_AB / 128, 256, 0, stream>>>(ea_ab, ei_ab, P1h, P2bh, BhWh, BlWh, wep,
                                                 alAB, cntA, cntB, rkAab, rkBab,
                                                 pm, pl, 1, E_AB);
    edge_score_k<<<E_AA / 128, 256, 0, stream>>>(ea_aa, ei_aa, P1h, P2ah, BhWh, BlWh, wep,
                                                 alAA, cntA, cntA, rkAaa, rkAaa,
                                                 pm + 2500, pl + 2500, 0, E_AA);

    // 3) softmax final reduction (both types)
    softmax_final_kernel<<<2, 1024, 0, stream>>>(pm, pl, ML, 2500);

    // 4) CSR scan + atomic-free fill (fused normalization)
    csr_scan_kernel<<<2, 1024, 0, stream>>>(cntA, offA, cntB, offB, N_A);
    csr_fill_kernel<<<(E_AB + 255) / 256, 256, 0, stream>>>(ei_ab, ei_aa, alAB, alAA, ML,
                                                            offA, offB, rkAab, rkBab, rkAaa,
                                                            idxA, idxB);

    // 5) fused gather + final transform
    gather_final<<<(N_A + 63) / 64, 256, 0, stream>>>(offA, idxA, xa16, xb16, x_a,
                                                      BhFT, BlFT, ft_b, TA, N_A);
    gather_final<<<(N_B + 63) / 64, 256, 0, stream>>>(offB, idxB, xa16, xb16, x_b,
                                                      BhFT, BlFT, ft_b, TB, N_B);

    (void)in_sizes; (void)n_in; (void)out_size; (void)ws_size;
}

// Round 7
// 331.913 us; speedup vs baseline: 3.7802x; 1.0184x over previous
//
#include <hip/hip_runtime.h>
#include <hip/hip_fp16.h>
#include <cstdint>
#include <cstddef>

// Problem constants (fixed by the reference)
#define N_A   50000
#define N_B   50000
#define E_AB  320000
#define E_AA  320000
#define IN_DIM 128
#define HID    128
#define ED     64

using bf16x8 = __attribute__((ext_vector_type(8))) short;
using f32x4  = __attribute__((ext_vector_type(4))) float;
typedef unsigned short ushort_t;
typedef unsigned int   uint_t;

__device__ inline ushort_t bf16r(float f) {   // f32 -> bf16 bits, RNE
    uint_t u = __float_as_uint(f);
    u = (u + 0x7FFF + ((u >> 16) & 1)) >> 16;
    return (ushort_t)u;
}
__device__ inline float bf2f(ushort_t h) {
    return __uint_as_float(((uint_t)h) << 16);
}
__device__ inline ushort_t f16r(float f) { return __half_as_ushort(__float2half_rn(f)); }
__device__ inline float f16f(ushort_t u) { return __half2float(__ushort_as_half(u)); }
__device__ inline uint_t packh2(float a, float b) {
    return (uint_t)f16r(a) | ((uint_t)f16r(b) << 16);
}

__device__ inline void online_merge(float& m, float& l, float om, float ol) {
    const float nm = fmaxf(m, om);
    l = l * __expf(m - nm) + ol * __expf(om - nm);
    m = nm;
}

// ---------------------------------------------------------------------------
// Pre-pack all weights into bf16 hi/lo MFMA B-fragments + permuted w_e.
// B frag (16x16x32): lane holds col = ct*16 + (lane&15), k = kt*32 + (lane>>4)*8 + j
// Sets: Wh (KT=2, 16 frags), W1 (KT=4, 32), W2 (KT=4, 32), FT (KT=4, 32).
// Block 112: wep[l15*8+ct] = we[ct*16+l15].
// ---------------------------------------------------------------------------
__global__ __launch_bounds__(64) void prep_w_all(
    const float* __restrict__ Wh, const float* __restrict__ W1,
    const float* __restrict__ W2, const float* __restrict__ FT,
    const float* __restrict__ we,
    ushort_t* __restrict__ BhWh, ushort_t* __restrict__ BlWh,
    ushort_t* __restrict__ BhW1, ushort_t* __restrict__ BlW1,
    ushort_t* __restrict__ BhW2, ushort_t* __restrict__ BlW2,
    ushort_t* __restrict__ BhFT, ushort_t* __restrict__ BlFT,
    float* __restrict__ wep)
{
    const int f = blockIdx.x;
    const int lane = threadIdx.x;
    if (f == 112) {
#pragma unroll
        for (int q = 0; q < 2; ++q) {
            const int idx = lane + q * 64;
            const int l15 = idx >> 3, ct = idx & 7;
            wep[idx] = we[ct * 16 + l15];
        }
        return;
    }
    const float* W; ushort_t *oh, *ol; int KT, fl;
    if (f < 16)      { W = Wh; oh = BhWh; ol = BlWh; KT = 2; fl = f; }
    else if (f < 48) { W = W1; oh = BhW1; ol = BlW1; KT = 4; fl = f - 16; }
    else if (f < 80) { W = W2; oh = BhW2; ol = BlW2; KT = 4; fl = f - 48; }
    else             { W = FT; oh = BhFT; ol = BlFT; KT = 4; fl = f - 80; }
    const int ct = fl / KT, kt = fl % KT;
    const int col = ct * 16 + (lane & 15);
    const int kb  = kt * 32 + (lane >> 4) * 8;
#pragma unroll
    for (int j = 0; j < 8; ++j) {
        const float v = W[(kb + j) * 128 + col];
        const ushort_t h = bf16r(v);
        oh[(size_t)(fl * 64 + lane) * 8 + j] = h;
        ol[(size_t)(fl * 64 + lane) * 8 + j] = bf16r(v - bf2f(h));
    }
}

// ---------------------------------------------------------------------------
// proj_dual: P1 = x_a@W1 + (bh+bn), P2 = x_a@W2, stored f16 in layout
// P[row*128 + l15*8 + ct]. Also emits f16 copy of x_a.
// ---------------------------------------------------------------------------
__global__ __launch_bounds__(256) void proj_dual_mfma(
    const float* __restrict__ X,
    const ushort_t* __restrict__ B1h, const ushort_t* __restrict__ B1l,
    const ushort_t* __restrict__ B2h, const ushort_t* __restrict__ B2l,
    const float* __restrict__ bh, const float* __restrict__ bn,
    ushort_t* __restrict__ P1, ushort_t* __restrict__ P2,
    ushort_t* __restrict__ X16, int N)
{
    const int lane = threadIdx.x & 63;
    const int l15 = lane & 15, lg = lane >> 4;
    const int r0 = blockIdx.x * 64 + (threadIdx.x >> 6) * 16;
    const int arow = (r0 + l15 < N) ? (r0 + l15) : (N - 1);

    bf16x8 ahi[4], alo[4];
#pragma unroll
    for (int kt = 0; kt < 4; ++kt) {
        float v[8];
        *(float4*)(v + 0) = *(const float4*)&X[(size_t)arow * 128 + kt * 32 + lg * 8];
        *(float4*)(v + 4) = *(const float4*)&X[(size_t)arow * 128 + kt * 32 + lg * 8 + 4];
        uint4 xu;
        xu.x = packh2(v[0], v[1]); xu.y = packh2(v[2], v[3]);
        xu.z = packh2(v[4], v[5]); xu.w = packh2(v[6], v[7]);
        *(uint4*)&X16[(size_t)arow * 128 + kt * 32 + lg * 8] = xu;
#pragma unroll
        for (int j = 0; j < 8; ++j) {
            const ushort_t h = bf16r(v[j]);
            ahi[kt][j] = (short)h;
            alo[kt][j] = (short)bf16r(v[j] - bf2f(h));
        }
    }

    f32x4 acc1[8], acc2[8];
#pragma unroll
    for (int ct = 0; ct < 8; ++ct) {
        const float b = bh[ct * 16 + l15] + bn[ct * 16 + l15];
        acc1[ct] = (f32x4){b, b, b, b};
        acc2[ct] = (f32x4){0.f, 0.f, 0.f, 0.f};
    }

#pragma unroll
    for (int ct = 0; ct < 8; ++ct) {
#pragma unroll
        for (int kt = 0; kt < 4; ++kt) {
            const size_t fo = (size_t)((ct * 4 + kt) * 64 + lane) * 8;
            const bf16x8 b1h = *(const bf16x8*)&B1h[fo];
            const bf16x8 b1l = *(const bf16x8*)&B1l[fo];
            const bf16x8 b2h = *(const bf16x8*)&B2h[fo];
            const bf16x8 b2l = *(const bf16x8*)&B2l[fo];
            acc1[ct] = __builtin_amdgcn_mfma_f32_16x16x32_bf16(ahi[kt], b1h, acc1[ct], 0, 0, 0);
            acc1[ct] = __builtin_amdgcn_mfma_f32_16x16x32_bf16(alo[kt], b1h, acc1[ct], 0, 0, 0);
            acc1[ct] = __builtin_amdgcn_mfma_f32_16x16x32_bf16(ahi[kt], b1l, acc1[ct], 0, 0, 0);
            acc2[ct] = __builtin_amdgcn_mfma_f32_16x16x32_bf16(ahi[kt], b2h, acc2[ct], 0, 0, 0);
            acc2[ct] = __builtin_amdgcn_mfma_f32_16x16x32_bf16(alo[kt], b2h, acc2[ct], 0, 0, 0);
            acc2[ct] = __builtin_amdgcn_mfma_f32_16x16x32_bf16(ahi[kt], b2l, acc2[ct], 0, 0, 0);
        }
    }
#pragma unroll
    for (int i = 0; i < 4; ++i) {
        const int row = r0 + lg * 4 + i;
        if (row < N) {
            uint4 u1, u2;
            u1.x = packh2(acc1[0][i], acc1[1][i]); u1.y = packh2(acc1[2][i], acc1[3][i]);
            u1.z = packh2(acc1[4][i], acc1[5][i]); u1.w = packh2(acc1[6][i], acc1[7][i]);
            u2.x = packh2(acc2[0][i], acc2[1][i]); u2.y = packh2(acc2[2][i], acc2[3][i]);
            u2.z = packh2(acc2[4][i], acc2[5][i]); u2.w = packh2(acc2[6][i], acc2[7][i]);
            *(uint4*)&P1[(size_t)row * 128 + l15 * 8] = u1;
            *(uint4*)&P2[(size_t)row * 128 + l15 * 8] = u2;
        }
    }
}

// proj_single: P = x_b@W2 (no bias), f16 interleaved; emits xb16.
__global__ __launch_bounds__(256) void proj_single_mfma(
    const float* __restrict__ X,
    const ushort_t* __restrict__ Bh, const ushort_t* __restrict__ Bl,
    ushort_t* __restrict__ P, ushort_t* __restrict__ X16, int N)
{
    const int lane = threadIdx.x & 63;
    const int l15 = lane & 15, lg = lane >> 4;
    const int r0 = blockIdx.x * 64 + (threadIdx.x >> 6) * 16;
    const int arow = (r0 + l15 < N) ? (r0 + l15) : (N - 1);

    bf16x8 ahi[4], alo[4];
#pragma unroll
    for (int kt = 0; kt < 4; ++kt) {
        float v[8];
        *(float4*)(v + 0) = *(const float4*)&X[(size_t)arow * 128 + kt * 32 + lg * 8];
        *(float4*)(v + 4) = *(const float4*)&X[(size_t)arow * 128 + kt * 32 + lg * 8 + 4];
        uint4 xu;
        xu.x = packh2(v[0], v[1]); xu.y = packh2(v[2], v[3]);
        xu.z = packh2(v[4], v[5]); xu.w = packh2(v[6], v[7]);
        *(uint4*)&X16[(size_t)arow * 128 + kt * 32 + lg * 8] = xu;
#pragma unroll
        for (int j = 0; j < 8; ++j) {
            const ushort_t h = bf16r(v[j]);
            ahi[kt][j] = (short)h;
            alo[kt][j] = (short)bf16r(v[j] - bf2f(h));
        }
    }

    f32x4 acc[8];
#pragma unroll
    for (int ct = 0; ct < 8; ++ct) acc[ct] = (f32x4){0.f, 0.f, 0.f, 0.f};

#pragma unroll
    for (int ct = 0; ct < 8; ++ct) {
#pragma unroll
        for (int kt = 0; kt < 4; ++kt) {
            const size_t fo = (size_t)((ct * 4 + kt) * 64 + lane) * 8;
            const bf16x8 bhf = *(const bf16x8*)&Bh[fo];
            const bf16x8 blf = *(const bf16x8*)&Bl[fo];
            acc[ct] = __builtin_amdgcn_mfma_f32_16x16x32_bf16(ahi[kt], bhf, acc[ct], 0, 0, 0);
            acc[ct] = __builtin_amdgcn_mfma_f32_16x16x32_bf16(alo[kt], bhf, acc[ct], 0, 0, 0);
            acc[ct] = __builtin_amdgcn_mfma_f32_16x16x32_bf16(ahi[kt], blf, acc[ct], 0, 0, 0);
        }
    }
#pragma unroll
    for (int i = 0; i < 4; ++i) {
        const int row = r0 + lg * 4 + i;
        if (row < N) {
            uint4 u;
            u.x = packh2(acc[0][i], acc[1][i]); u.y = packh2(acc[2][i], acc[3][i]);
            u.z = packh2(acc[4][i], acc[5][i]); u.w = packh2(acc[6][i], acc[7][i]);
            *(uint4*)&P[(size_t)row * 128 + l15 * 8] = u;
        }
    }
}

// ---------------------------------------------------------------------------
// Merged edge-score kernel, both types in one launch (grid 10000):
//  blocks [0,5000)  -> AB edges (count cntA[s], cntB[d])
//  blocks [5000,10000) -> AA edges (count cntA[s])
// 64 edges/block, 16/wave. Wh B-fragments staged in LDS; P-gathers hoisted
// to the top so their latency hides under A-conversion + MFMA.
// Fused: CSR count+rank, softmax block partials (pm/pl[blockIdx.x]).
// ---------------------------------------------------------------------------
__global__ __launch_bounds__(256) void edge_score_k(
    const float* __restrict__ ea_ab, const float* __restrict__ ea_aa,
    const int*   __restrict__ ei_ab, const int*   __restrict__ ei_aa,
    const ushort_t* __restrict__ P1h,
    const ushort_t* __restrict__ P2ah, const ushort_t* __restrict__ P2bh,
    const ushort_t* __restrict__ Bhi,  const ushort_t* __restrict__ Blo,
    const float* __restrict__ wep,
    float* __restrict__ scAB, float* __restrict__ scAA,
    int* __restrict__ cntA, int* __restrict__ cntB,
    int* __restrict__ rkAab, int* __restrict__ rkBab, int* __restrict__ rkAaa,
    float* __restrict__ pm, float* __restrict__ pl)
{
    const int t    = threadIdx.x;
    const int lane = t & 63;
    const int l15  = lane & 15;
    const int lg   = lane >> 4;
    const int wv   = t >> 6;
    const int type = (blockIdx.x >= 5000);
    const int bb   = type ? (blockIdx.x - 5000) : blockIdx.x;
    const int eb   = bb * 64;

    const float* __restrict__ ea  = type ? ea_aa : ea_ab;
    const int*   __restrict__ ei  = type ? ei_aa : ei_ab;
    const ushort_t* __restrict__ P2h = type ? P2ah : P2bh;
    float* __restrict__ score = type ? scAA : scAB;

    __shared__ ushort_t sBh[8192];   // 16 KB
    __shared__ ushort_t sBl[8192];   // 16 KB
    // stage Wh fragments (linear copy; issued first so vmcnt waits for these
    // don't drain the later P gathers)
    {
        const uint4* gh = (const uint4*)Bhi;
        const uint4* gl = (const uint4*)Blo;
        uint4* sh = (uint4*)sBh;
        uint4* sl = (uint4*)sBl;
#pragma unroll
        for (int i = 0; i < 4; ++i) {
            sh[t + i * 256] = gh[t + i * 256];
            sl[t + i * 256] = gl[t + i * 256];
        }
    }

    // fused CSR count + rank
    if (t < 64) {
        const int e = eb + t;
        const int s = ei[e];
        const int r = atomicAdd(&cntA[s], 1);
        if (type) rkAaa[e] = r; else rkAab[e] = r;
    } else if (t < 128 && !type) {
        const int e = eb + (t - 64);
        const int d = ei[(size_t)E_AB + e];
        rkBab[e] = atomicAdd(&cntB[d], 1);
    }

    const int e0 = eb + wv * 16;   // this wave's 16 edges

    // hoisted indices + P gathers (fly under A-conversion + MFMA)
    int sidx[4], didx[4];
#pragma unroll
    for (int i = 0; i < 4; ++i) {
        const int e = e0 + lg * 4 + i;
        sidx[i] = ei[e];
        didx[i] = ei[(size_t)E_AB + e];   // E identical for both types
    }
    uint4 p1u[4], p2u[4];
#pragma unroll
    for (int i = 0; i < 4; ++i) {
        p1u[i] = *(const uint4*)&P1h[(size_t)sidx[i] * 128 + l15 * 8];
        p2u[i] = *(const uint4*)&P2h[(size_t)didx[i] * 128 + l15 * 8];
    }

    // A fragment: row = l15 (edge e0+l15), k = kt*32 + lg*8 + j
    const float* arow = &ea[(size_t)(e0 + l15) * 64 + lg * 8];
    float af[16];
    *(float4*)(af + 0)  = *(const float4*)(arow + 0);
    *(float4*)(af + 4)  = *(const float4*)(arow + 4);
    *(float4*)(af + 8)  = *(const float4*)(arow + 32);
    *(float4*)(af + 12) = *(const float4*)(arow + 36);

    bf16x8 ahi0, alo0, ahi1, alo1;
#pragma unroll
    for (int j = 0; j < 8; ++j) {
        const ushort_t h0 = bf16r(af[j]);
        ahi0[j] = (short)h0;
        alo0[j] = (short)bf16r(af[j] - bf2f(h0));
        const ushort_t h1 = bf16r(af[8 + j]);
        ahi1[j] = (short)h1;
        alo1[j] = (short)bf16r(af[8 + j] - bf2f(h1));
    }

    __syncthreads();   // staging complete

    f32x4 acc[8];
#pragma unroll
    for (int ct = 0; ct < 8; ++ct) acc[ct] = (f32x4){0.f, 0.f, 0.f, 0.f};

#pragma unroll
    for (int ct = 0; ct < 8; ++ct) {
        const bf16x8 bh0 = *(const bf16x8*)&sBh[(ct * 2 + 0) * 512 + lane * 8];
        const bf16x8 bl0 = *(const bf16x8*)&sBl[(ct * 2 + 0) * 512 + lane * 8];
        const bf16x8 bh1 = *(const bf16x8*)&sBh[(ct * 2 + 1) * 512 + lane * 8];
        const bf16x8 bl1 = *(const bf16x8*)&sBl[(ct * 2 + 1) * 512 + lane * 8];
        acc[ct] = __builtin_amdgcn_mfma_f32_16x16x32_bf16(ahi0, bh0, acc[ct], 0, 0, 0);
        acc[ct] = __builtin_amdgcn_mfma_f32_16x16x32_bf16(alo0, bh0, acc[ct], 0, 0, 0);
        acc[ct] = __builtin_amdgcn_mfma_f32_16x16x32_bf16(ahi0, bl0, acc[ct], 0, 0, 0);
        acc[ct] = __builtin_amdgcn_mfma_f32_16x16x32_bf16(ahi1, bh1, acc[ct], 0, 0, 0);
        acc[ct] = __builtin_amdgcn_mfma_f32_16x16x32_bf16(alo1, bh1, acc[ct], 0, 0, 0);
        acc[ct] = __builtin_amdgcn_mfma_f32_16x16x32_bf16(ahi1, bl1, acc[ct], 0, 0, 0);
    }

    float w8[8];
    *(float4*)(w8 + 0) = *(const float4*)&wep[l15 * 8];
    *(float4*)(w8 + 4) = *(const float4*)&wep[l15 * 8 + 4];

    float part[4];
#pragma unroll
    for (int i = 0; i < 4; ++i) {
        const __half2* h1 = (const __half2*)&p1u[i];
        const __half2* h2 = (const __half2*)&p2u[i];
        float p = 0.f;
#pragma unroll
        for (int q = 0; q < 4; ++q) {
            const float2 pf = __half22float2(__hadd2(h1[q], h2[q]));
            const float v0 = acc[2 * q][i] + pf.x;
            const float v1 = acc[2 * q + 1][i] + pf.y;
            p = fmaf(fmaxf(v0, 0.f), w8[2 * q], p);
            p = fmaf(fmaxf(v1, 0.f), w8[2 * q + 1], p);
        }
        part[i] = p;
    }
#pragma unroll
    for (int m = 8; m >= 1; m >>= 1) {
#pragma unroll
        for (int i = 0; i < 4; ++i) part[i] += __shfl_xor(part[i], m, 64);
    }
    if (l15 == 0) {
#pragma unroll
        for (int i = 0; i < 4; ++i) score[e0 + lg * 4 + i] = part[i];
    }

    // fused softmax partials over this wave's 16 scores
    float mw = fmaxf(fmaxf(part[0], part[1]), fmaxf(part[2], part[3]));
    float lw = __expf(part[0] - mw) + __expf(part[1] - mw)
             + __expf(part[2] - mw) + __expf(part[3] - mw);
#pragma unroll
    for (int off = 16; off <= 32; off <<= 1) {
        const float om = __shfl_xor(mw, off, 64);
        const float ol = __shfl_xor(lw, off, 64);
        online_merge(mw, lw, om, ol);
    }
    __shared__ float smm[4], sll[4];
    if (lane == 0) { smm[wv] = mw; sll[wv] = lw; }
    __syncthreads();
    if (t == 0) {
        float M = smm[0], L = sll[0];
        for (int i = 1; i < 4; ++i) online_merge(M, L, smm[i], sll[i]);
        pm[blockIdx.x] = M;
        pl[blockIdx.x] = L;
    }
}

// ---------------------------------------------------------------------------
// Final softmax reduction over block partials; grid 2 (type per block)
// ---------------------------------------------------------------------------
__global__ __launch_bounds__(1024) void softmax_final_kernel(
    const float* __restrict__ pm, const float* __restrict__ pl,
    float* __restrict__ ML, int nPart)
{
    const int type = blockIdx.x;
    const float* mi = pm + type * nPart;
    const float* li = pl + type * nPart;
    float m = -1e30f, l = 0.f;
    for (int i = threadIdx.x; i < nPart; i += 1024) online_merge(m, l, mi[i], li[i]);
#pragma unroll
    for (int off = 1; off < 64; off <<= 1) {
        const float om = __shfl_xor(m, off, 64);
        const float ol = __shfl_xor(l, off, 64);
        online_merge(m, l, om, ol);
    }
    __shared__ float smm[16], sll[16];
    const int w = threadIdx.x >> 6, lane = threadIdx.x & 63;
    if (lane == 0) { smm[w] = m; sll[w] = l; }
    __syncthreads();
    if (threadIdx.x == 0) {
        float M = smm[0], L = sll[0];
        for (int i = 1; i < 16; ++i) online_merge(M, L, smm[i], sll[i]);
        ML[type * 2]     = M;
        ML[type * 2 + 1] = L;
    }
}

// ---------------------------------------------------------------------------
// CSR scan
// ---------------------------------------------------------------------------
__global__ __launch_bounds__(1024) void csr_scan_kernel(
    const int* __restrict__ cntA, int* __restrict__ offA,
    const int* __restrict__ cntB, int* __restrict__ offB, int N)
{
    const int* cnt = (blockIdx.x == 0) ? cntA : cntB;
    int* off = (blockIdx.x == 0) ? offA : offB;

    __shared__ int warpsum[16];
    const int t = threadIdx.x, lane = t & 63, w = t >> 6;
    int carry = 0;

    for (int base = 0; base < N; base += 1024) {
        const int i = base + t;
        const int v = (i < N) ? cnt[i] : 0;
        int x = v;
#pragma unroll
        for (int d = 1; d < 64; d <<= 1) {
            const int y = __shfl_up(x, d, 64);
            if (lane >= d) x += y;
        }
        if (lane == 63) warpsum[w] = x;
        __syncthreads();
        if (w == 0 && lane < 16) {
            int s = warpsum[lane];
#pragma unroll
            for (int d = 1; d < 16; d <<= 1) {
                const int y = __shfl_up(s, d, 64);
                if (lane >= d) s += y;
            }
            warpsum[lane] = s;
        }
        __syncthreads();
        const int excl = (x - v) + ((w > 0) ? warpsum[w - 1] : 0) + carry;
        if (i < N) off[i] = excl;
        carry += warpsum[15];
        __syncthreads();
    }
    if (t == 0) off[N] = carry;
}

// Atomic-free fill with fused softmax normalization (positions clamped for
// rocprof-replay atomic-inflation safety).
__global__ __launch_bounds__(256) void csr_fill_kernel(
    const int* __restrict__ ei_ab, const int* __restrict__ ei_aa,
    float* __restrict__ scAB, float* __restrict__ scAA,
    const float* __restrict__ ML,
    const int* __restrict__ offA, const int* __restrict__ offB,
    const int* __restrict__ rkAab, const int* __restrict__ rkBab,
    const int* __restrict__ rkAaa,
    int2* __restrict__ idxA, int2* __restrict__ idxB)
{
    const int i = blockIdx.x * 256 + threadIdx.x;
    const float Mab = ML[0], rLab = 1.0f / ML[1];
    const float Maa = ML[2], rLaa = 1.0f / ML[3];
    if (i < E_AB) {
        const float a = __expf(scAB[i] - Mab) * rLab;
        scAB[i] = a;
        const int s = ei_ab[i], d = ei_ab[E_AB + i];
        const int ab = __float_as_int(a);
        int pA = offA[s] + rkAab[i]; if (pA > 2 * E_AB - 1) pA = 2 * E_AB - 1;
        int pB = offB[d] + rkBab[i]; if (pB > E_AB - 1) pB = E_AB - 1;
        idxA[pA] = make_int2(d | (1 << 20), ab);
        idxB[pB] = make_int2(s, ab);
    }
    if (i < E_AA) {
        const float a = __expf(scAA[i] - Maa) * rLaa;
        scAA[i] = a;
        const int s = ei_aa[i];
        const int daa = ei_aa[E_AA + i];
        int pA = offA[s] + rkAaa[i]; if (pA > 2 * E_AB - 1) pA = 2 * E_AB - 1;
        idxA[pA] = make_int2(daa, __float_as_int(a));
    }
}

// ---------------------------------------------------------------------------
// Fused gather + final. Phase 1: quarter-wave per row, 4-wide entry unroll
// (independent gathers -> 4 idx + 4 row fetches in flight). Phase 2: final
// MFMA (T <- T + T@FT + fb) on the same 16 rows (L2-hot).
// ---------------------------------------------------------------------------
__global__ __launch_bounds__(256) void gather_final(
    const int*  __restrict__ off, const int2* __restrict__ idx,
    const ushort_t* __restrict__ xa16, const ushort_t* __restrict__ xb16,
    const float* __restrict__ xself,
    const ushort_t* __restrict__ Bh, const ushort_t* __restrict__ Bl,
    const float* __restrict__ fb,
    float* __restrict__ T, int N)
{
    const int lane = threadIdx.x & 63;
    const int l15  = lane & 15, lg = lane >> 4;
    const int wv   = threadIdx.x >> 6;
    const int r0   = blockIdx.x * 64 + wv * 16;

    // ---- Phase 1: gather 16 rows (4 steps x 4 concurrent quarter-wave rows)
    for (int s = 0; s < 4; ++s) {
        const int row = r0 + s * 4 + lg;
        if (row < N) {
            const int beg = off[row], end = off[row + 1];
            float a8[8];
            *(float4*)(a8 + 0) = *(const float4*)&xself[(size_t)row * 128 + l15 * 8];
            *(float4*)(a8 + 4) = *(const float4*)&xself[(size_t)row * 128 + l15 * 8 + 4];
            int e = beg;
            for (; e + 3 < end; e += 4) {
                int2 q[4];
#pragma unroll
                for (int k = 0; k < 4; ++k) q[k] = idx[e + k];
                uint4 f[4];
#pragma unroll
                for (int k = 0; k < 4; ++k) {
                    const ushort_t* sp = (q[k].x & (1 << 20)) ? xb16 : xa16;
                    f[k] = *(const uint4*)&sp[(size_t)(q[k].x & 0xFFFFF) * 128 + l15 * 8];
                }
#pragma unroll
                for (int k = 0; k < 4; ++k) {
                    const float al = __int_as_float(q[k].y);
                    const __half2* hp = (const __half2*)&f[k];
#pragma unroll
                    for (int j = 0; j < 4; ++j) {
                        const float2 vf = __half22float2(hp[j]);
                        a8[2 * j]     = fmaf(-al, vf.x, a8[2 * j]);
                        a8[2 * j + 1] = fmaf(-al, vf.y, a8[2 * j + 1]);
                    }
                }
            }
            for (; e < end; ++e) {
                const int2 q0 = idx[e];
                const float al = __int_as_float(q0.y);
                const ushort_t* sp = (q0.x & (1 << 20)) ? xb16 : xa16;
                const uint4 f0 = *(const uint4*)&sp[(size_t)(q0.x & 0xFFFFF) * 128 + l15 * 8];
                const __half2* hp = (const __half2*)&f0;
#pragma unroll
                for (int j = 0; j < 4; ++j) {
                    const float2 vf = __half22float2(hp[j]);
                    a8[2 * j]     = fmaf(-al, vf.x, a8[2 * j]);
                    a8[2 * j + 1] = fmaf(-al, vf.y, a8[2 * j + 1]);
                }
            }
            *(float4*)&T[(size_t)row * 128 + l15 * 8]     = *(float4*)(a8 + 0);
            *(float4*)&T[(size_t)row * 128 + l15 * 8 + 4] = *(float4*)(a8 + 4);
        }
    }
    __syncthreads();

    // ---- Phase 2: final MFMA on rows [r0, r0+16)
    const int arow = (r0 + l15 < N) ? (r0 + l15) : (N - 1);
    bf16x8 ahi[4], alo[4];
#pragma unroll
    for (int kt = 0; kt < 4; ++kt) {
        float v[8];
        *(float4*)(v + 0) = *(const float4*)&T[(size_t)arow * 128 + kt * 32 + lg * 8];
        *(float4*)(v + 4) = *(const float4*)&T[(size_t)arow * 128 + kt * 32 + lg * 8 + 4];
#pragma unroll
        for (int j = 0; j < 8; ++j) {
            const ushort_t h = bf16r(v[j]);
            ahi[kt][j] = (short)h;
            alo[kt][j] = (short)bf16r(v[j] - bf2f(h));
        }
    }

    f32x4 acc[8];
#pragma unroll
    for (int ct = 0; ct < 8; ++ct) {
        const float b = fb[ct * 16 + l15];
#pragma unroll
        for (int i = 0; i < 4; ++i) {
            const int row = r0 + lg * 4 + i;
            const int rr = (row < N) ? row : (N - 1);
            acc[ct][i] = T[(size_t)rr * 128 + ct * 16 + l15] + b;
        }
    }

#pragma unroll
    for (int ct = 0; ct < 8; ++ct) {
#pragma unroll
        for (int kt = 0; kt < 4; ++kt) {
            const size_t fo = (size_t)((ct * 4 + kt) * 64 + lane) * 8;
            const bf16x8 bhf = *(const bf16x8*)&Bh[fo];
            const bf16x8 blf = *(const bf16x8*)&Bl[fo];
            acc[ct] = __builtin_amdgcn_mfma_f32_16x16x32_bf16(ahi[kt], bhf, acc[ct], 0, 0, 0);
            acc[ct] = __builtin_amdgcn_mfma_f32_16x16x32_bf16(alo[kt], bhf, acc[ct], 0, 0, 0);
            acc[ct] = __builtin_amdgcn_mfma_f32_16x16x32_bf16(ahi[kt], blf, acc[ct], 0, 0, 0);
        }
    }
#pragma unroll
    for (int ct = 0; ct < 8; ++ct) {
#pragma unroll
        for (int i = 0; i < 4; ++i) {
            const int row = r0 + lg * 4 + i;
            if (row < N) T[(size_t)row * 128 + ct * 16 + l15] = acc[ct][i];
        }
    }
}

// ---------------------------------------------------------------------------
extern "C" void kernel_launch(void* const* d_in, const int* in_sizes, int n_in,
                              void* d_out, int out_size, void* d_ws, size_t ws_size,
                              hipStream_t stream)
{
    const float* x_a   = (const float*)d_in[0];
    const float* x_b   = (const float*)d_in[1];
    const int*   ei_ab = (const int*)d_in[2];
    const float* ea_ab = (const float*)d_in[3];
    const int*   ei_aa = (const int*)d_in[4];
    const float* ea_aa = (const float*)d_in[5];
    const float* Wh_w  = (const float*)d_in[6];
    const float* Wh_b  = (const float*)d_in[7];
    const float* Wn_w  = (const float*)d_in[8];
    const float* Wn_b  = (const float*)d_in[9];
    const float* w_e   = (const float*)d_in[10];
    const float* ft_w  = (const float*)d_in[11];
    const float* ft_b  = (const float*)d_in[12];

    float* out = (float*)d_out;
    float* ws  = (float*)d_ws;

    // ws layout (float offsets; all regions disjoint)
    ushort_t* P1h  = (ushort_t*)(ws);              // 6.4M ushorts
    ushort_t* P2ah = (ushort_t*)(ws + 3200000);
    ushort_t* P2bh = (ushort_t*)(ws + 6400000);
    ushort_t* xa16 = (ushort_t*)(ws + 9600000);
    ushort_t* xb16 = (ushort_t*)(ws + 12800000);
    int* rkAab = (int*)(ws + 16000000);
    int* rkBab = (int*)(ws + 16320000);
    int* rkAaa = (int*)(ws + 16640000);
    int* cntA  = (int*)(ws + 16960000);            // cntA+cntB contiguous
    int* cntB  = (int*)(ws + 17010000);
    int* offA  = (int*)(ws + 17060000);            // 50001
    int* offB  = (int*)(ws + 17110004);            // 50001
    float* pm  = ws + 17160008;                    // 10000 (5000 per type)
    float* pl  = ws + 17170008;                    // 10000
    float* ML  = ws + 17180008;                    // 4
    float* wep = ws + 17180016;                    // 128
    ushort_t* FR = (ushort_t*)(ws + 17180208);     // 114688 ushorts
    ushort_t* BhWh = FR;
    ushort_t* BlWh = FR + 8192;
    ushort_t* BhW1 = FR + 16384;
    ushort_t* BlW1 = FR + 32768;
    ushort_t* BhW2 = FR + 49152;
    ushort_t* BlW2 = FR + 65536;
    ushort_t* BhFT = FR + 81920;
    ushort_t* BlFT = FR + 98304;
    int2* idxA = (int2*)(ws + 17240000);           // 640000 entries
    int2* idxB = (int2*)(ws + 18520000);           // 320000 entries

    // d_out layout: out_a[6.4M] out_b[6.4M] alpha_ab[320K] alpha_aa[320K]
    float* TA   = out;
    float* TB   = out + 6400000;
    float* alAB = out + 12800000;   // raw scores, then normalized in csr_fill
    float* alAA = out + 13120000;

    // 0) zero CSR counters; pack weights
    hipMemsetAsync(cntA, 0, 100000 * sizeof(int), stream);
    prep_w_all<<<113, 64, 0, stream>>>(Wh_w, Wn_w, Wn_w + 128 * 128, ft_w, w_e,
                                       BhWh, BlWh, BhW1, BlW1, BhW2, BlW2, BhFT, BlFT, wep);

    // 1) node projections (f16 tables, interleaved layout) + f16 x copies
    proj_dual_mfma<<<(N_A + 63) / 64, 256, 0, stream>>>(x_a, BhW1, BlW1, BhW2, BlW2,
                                                        Wh_b, Wn_b, P1h, P2ah, xa16, N_A);
    proj_single_mfma<<<(N_B + 63) / 64, 256, 0, stream>>>(x_b, BhW2, BlW2, P2bh, xb16, N_B);

    // 2) merged edge scores (fused: CSR count+rank, softmax block partials)
    edge_score_k<<<10000, 256, 0, stream>>>(ea_ab, ea_aa, ei_ab, ei_aa,
                                            P1h, P2ah, P2bh, BhWh, BlWh, wep,
                                            alAB, alAA, cntA, cntB,
                                            rkAab, rkBab, rkAaa, pm, pl);

    // 3) softmax final reduction (both types)
    softmax_final_kernel<<<2, 1024, 0, stream>>>(pm, pl, ML, 5000);

    // 4) CSR scan + atomic-free fill (fused normalization)
    csr_scan_kernel<<<2, 1024, 0, stream>>>(cntA, offA, cntB, offB, N_A);
    csr_fill_kernel<<<(E_AB + 255) / 256, 256, 0, stream>>>(ei_ab, ei_aa, alAB, alAA, ML,
                                                            offA, offB, rkAab, rkBab, rkAaa,
                                                            idxA, idxB);

    // 5) fused gather + final transform
    gather_final<<<(N_A + 63) / 64, 256, 0, stream>>>(offA, idxA, xa16, xb16, x_a,
                                                      BhFT, BlFT, ft_b, TA, N_A);
    gather_final<<<(N_B + 63) / 64, 256, 0, stream>>>(offB, idxB, xa16, xb16, x_b,
                                                      BhFT, BlFT, ft_b, TB, N_B);

    (void)in_sizes; (void)n_in; (void)out_size; (void)ws_size;
}